// Round 5
// baseline (14039.220 us; speedup 1.0000x reference)
//
#include <hip/hip_runtime.h>
#include <hip/hip_cooperative_groups.h>
#include <cmath>

namespace cg = cooperative_groups;

#define Wd 256
#define Hd 256
#define HWd 65536
#define NTOT 4194304
#define NACC 51
#define NSLOT 64                     // atomic slots per step, one 64B line each

#define C_COUP (2.0f / 4194304.0f)   // 2*COUPLING/N
#define C_KIN  (0.2f / 4194304.0f)   // 2*ALPHA/N
#define C_VOID 0.0098f               // 2*GAMMA^2
#define SCFP 68719476736.0           // 2^36 fixed-point scale

// block-level reduce of phi^2 sums -> one deterministic fixed-point atomic pair
__device__ __forceinline__ void block_acc(float sumx, float sumy, float* sRed,
                                          unsigned long long* slot) {
    for (int off = 32; off > 0; off >>= 1) {
        sumx += __shfl_down(sumx, off, 64);
        sumy += __shfl_down(sumy, off, 64);
    }
    const int tid = threadIdx.x;
    const int wid = tid >> 6;
    if ((tid & 63) == 0) { sRed[wid] = sumx; sRed[4 + wid] = sumy; }
    __syncthreads();
    if (tid == 0) {
        float fx = sRed[0] + sRed[1] + sRed[2] + sRed[3];
        float fy = sRed[4] + sRed[5] + sRed[6] + sRed[7];
        atomicAdd(&slot[0], (unsigned long long)((double)fx * SCFP + 0.5));
        atomicAdd(&slot[1], (unsigned long long)((double)fy * SCFP + 0.5));
    }
}

// ===================== persistent cooperative kernel =====================
__global__ __launch_bounds__(256, 4)
void k_persist(const float* __restrict__ S,
               const float* __restrict__ px0, const float* __restrict__ py0,
               float* __restrict__ outAx, float* __restrict__ outAy,
               float* __restrict__ outBx, float* __restrict__ outBy,
               float* __restrict__ sp, unsigned long long* __restrict__ acc)
{
    __shared__ __align__(16) float sPx[36][44];
    __shared__ __align__(16) float sPy[36][44];
    __shared__ float sC1x[34][35], sC2x[34][35];
    __shared__ float sC1y[34][35], sC2y[34][35];
    __shared__ float sRed[8];

    const int tid = threadIdx.x;
    const int b   = blockIdx.x;
    const int x0  = (b & 7) * 32;
    const int y0  = ((b >> 3) & 7) * 32;
    const int zb  = (b >> 6) * 4;          // 4 owned z-slices
    const int cgi = tid & 7;
    const int rr  = tid >> 3;
    const int gy  = y0 + rr;
    const int gxb = x0 + 4 * cgi;
    const bool ok_e = (gxb + 4 < Wd);
    const bool ok_d = (gy + 1 < Hd);

    // Adam state in registers for the whole run: 16 elements x (mx,vx,my,vy)
    float stmx[4][4], stvx[4][4], stmy[4][4], stvy[4][4];

    // ---- init: zero state, initial ||phi0||^2 over owned tiles ----
    float sx = 0.f, sy = 0.f;
#pragma unroll
    for (int zi = 0; zi < 4; ++zi) {
        const size_t idx = (size_t)(zb + zi) * HWd + (size_t)gy * Wd + gxb;
        float4 x = *(const float4*)(px0 + idx);
        float4 y = *(const float4*)(py0 + idx);
        sx += x.x*x.x + x.y*x.y + x.z*x.z + x.w*x.w;
        sy += y.x*y.x + y.y*y.y + y.z*y.z + y.w*y.w;
#pragma unroll
        for (int j = 0; j < 4; ++j) {
            stmx[zi][j] = 0.f; stvx[zi][j] = 0.f;
            stmy[zi][j] = 0.f; stvy[zi][j] = 0.f;
        }
    }
    block_acc(sx, sy, sRed, acc + (size_t)(b & 63) * 8);
    cg::this_grid().sync();

    double b1p = 1.0, b2p = 1.0;

    for (int t = 1; t <= 50; ++t) {
        b1p *= 0.9; b2p *= 0.999;
        const float a_step  = (float)(0.05 / (1.0 - b1p));
        const float inv_bc2 = (float)(1.0 / (1.0 - b2p));

        // SSB coefs from previous step's fixed-point slots (order-independent)
        const unsigned long long* ap = acc + (size_t)(t - 1) * NSLOT * 8;
        unsigned long long axu = 0ull, ayu = 0ull;
#pragma unroll 8
        for (int i = 0; i < NSLOT; ++i) { axu += ap[i * 8]; ayu += ap[i * 8 + 1]; }
        double axd = (double)axu * (1.0 / SCFP);
        double ayd = (double)ayu * (1.0 / SCFP);
        double nxd = sqrt(axd), nyd = sqrt(ayd);
        double pnd = nxd + nyd;
        double uu  = pnd * pnd - 0.01;       // V^2
        double sg  = (uu > 0.0) ? 1.0 : ((uu < 0.0) ? -1.0 : 0.0);
        const float coefx = (float)(0.2 * sg * pnd / nxd);
        const float coefy = (float)(0.2 * sg * pnd / nyd);

        const float* pix; const float* piy;
        float* pox; float* poy;
        if (t == 1)     { pix = px0;   piy = py0;   }
        else if (t & 1) { pix = outAx; piy = outAy; }
        else            { pix = outBx; piy = outBy; }
        if (t & 1)      { pox = outBx; poy = outBy; }
        else            { pox = outAx; poy = outAy; }

        float sumx = 0.f, sumy = 0.f;

#pragma unroll
        for (int zi = 0; zi < 4; ++zi) {
            const size_t base = (size_t)(zb + zi) * HWd;

            // ---- strip loads, both fields: 720 float4 tasks ----
#pragma unroll
            for (int k = 0; k < 3; ++k) {
                int task = tid + k * 256;
                if (task < 720) {
                    int f = (task >= 360) ? 1 : 0;
                    int r = task - f * 360;
                    int u = (r * 205) >> 11;         // r/10 exact for r<360
                    int v = r - 10 * u;
                    int gyy = y0 - 2 + u, gxx = x0 - 4 + 4 * v;
                    float4 val = make_float4(0.f, 0.f, 0.f, 0.f);
                    if ((unsigned)gyy < 256u && (unsigned)gxx < 256u) {
                        const float* src = f ? piy : pix;
                        val = *(const float4*)(src + base + (size_t)gyy * Wd + gxx);
                    }
                    float* dst = f ? &sPy[u][4 * v] : &sPx[u][4 * v];
                    *(float4*)dst = val;
                }
            }
            __syncthreads();

            // ---- c-stage both fields: 2x1156 scalar tasks ----
#pragma unroll
            for (int k = 0; k < 10; ++k) {
                int task = tid + k * 256;
                if (task < 2312) {
                    int f = (task >= 1156) ? 1 : 0;
                    int r = task - f * 1156;
                    int a = (r * 1929) >> 16;        // r/34 exact for r<1156
                    int bb = r - 34 * a;
                    int gyy = y0 - 1 + a, gxx = x0 - 1 + bb;
                    float c1 = 0.f, c2 = 0.f;
                    if ((unsigned)gyy < 256u && (unsigned)gxx < 256u) {
                        float (*sP)[44] = f ? sPy : sPx;
                        float tl = sP[a][bb + 2],     tc = sP[a][bb + 3],      tr = sP[a][bb + 4];
                        float ml = sP[a + 1][bb + 2],                          mr = sP[a + 1][bb + 4];
                        float bl = sP[a + 2][bb + 2], bc_ = sP[a + 2][bb + 3], br = sP[a + 2][bb + 4];
                        c1 = 0.125f * (tr - tl) + 0.25f * (mr - ml) + 0.125f * (br - bl);
                        c2 = 0.125f * (bl - tl) + 0.25f * (bc_ - tc) + 0.125f * (br - tr);
                    }
                    (f ? sC1y : sC1x)[a][bb] = c1;
                    (f ? sC2y : sC2x)[a][bb] = c2;
                }
            }
            __syncthreads();

            // ---- d-stage: dK + center phi, both fields ----
            float dKx[4], dKy[4], pxa[4], pya[4];
            {
                float4 p4 = *(float4*)&sPx[rr + 2][4 * cgi + 4];
                pxa[0] = p4.x; pxa[1] = p4.y; pxa[2] = p4.z; pxa[3] = p4.w;
                float4 q4 = *(float4*)&sPy[rr + 2][4 * cgi + 4];
                pya[0] = q4.x; pya[1] = q4.y; pya[2] = q4.z; pya[3] = q4.w;
#pragma unroll
                for (int j = 0; j < 4; ++j) {
                    int b0 = 4 * cgi + j;
                    dKx[j] = 0.125f * (sC1x[rr][b0 + 2]     - sC1x[rr][b0])
                           + 0.25f  * (sC1x[rr + 1][b0 + 2] - sC1x[rr + 1][b0])
                           + 0.125f * (sC1x[rr + 2][b0 + 2] - sC1x[rr + 2][b0])
                           + 0.125f * (sC2x[rr + 2][b0]     - sC2x[rr][b0])
                           + 0.25f  * (sC2x[rr + 2][b0 + 1] - sC2x[rr][b0 + 1])
                           + 0.125f * (sC2x[rr + 2][b0 + 2] - sC2x[rr][b0 + 2]);
                    dKy[j] = 0.125f * (sC1y[rr][b0 + 2]     - sC1y[rr][b0])
                           + 0.25f  * (sC1y[rr + 1][b0 + 2] - sC1y[rr + 1][b0])
                           + 0.125f * (sC1y[rr + 2][b0 + 2] - sC1y[rr + 2][b0])
                           + 0.125f * (sC2y[rr + 2][b0]     - sC2y[rr][b0])
                           + 0.25f  * (sC2y[rr + 2][b0 + 1] - sC2y[rr][b0 + 1])
                           + 0.125f * (sC2y[rr + 2][b0 + 2] - sC2y[rr][b0 + 2]);
                }
            }
            __syncthreads();   // LDS reads done; next zi may overwrite

            // ---- pointwise grad + Adam (state in registers) ----
            const size_t idx = base + (size_t)gy * Wd + gxb;
            float4 s4 = *(const float4*)(S + idx);
            float sa[4] = {s4.x, s4.y, s4.z, s4.w};
            float sE = ok_e ? S[idx + 4] : 0.f;
            float4 sD = ok_d ? *(const float4*)(S + idx + Wd) : make_float4(0.f, 0.f, 0.f, 0.f);
            float sdv[4] = {sD.x, sD.y, sD.z, sD.w};
            float npx[4], npy[4], spv[4];
#pragma unroll
            for (int j = 0; j < 4; ++j) {
                float dx_ = (j < 3) ? (sa[j + 1] - sa[j]) : (ok_e ? (sE - sa[3]) : 0.f);
                float dy_ = ok_d ? (sdv[j] - sa[j]) : 0.f;
                float R = pxa[j] * dx_ + pya[j] * dy_;
                float vmc = (sa[j] < 0.05f) ? C_VOID : 0.f;
                float gx_ = C_COUP * R * dx_ - C_KIN * dKx[j] + (coefx + vmc) * pxa[j];
                float gy_ = C_COUP * R * dy_ - C_KIN * dKy[j] + (coefy + vmc) * pya[j];

                float m1 = 0.9f * stmx[zi][j] + 0.1f * gx_;
                float v1 = 0.999f * stvx[zi][j] + 0.001f * gx_ * gx_;
                stmx[zi][j] = m1; stvx[zi][j] = v1;
                npx[j] = pxa[j] - a_step * m1 / (sqrtf(v1 * inv_bc2) + 1e-8f);
                sumx += npx[j] * npx[j];

                float m2 = 0.9f * stmy[zi][j] + 0.1f * gy_;
                float v2 = 0.999f * stvy[zi][j] + 0.001f * gy_ * gy_;
                stmy[zi][j] = m2; stvy[zi][j] = v2;
                npy[j] = pya[j] - a_step * m2 / (sqrtf(v2 * inv_bc2) + 1e-8f);
                sumy += npy[j] * npy[j];

                spv[j] = sa[j] + R;
            }
            *(float4*)(pox + idx) = make_float4(npx[0], npx[1], npx[2], npx[3]);
            *(float4*)(poy + idx) = make_float4(npy[0], npy[1], npy[2], npy[3]);
            if (t == 50)
                *(float4*)(sp + idx) = make_float4(spv[0], spv[1], spv[2], spv[3]);
        }

        block_acc(sumx, sumy, sRed, acc + ((size_t)t * NSLOT + (size_t)(b & 63)) * 8);
        cg::this_grid().sync();
    }
}

// ===================== fallback (proven R4 path) =====================
__device__ __forceinline__ void field_pass(
        const float* __restrict__ phiIn, size_t base, int x0, int y0,
        int tid, int cgi, int rr,
        float (*sP)[44], float (*sC1)[35], float (*sC2)[35],
        float dK[4], float pv[4])
{
#pragma unroll
    for (int k = 0; k < 2; ++k) {
        int task = tid + k * 256;
        if (task < 360) {
            int u = (task * 205) >> 11;
            int v = task - 10 * u;
            int gy = y0 - 2 + u, gx = x0 - 4 + 4 * v;
            float4 val = make_float4(0.f, 0.f, 0.f, 0.f);
            if ((unsigned)gy < 256u && (unsigned)gx < 256u)
                val = *(const float4*)(phiIn + base + (size_t)gy * Wd + gx);
            *(float4*)&sP[u][4 * v] = val;
        }
    }
    __syncthreads();
#pragma unroll
    for (int k = 0; k < 5; ++k) {
        int task = tid + k * 256;
        if (task < 1156) {
            int a = (task * 1929) >> 16;
            int b = task - 34 * a;
            int gy = y0 - 1 + a, gx = x0 - 1 + b;
            float c1 = 0.f, c2 = 0.f;
            if ((unsigned)gy < 256u && (unsigned)gx < 256u) {
                float tl = sP[a][b + 2],     tc = sP[a][b + 3],      tr = sP[a][b + 4];
                float ml = sP[a + 1][b + 2],                         mr = sP[a + 1][b + 4];
                float bl = sP[a + 2][b + 2], bc_ = sP[a + 2][b + 3], br = sP[a + 2][b + 4];
                c1 = 0.125f * (tr - tl) + 0.25f * (mr - ml) + 0.125f * (br - bl);
                c2 = 0.125f * (bl - tl) + 0.25f * (bc_ - tc) + 0.125f * (br - tr);
            }
            sC1[a][b] = c1; sC2[a][b] = c2;
        }
    }
    __syncthreads();
    {
        float4 p4 = *(float4*)&sP[rr + 2][4 * cgi + 4];
        pv[0] = p4.x; pv[1] = p4.y; pv[2] = p4.z; pv[3] = p4.w;
#pragma unroll
        for (int j = 0; j < 4; ++j) {
            int b0 = 4 * cgi + j;
            dK[j] = 0.125f * (sC1[rr][b0 + 2]     - sC1[rr][b0])
                  + 0.25f  * (sC1[rr + 1][b0 + 2] - sC1[rr + 1][b0])
                  + 0.125f * (sC1[rr + 2][b0 + 2] - sC1[rr + 2][b0])
                  + 0.125f * (sC2[rr + 2][b0]     - sC2[rr][b0])
                  + 0.25f  * (sC2[rr + 2][b0 + 1] - sC2[rr][b0 + 1])
                  + 0.125f * (sC2[rr + 2][b0 + 2] - sC2[rr][b0 + 2]);
        }
    }
    __syncthreads();
}

__global__ __launch_bounds__(256)
void k_step(const float* __restrict__ S,
            const float* __restrict__ pxin, const float* __restrict__ pyin,
            float* __restrict__ pxout, float* __restrict__ pyout,
            float* __restrict__ mx, float* __restrict__ my,
            float* __restrict__ vx, float* __restrict__ vy,
            const unsigned long long* __restrict__ accPrev,
            unsigned long long* __restrict__ accCur,
            float a_step, float inv_bc2, int write_sp, float* __restrict__ sp)
{
    __shared__ __align__(16) float sP[36][44];
    __shared__ float sC1[34][35];
    __shared__ float sC2[34][35];
    __shared__ float sRed[8];

    const int tid = threadIdx.x;
    const int cgi = tid & 7;
    const int rr  = tid >> 3;
    const int x0  = blockIdx.x * 32;
    const int y0  = blockIdx.y * 32;
    const size_t base = (size_t)blockIdx.z * HWd;

    unsigned long long axu = 0ull, ayu = 0ull;
#pragma unroll 8
    for (int i = 0; i < NSLOT; ++i) { axu += accPrev[i * 8]; ayu += accPrev[i * 8 + 1]; }
    double axd = (double)axu * (1.0 / SCFP);
    double ayd = (double)ayu * (1.0 / SCFP);
    double nxd = sqrt(axd), nyd = sqrt(ayd);
    double pnd = nxd + nyd;
    double uu = pnd * pnd - 0.01;
    double sg = (uu > 0.0) ? 1.0 : ((uu < 0.0) ? -1.0 : 0.0);
    const float coefx = (float)(0.2 * sg * pnd / nxd);
    const float coefy = (float)(0.2 * sg * pnd / nyd);

    float dKx[4], dKy[4], pxa[4], pya[4];
    field_pass(pxin, base, x0, y0, tid, cgi, rr, sP, sC1, sC2, dKx, pxa);
    field_pass(pyin, base, x0, y0, tid, cgi, rr, sP, sC1, sC2, dKy, pya);

    const int gy = y0 + rr;
    const int gxb = x0 + 4 * cgi;
    const size_t idx = base + (size_t)gy * Wd + gxb;

    float4 s4 = *(const float4*)(S + idx);
    float sa[4] = {s4.x, s4.y, s4.z, s4.w};
    const bool ok_e = (gxb + 4 < Wd);
    float sE = ok_e ? S[idx + 4] : 0.f;
    const bool ok_d = (gy + 1 < Hd);
    float4 sD = ok_d ? *(const float4*)(S + idx + Wd) : make_float4(0.f, 0.f, 0.f, 0.f);
    float sdv[4] = {sD.x, sD.y, sD.z, sD.w};

    float4 m4x = *(const float4*)(mx + idx);
    float4 v4x = *(const float4*)(vx + idx);
    float4 m4y = *(const float4*)(my + idx);
    float4 v4y = *(const float4*)(vy + idx);
    float ma[4] = {m4x.x, m4x.y, m4x.z, m4x.w};
    float va[4] = {v4x.x, v4x.y, v4x.z, v4x.w};
    float mb[4] = {m4y.x, m4y.y, m4y.z, m4y.w};
    float vb[4] = {v4y.x, v4y.y, v4y.z, v4y.w};

    float nmx[4], nvx[4], npx[4], nmy[4], nvy[4], npy[4], spv[4];
    float sumx = 0.f, sumy = 0.f;
#pragma unroll
    for (int j = 0; j < 4; ++j) {
        float dx_ = (j < 3) ? (sa[j + 1] - sa[j]) : (ok_e ? (sE - sa[3]) : 0.f);
        float dy_ = ok_d ? (sdv[j] - sa[j]) : 0.f;
        float R = pxa[j] * dx_ + pya[j] * dy_;
        float vmc = (sa[j] < 0.05f) ? C_VOID : 0.f;
        float gx_ = C_COUP * R * dx_ - C_KIN * dKx[j] + (coefx + vmc) * pxa[j];
        float gy_ = C_COUP * R * dy_ - C_KIN * dKy[j] + (coefy + vmc) * pya[j];

        float m1 = 0.9f * ma[j] + 0.1f * gx_;
        float v1 = 0.999f * va[j] + 0.001f * gx_ * gx_;
        nmx[j] = m1; nvx[j] = v1;
        npx[j] = pxa[j] - a_step * m1 / (sqrtf(v1 * inv_bc2) + 1e-8f);
        sumx += npx[j] * npx[j];

        float m2 = 0.9f * mb[j] + 0.1f * gy_;
        float v2 = 0.999f * vb[j] + 0.001f * gy_ * gy_;
        nmy[j] = m2; nvy[j] = v2;
        npy[j] = pya[j] - a_step * m2 / (sqrtf(v2 * inv_bc2) + 1e-8f);
        sumy += npy[j] * npy[j];

        spv[j] = sa[j] + R;
    }
    *(float4*)(mx + idx)    = make_float4(nmx[0], nmx[1], nmx[2], nmx[3]);
    *(float4*)(vx + idx)    = make_float4(nvx[0], nvx[1], nvx[2], nvx[3]);
    *(float4*)(pxout + idx) = make_float4(npx[0], npx[1], npx[2], npx[3]);
    *(float4*)(my + idx)    = make_float4(nmy[0], nmy[1], nmy[2], nmy[3]);
    *(float4*)(vy + idx)    = make_float4(nvy[0], nvy[1], nvy[2], nvy[3]);
    *(float4*)(pyout + idx) = make_float4(npy[0], npy[1], npy[2], npy[3]);
    if (write_sp)
        *(float4*)(sp + idx) = make_float4(spv[0], spv[1], spv[2], spv[3]);

    block_acc(sumx, sumy, sRed, accCur + (size_t)blockIdx.z * 8);
}

__global__ __launch_bounds__(256)
void k_init(const float* __restrict__ px0, const float* __restrict__ py0,
            float* __restrict__ pxA, float* __restrict__ pyA,
            float* __restrict__ mx, float* __restrict__ my,
            float* __restrict__ vx, float* __restrict__ vy,
            unsigned long long* __restrict__ acc0)
{
    __shared__ float sRed[8];
    const int tid = threadIdx.x;
    const size_t base = (size_t)blockIdx.x * 2048;
    float4 z4 = make_float4(0.f, 0.f, 0.f, 0.f);
    float sx = 0.f, sy = 0.f;
#pragma unroll
    for (int k = 0; k < 2; ++k) {
        size_t idx = base + (size_t)(k * 1024 + tid * 4);
        float4 x = *(const float4*)(px0 + idx);
        float4 y = *(const float4*)(py0 + idx);
        *(float4*)(pxA + idx) = x;  *(float4*)(pyA + idx) = y;
        *(float4*)(mx + idx) = z4;  *(float4*)(my + idx) = z4;
        *(float4*)(vx + idx) = z4;  *(float4*)(vy + idx) = z4;
        sx += x.x * x.x + x.y * x.y + x.z * x.z + x.w * x.w;
        sy += y.x * y.x + y.y * y.y + y.z * y.z + y.w * y.w;
    }
    block_acc(sx, sy, sRed, acc0 + (size_t)(blockIdx.x & (NSLOT - 1)) * 8);
}

extern "C" void kernel_launch(void* const* d_in, const int* in_sizes, int n_in,
                              void* d_out, int out_size, void* d_ws, size_t ws_size,
                              hipStream_t stream) {
    (void)in_sizes; (void)n_in; (void)out_size; (void)ws_size;
    const float* S   = (const float*)d_in[0];
    const float* px0 = (const float*)d_in[1];
    const float* py0 = (const float*)d_in[2];
    float* out = (float*)d_out;

    float* sp     = out;                      // slot 0: Sp
    float* outA_x = out + (size_t)NTOT;       // slot 1: phi_x post
    float* outA_y = out + 2 * (size_t)NTOT;   // slot 2: phi_y post
    float* outB_x = out + 3 * (size_t)NTOT;   // slot 3: phi_x pre
    float* outB_y = out + 4 * (size_t)NTOT;   // slot 4: phi_y pre

    float* ws = (float*)d_ws;
    float* mx = ws;                           // fallback Adam state
    float* my = mx + (size_t)NTOT;
    float* vx = my + (size_t)NTOT;
    float* vy = vx + (size_t)NTOT;
    unsigned long long* acc = (unsigned long long*)(vy + (size_t)NTOT);  // [NACC][NSLOT][8]

    hipMemsetAsync(acc, 0, (size_t)NACC * NSLOT * 8 * sizeof(unsigned long long), stream);

    void* args[] = { (void*)&S, (void*)&px0, (void*)&py0,
                     (void*)&outA_x, (void*)&outA_y, (void*)&outB_x, (void*)&outB_y,
                     (void*)&sp, (void*)&acc };
    hipError_t rc = hipLaunchCooperativeKernel(reinterpret_cast<void*>(k_persist),
                                               dim3(1024), dim3(256), args, 0, stream);
    if (rc != hipSuccess) {
        // fallback: proven non-cooperative path
        dim3 grid(8, 8, 64), blk(256, 1, 1);
        k_init<<<2048, 256, 0, stream>>>(px0, py0, outA_x, outA_y, mx, my, vx, vy, acc);
        for (int t = 1; t <= 50; ++t) {
            double bc1 = 1.0 - pow(0.9, (double)t);
            double bc2 = 1.0 - pow(0.999, (double)t);
            float a_step = (float)(0.05 / bc1);
            float inv_bc2 = (float)(1.0 / bc2);
            bool odd = (t & 1) != 0;
            const float* pix = odd ? outA_x : outB_x;
            const float* piy = odd ? outA_y : outB_y;
            float* pox = odd ? outB_x : outA_x;
            float* poy = odd ? outB_y : outA_y;
            k_step<<<grid, blk, 0, stream>>>(S, pix, piy, pox, poy,
                                             mx, my, vx, vy,
                                             acc + (size_t)(t - 1) * NSLOT * 8,
                                             acc + (size_t)t * NSLOT * 8,
                                             a_step, inv_bc2, (t == 50) ? 1 : 0, sp);
        }
    }
}

// Round 6
// 2224.777 us; speedup vs baseline: 6.3104x; 6.3104x over previous
//
#include <hip/hip_runtime.h>
#include <cmath>

#define Wd 256
#define Hd 256
#define HWd 65536
#define NTOT 4194304
#define NACC 51
#define NSLOT 64                     // atomic slots per step, one 64B line each

#define C_COUP (2.0f / 4194304.0f)   // 2*COUPLING/N
#define C_KIN  (0.2f / 4194304.0f)   // 2*ALPHA/N
#define C_VOID 0.0098f               // 2*GAMMA^2
#define SCFP 68719476736.0           // 2^36 fixed-point scale

// ---- packed bf16 pair helpers (RNE, deterministic) ----
__device__ __forceinline__ float bflo(unsigned w) { return __uint_as_float(w << 16); }
__device__ __forceinline__ float bfhi(unsigned w) { return __uint_as_float(w & 0xFFFF0000u); }
__device__ __forceinline__ unsigned bfpack(float lo, float hi) {
    unsigned ul = __float_as_uint(lo);
    ul = (ul + 0x7FFFu + ((ul >> 16) & 1u)) >> 16;
    unsigned uh = __float_as_uint(hi);
    uh = (uh + 0x7FFFu + ((uh >> 16) & 1u)) & 0xFFFF0000u;
    return (ul & 0xFFFFu) | uh;
}

// block-level reduce of phi^2 sums -> one deterministic fixed-point atomic pair
// into this block's z-slot (64B-padded line; 64 blocks/slot -> low contention)
__device__ __forceinline__ void block_acc(float sumx, float sumy, float* sRed,
                                          unsigned long long* slot) {
    for (int off = 32; off > 0; off >>= 1) {
        sumx += __shfl_down(sumx, off, 64);
        sumy += __shfl_down(sumy, off, 64);
    }
    const int tid = threadIdx.x;
    const int wid = tid >> 6;
    if ((tid & 63) == 0) { sRed[wid] = sumx; sRed[4 + wid] = sumy; }
    __syncthreads();
    if (tid == 0) {
        float fx = sRed[0] + sRed[1] + sRed[2] + sRed[3];
        float fy = sRed[4] + sRed[5] + sRed[6] + sRed[7];
        atomicAdd(&slot[0], (unsigned long long)((double)fx * SCFP + 0.5));
        atomicAdd(&slot[1], (unsigned long long)((double)fy * SCFP + 0.5));
    }
}

// one field: f4 strip load (36 rows x 40 cols, halo 2/4) -> c-stage (Sobel corr)
// -> d-stage (second corr) producing dK[4] and center phi pv[4] per thread
__device__ __forceinline__ void field_pass(
        const float* __restrict__ phiIn, size_t base, int x0, int y0,
        int tid, int cgi, int rr,
        float (*sP)[44], float (*sC1)[35], float (*sC2)[35],
        float dK[4], float pv[4])
{
    // load: 360 tasks of float4 (36 rows x 10 groups)
#pragma unroll
    for (int k = 0; k < 2; ++k) {
        int task = tid + k * 256;
        if (task < 360) {
            int u = (task * 205) >> 11;          // task/10 exact for task<360
            int v = task - 10 * u;
            int gy = y0 - 2 + u, gx = x0 - 4 + 4 * v;
            float4 val = make_float4(0.f, 0.f, 0.f, 0.f);
            if ((unsigned)gy < 256u && (unsigned)gx < 256u)
                val = *(const float4*)(phiIn + base + (size_t)gy * Wd + gx);
            *(float4*)&sP[u][4 * v] = val;
        }
    }
    __syncthreads();
    // c-stage: 34x34 region (halo 1), scalar
#pragma unroll
    for (int k = 0; k < 5; ++k) {
        int task = tid + k * 256;
        if (task < 1156) {
            int a = (task * 1929) >> 16;         // task/34 exact for task<1156
            int b = task - 34 * a;
            int gy = y0 - 1 + a, gx = x0 - 1 + b;
            float c1 = 0.f, c2 = 0.f;
            if ((unsigned)gy < 256u && (unsigned)gx < 256u) {
                float tl = sP[a][b + 2],     tc = sP[a][b + 3],      tr = sP[a][b + 4];
                float ml = sP[a + 1][b + 2],                         mr = sP[a + 1][b + 4];
                float bl = sP[a + 2][b + 2], bc_ = sP[a + 2][b + 3], br = sP[a + 2][b + 4];
                c1 = 0.125f * (tr - tl) + 0.25f * (mr - ml) + 0.125f * (br - bl);
                c2 = 0.125f * (bl - tl) + 0.25f * (bc_ - tc) + 0.125f * (br - tr);
            }
            sC1[a][b] = c1; sC2[a][b] = c2;
        }
    }
    __syncthreads();
    // d-stage: thread -> (row rr, cols 4cgi..4cgi+3)
    {
        float4 p4 = *(float4*)&sP[rr + 2][4 * cgi + 4];
        pv[0] = p4.x; pv[1] = p4.y; pv[2] = p4.z; pv[3] = p4.w;
#pragma unroll
        for (int j = 0; j < 4; ++j) {
            int b0 = 4 * cgi + j;
            dK[j] = 0.125f * (sC1[rr][b0 + 2]     - sC1[rr][b0])
                  + 0.25f  * (sC1[rr + 1][b0 + 2] - sC1[rr + 1][b0])
                  + 0.125f * (sC1[rr + 2][b0 + 2] - sC1[rr + 2][b0])
                  + 0.125f * (sC2[rr + 2][b0]     - sC2[rr][b0])
                  + 0.25f  * (sC2[rr + 2][b0 + 1] - sC2[rr][b0 + 1])
                  + 0.125f * (sC2[rr + 2][b0 + 2] - sC2[rr][b0 + 2]);
        }
    }
    __syncthreads();
}

__global__ __launch_bounds__(256)
void k_step(const float* __restrict__ S,
            const float* __restrict__ pxin, const float* __restrict__ pyin,
            float* __restrict__ pxout, float* __restrict__ pyout,
            unsigned* __restrict__ mP, unsigned* __restrict__ vP,
            const unsigned long long* __restrict__ accPrev,
            unsigned long long* __restrict__ accCur,
            float a_step, float inv_bc2, int write_sp, float* __restrict__ sp)
{
    __shared__ __align__(16) float sP[36][44];
    __shared__ float sC1[34][35];
    __shared__ float sC2[34][35];
    __shared__ float sRed[8];

    const int tid = threadIdx.x;
    const int cgi = tid & 7;
    const int rr  = tid >> 3;
    const int x0  = blockIdx.x * 32;
    const int y0  = blockIdx.y * 32;
    const size_t base = (size_t)blockIdx.z * HWd;

    // SSB coefs: sum the previous step's 64 fixed-point slot pairs (uniform
    // scalar loads, integer adds -> order-independent, deterministic)
    unsigned long long axu = 0ull, ayu = 0ull;
#pragma unroll 8
    for (int i = 0; i < NSLOT; ++i) { axu += accPrev[i * 8]; ayu += accPrev[i * 8 + 1]; }
    double axd = (double)axu * (1.0 / SCFP);
    double ayd = (double)ayu * (1.0 / SCFP);
    double nxd = sqrt(axd), nyd = sqrt(ayd);
    double pnd = nxd + nyd;
    double uu = pnd * pnd - 0.01;                 // V^2
    double sg = (uu > 0.0) ? 1.0 : ((uu < 0.0) ? -1.0 : 0.0);
    const float coefx = (float)(0.2 * sg * pnd / nxd);
    const float coefy = (float)(0.2 * sg * pnd / nyd);

    float dKx[4], dKy[4], pxa[4], pya[4];
    field_pass(pxin, base, x0, y0, tid, cgi, rr, sP, sC1, sC2, dKx, pxa);
    field_pass(pyin, base, x0, y0, tid, cgi, rr, sP, sC1, sC2, dKy, pya);

    // ---- pointwise grad + Adam (state packed bf16; all traffic 16B/thread) ----
    const int gy = y0 + rr;
    const int gxb = x0 + 4 * cgi;
    const size_t idx = base + (size_t)gy * Wd + gxb;

    float4 s4 = *(const float4*)(S + idx);
    float sa[4] = {s4.x, s4.y, s4.z, s4.w};
    const bool ok_e = (gxb + 4 < Wd);
    float sE = ok_e ? S[idx + 4] : 0.f;
    const bool ok_d = (gy + 1 < Hd);
    float4 sD = ok_d ? *(const float4*)(S + idx + Wd) : make_float4(0.f, 0.f, 0.f, 0.f);
    float sdv[4] = {sD.x, sD.y, sD.z, sD.w};

    uint4 mp4 = *(const uint4*)(mP + idx);
    uint4 vp4 = *(const uint4*)(vP + idx);
    unsigned mpv[4] = {mp4.x, mp4.y, mp4.z, mp4.w};
    unsigned vpv[4] = {vp4.x, vp4.y, vp4.z, vp4.w};

    unsigned nmw[4], nvw[4];
    float npx[4], npy[4], spv[4];
    float sumx = 0.f, sumy = 0.f;
#pragma unroll
    for (int j = 0; j < 4; ++j) {
        float dx_ = (j < 3) ? (sa[j + 1] - sa[j]) : (ok_e ? (sE - sa[3]) : 0.f);
        float dy_ = ok_d ? (sdv[j] - sa[j]) : 0.f;
        float R = pxa[j] * dx_ + pya[j] * dy_;
        float vmc = (sa[j] < 0.05f) ? C_VOID : 0.f;
        float gx_ = C_COUP * R * dx_ - C_KIN * dKx[j] + (coefx + vmc) * pxa[j];
        float gy_ = C_COUP * R * dy_ - C_KIN * dKy[j] + (coefy + vmc) * pya[j];

        float m1 = 0.9f * bflo(mpv[j]) + 0.1f * gx_;
        float v1 = 0.999f * bflo(vpv[j]) + 0.001f * gx_ * gx_;
        npx[j] = pxa[j] - a_step * m1 / (sqrtf(v1 * inv_bc2) + 1e-8f);
        sumx += npx[j] * npx[j];

        float m2 = 0.9f * bfhi(mpv[j]) + 0.1f * gy_;
        float v2 = 0.999f * bfhi(vpv[j]) + 0.001f * gy_ * gy_;
        npy[j] = pya[j] - a_step * m2 / (sqrtf(v2 * inv_bc2) + 1e-8f);
        sumy += npy[j] * npy[j];

        nmw[j] = bfpack(m1, m2);
        nvw[j] = bfpack(v1, v2);
        spv[j] = sa[j] + R;
    }
    *(uint4*)(mP + idx)     = make_uint4(nmw[0], nmw[1], nmw[2], nmw[3]);
    *(uint4*)(vP + idx)     = make_uint4(nvw[0], nvw[1], nvw[2], nvw[3]);
    *(float4*)(pxout + idx) = make_float4(npx[0], npx[1], npx[2], npx[3]);
    *(float4*)(pyout + idx) = make_float4(npy[0], npy[1], npy[2], npy[3]);
    if (write_sp)
        *(float4*)(sp + idx) = make_float4(spv[0], spv[1], spv[2], spv[3]);

    block_acc(sumx, sumy, sRed, accCur + (size_t)blockIdx.z * 8);
}

__global__ __launch_bounds__(256)
void k_init(const float* __restrict__ px0, const float* __restrict__ py0,
            float* __restrict__ pxA, float* __restrict__ pyA,
            unsigned* __restrict__ mP, unsigned* __restrict__ vP,
            unsigned long long* __restrict__ acc0)
{
    __shared__ float sRed[8];
    const int tid = threadIdx.x;
    const size_t base = (size_t)blockIdx.x * 2048;
    uint4 z4 = make_uint4(0u, 0u, 0u, 0u);
    float sx = 0.f, sy = 0.f;
#pragma unroll
    for (int k = 0; k < 2; ++k) {
        size_t idx = base + (size_t)(k * 1024 + tid * 4);
        float4 x = *(const float4*)(px0 + idx);
        float4 y = *(const float4*)(py0 + idx);
        *(float4*)(pxA + idx) = x;  *(float4*)(pyA + idx) = y;
        *(uint4*)(mP + idx) = z4;   *(uint4*)(vP + idx) = z4;
        sx += x.x * x.x + x.y * x.y + x.z * x.z + x.w * x.w;
        sy += y.x * y.x + y.y * y.y + y.z * y.z + y.w * y.w;
    }
    block_acc(sx, sy, sRed, acc0 + (size_t)(blockIdx.x & (NSLOT - 1)) * 8);
}

extern "C" void kernel_launch(void* const* d_in, const int* in_sizes, int n_in,
                              void* d_out, int out_size, void* d_ws, size_t ws_size,
                              hipStream_t stream) {
    (void)in_sizes; (void)n_in; (void)out_size; (void)ws_size;
    const float* S   = (const float*)d_in[0];
    const float* px0 = (const float*)d_in[1];
    const float* py0 = (const float*)d_in[2];
    float* out = (float*)d_out;

    float* sp     = out;                      // slot 0: Sp
    float* outA_x = out + (size_t)NTOT;       // slot 1: phi_x post
    float* outA_y = out + 2 * (size_t)NTOT;   // slot 2: phi_y post
    float* outB_x = out + 3 * (size_t)NTOT;   // slot 3: phi_x pre
    float* outB_y = out + 4 * (size_t)NTOT;   // slot 4: phi_y pre

    unsigned* ws = (unsigned*)d_ws;
    unsigned* mP = ws;                        // packed (bf16 mx, bf16 my), 16 MB
    unsigned* vP = mP + (size_t)NTOT;         // packed (bf16 vx, bf16 vy), 16 MB
    // acc: [NACC][NSLOT][8] ull — each slot pair on its own 64B line
    unsigned long long* acc = (unsigned long long*)(vP + (size_t)NTOT);

    hipMemsetAsync(acc, 0, (size_t)NACC * NSLOT * 8 * sizeof(unsigned long long), stream);

    dim3 grid(8, 8, 64), blk(256, 1, 1);

    k_init<<<2048, 256, 0, stream>>>(px0, py0, outA_x, outA_y, mP, vP, acc);

    for (int t = 1; t <= 50; ++t) {
        double bc1 = 1.0 - pow(0.9, (double)t);
        double bc2 = 1.0 - pow(0.999, (double)t);
        float a_step = (float)(0.05 / bc1);
        float inv_bc2 = (float)(1.0 / bc2);
        bool odd = (t & 1) != 0;
        const float* pix = odd ? outA_x : outB_x;
        const float* piy = odd ? outA_y : outB_y;
        float* pox = odd ? outB_x : outA_x;
        float* poy = odd ? outB_y : outA_y;
        k_step<<<grid, blk, 0, stream>>>(S, pix, piy, pox, poy,
                                         mP, vP,
                                         acc + (size_t)(t - 1) * NSLOT * 8,
                                         acc + (size_t)t * NSLOT * 8,
                                         a_step, inv_bc2, (t == 50) ? 1 : 0, sp);
    }
}

// Round 7
// 2192.176 us; speedup vs baseline: 6.4042x; 1.0149x over previous
//
#include <hip/hip_runtime.h>
#include <hip/hip_fp16.h>
#include <cmath>

#define Wd 256
#define Hd 256
#define HWd 65536
#define NTOT 4194304
#define NACC 51
#define NSLOT 64                     // atomic slots per step, one 64B line each

#define C_COUP (2.0f / 4194304.0f)   // 2*COUPLING/N
#define C_KIN  (0.2f / 4194304.0f)   // 2*ALPHA/N
#define C_VOID 0.0098f               // 2*GAMMA^2
#define SCFP 68719476736.0           // 2^36 fixed-point scale

// ---- packed bf16 pair helpers for Adam state (RNE, deterministic) ----
__device__ __forceinline__ float bflo(unsigned w) { return __uint_as_float(w << 16); }
__device__ __forceinline__ float bfhi(unsigned w) { return __uint_as_float(w & 0xFFFF0000u); }
__device__ __forceinline__ unsigned bfpack(float lo, float hi) {
    unsigned ul = __float_as_uint(lo);
    ul = (ul + 0x7FFFu + ((ul >> 16) & 1u)) >> 16;
    unsigned uh = __float_as_uint(hi);
    uh = (uh + 0x7FFFu + ((uh >> 16) & 1u)) & 0xFFFF0000u;
    return (ul & 0xFFFFu) | uh;
}

// ---- packed fp16 pair helpers for phi ping-pong (RNE, deterministic) ----
__device__ __forceinline__ float2 unpackh2(unsigned w) {
    __half2 h = *(__half2*)&w;
    return __half22float2(h);
}
__device__ __forceinline__ unsigned packh2(float a, float b) {
    __half2 h = __floats2half2_rn(a, b);
    return *(unsigned*)&h;
}

// block-level reduce of phi^2 sums -> one deterministic fixed-point atomic pair
__device__ __forceinline__ void block_acc(float sumx, float sumy, float* sRed,
                                          unsigned long long* slot) {
    for (int off = 32; off > 0; off >>= 1) {
        sumx += __shfl_down(sumx, off, 64);
        sumy += __shfl_down(sumy, off, 64);
    }
    const int tid = threadIdx.x;
    const int wid = tid >> 6;
    if ((tid & 63) == 0) { sRed[wid] = sumx; sRed[4 + wid] = sumy; }
    __syncthreads();
    if (tid == 0) {
        float fx = sRed[0] + sRed[1] + sRed[2] + sRed[3];
        float fy = sRed[4] + sRed[5] + sRed[6] + sRed[7];
        atomicAdd(&slot[0], (unsigned long long)((double)fx * SCFP + 0.5));
        atomicAdd(&slot[1], (unsigned long long)((double)fy * SCFP + 0.5));
    }
}

// mode: 0 = write packed only; 1 = packed + f32 outs (step 49);
//       2 = f32 outs + sp, no packed (step 50)
__global__ __launch_bounds__(256)
void k_step(const float* __restrict__ S,
            const unsigned* __restrict__ pPrev, unsigned* __restrict__ pCur,
            unsigned* __restrict__ mP, unsigned* __restrict__ vP,
            const unsigned long long* __restrict__ accPrev,
            unsigned long long* __restrict__ accCur,
            float a_step, float inv_bc2, int mode,
            float* __restrict__ outx, float* __restrict__ outy,
            float* __restrict__ sp)
{
    __shared__ __align__(16) float sPx[36][44];
    __shared__ __align__(16) float sPy[36][44];
    __shared__ float sC1x[34][35], sC2x[34][35];
    __shared__ float sC1y[34][35], sC2y[34][35];
    __shared__ float sRed[8];

    const int tid = threadIdx.x;
    const int cgi = tid & 7;
    const int rr  = tid >> 3;
    const int x0  = blockIdx.x * 32;
    const int y0  = blockIdx.y * 32;
    const size_t base = (size_t)blockIdx.z * HWd;

    // SSB coefs: sum previous step's 64 fixed-point slot pairs (order-independent)
    unsigned long long axu = 0ull, ayu = 0ull;
#pragma unroll 8
    for (int i = 0; i < NSLOT; ++i) { axu += accPrev[i * 8]; ayu += accPrev[i * 8 + 1]; }
    double axd = (double)axu * (1.0 / SCFP);
    double ayd = (double)ayu * (1.0 / SCFP);
    double nxd = sqrt(axd), nyd = sqrt(ayd);
    double pnd = nxd + nyd;
    double uu = pnd * pnd - 0.01;                 // V^2
    double sg = (uu > 0.0) ? 1.0 : ((uu < 0.0) ? -1.0 : 0.0);
    const float coefx = (float)(0.2 * sg * pnd / nxd);
    const float coefy = (float)(0.2 * sg * pnd / nyd);

    // ---- strip load, both fields from one packed array: 360 uint4 tasks ----
#pragma unroll
    for (int k = 0; k < 2; ++k) {
        int task = tid + (k << 8);
        if (task < 360) {
            int u = (task * 205) >> 11;          // task/10 exact for task<360
            int v = task - 10 * u;
            int gy = y0 - 2 + u, gx = x0 - 4 + 4 * v;
            uint4 w = make_uint4(0u, 0u, 0u, 0u);
            if ((unsigned)gy < 256u && (unsigned)gx < 256u)
                w = *(const uint4*)(pPrev + base + (size_t)gy * Wd + gx);
            float2 a = unpackh2(w.x), b = unpackh2(w.y);
            float2 c = unpackh2(w.z), d = unpackh2(w.w);
            *(float4*)&sPx[u][4 * v] = make_float4(a.x, b.x, c.x, d.x);
            *(float4*)&sPy[u][4 * v] = make_float4(a.y, b.y, c.y, d.y);
        }
    }
    __syncthreads();

    // ---- c-stage, both fields: 2x1156 scalar tasks ----
#pragma unroll
    for (int k = 0; k < 10; ++k) {
        int task = tid + (k << 8);
        if (task < 2312) {
            int f = (task >= 1156) ? 1 : 0;
            int r = task - (f ? 1156 : 0);
            int a = (r * 1929) >> 16;            // r/34 exact for r<1156
            int bb = r - 34 * a;
            int gyy = y0 - 1 + a, gxx = x0 - 1 + bb;
            float c1 = 0.f, c2 = 0.f;
            if ((unsigned)gyy < 256u && (unsigned)gxx < 256u) {
                float (*sP)[44] = f ? sPy : sPx;
                float tl = sP[a][bb + 2],     tc = sP[a][bb + 3],      tr = sP[a][bb + 4];
                float ml = sP[a + 1][bb + 2],                          mr = sP[a + 1][bb + 4];
                float bl = sP[a + 2][bb + 2], bc_ = sP[a + 2][bb + 3], br = sP[a + 2][bb + 4];
                c1 = 0.125f * (tr - tl) + 0.25f * (mr - ml) + 0.125f * (br - bl);
                c2 = 0.125f * (bl - tl) + 0.25f * (bc_ - tc) + 0.125f * (br - tr);
            }
            (f ? sC1y : sC1x)[a][bb] = c1;
            (f ? sC2y : sC2x)[a][bb] = c2;
        }
    }
    __syncthreads();

    // ---- d-stage: second Sobel corr + center phi, both fields ----
    float dKx[4], dKy[4], pxa[4], pya[4];
    {
        float4 p4 = *(float4*)&sPx[rr + 2][4 * cgi + 4];
        pxa[0] = p4.x; pxa[1] = p4.y; pxa[2] = p4.z; pxa[3] = p4.w;
        float4 q4 = *(float4*)&sPy[rr + 2][4 * cgi + 4];
        pya[0] = q4.x; pya[1] = q4.y; pya[2] = q4.z; pya[3] = q4.w;
#pragma unroll
        for (int j = 0; j < 4; ++j) {
            int b0 = 4 * cgi + j;
            dKx[j] = 0.125f * (sC1x[rr][b0 + 2]     - sC1x[rr][b0])
                   + 0.25f  * (sC1x[rr + 1][b0 + 2] - sC1x[rr + 1][b0])
                   + 0.125f * (sC1x[rr + 2][b0 + 2] - sC1x[rr + 2][b0])
                   + 0.125f * (sC2x[rr + 2][b0]     - sC2x[rr][b0])
                   + 0.25f  * (sC2x[rr + 2][b0 + 1] - sC2x[rr][b0 + 1])
                   + 0.125f * (sC2x[rr + 2][b0 + 2] - sC2x[rr][b0 + 2]);
            dKy[j] = 0.125f * (sC1y[rr][b0 + 2]     - sC1y[rr][b0])
                   + 0.25f  * (sC1y[rr + 1][b0 + 2] - sC1y[rr + 1][b0])
                   + 0.125f * (sC1y[rr + 2][b0 + 2] - sC1y[rr + 2][b0])
                   + 0.125f * (sC2y[rr + 2][b0]     - sC2y[rr][b0])
                   + 0.25f  * (sC2y[rr + 2][b0 + 1] - sC2y[rr][b0 + 1])
                   + 0.125f * (sC2y[rr + 2][b0 + 2] - sC2y[rr][b0 + 2]);
        }
    }

    // ---- pointwise grad + Adam (state packed bf16, phi packed fp16) ----
    const int gy = y0 + rr;
    const int gxb = x0 + 4 * cgi;
    const size_t idx = base + (size_t)gy * Wd + gxb;

    float4 s4 = *(const float4*)(S + idx);
    float sa[4] = {s4.x, s4.y, s4.z, s4.w};
    const bool ok_e = (gxb + 4 < Wd);
    float sE = ok_e ? S[idx + 4] : 0.f;
    const bool ok_d = (gy + 1 < Hd);
    float4 sD = ok_d ? *(const float4*)(S + idx + Wd) : make_float4(0.f, 0.f, 0.f, 0.f);
    float sdv[4] = {sD.x, sD.y, sD.z, sD.w};

    uint4 mp4 = *(const uint4*)(mP + idx);
    uint4 vp4 = *(const uint4*)(vP + idx);
    unsigned mpv[4] = {mp4.x, mp4.y, mp4.z, mp4.w};
    unsigned vpv[4] = {vp4.x, vp4.y, vp4.z, vp4.w};

    unsigned nmw[4], nvw[4], npk[4];
    float npx[4], npy[4], spv[4];
    float sumx = 0.f, sumy = 0.f;
#pragma unroll
    for (int j = 0; j < 4; ++j) {
        float dx_ = (j < 3) ? (sa[j + 1] - sa[j]) : (ok_e ? (sE - sa[3]) : 0.f);
        float dy_ = ok_d ? (sdv[j] - sa[j]) : 0.f;
        float R = pxa[j] * dx_ + pya[j] * dy_;
        float vmc = (sa[j] < 0.05f) ? C_VOID : 0.f;
        float gx_ = C_COUP * R * dx_ - C_KIN * dKx[j] + (coefx + vmc) * pxa[j];
        float gy_ = C_COUP * R * dy_ - C_KIN * dKy[j] + (coefy + vmc) * pya[j];

        float m1 = 0.9f * bflo(mpv[j]) + 0.1f * gx_;
        float v1 = 0.999f * bflo(vpv[j]) + 0.001f * gx_ * gx_;
        npx[j] = pxa[j] - a_step * m1 / (sqrtf(v1 * inv_bc2) + 1e-8f);
        sumx += npx[j] * npx[j];

        float m2 = 0.9f * bfhi(mpv[j]) + 0.1f * gy_;
        float v2 = 0.999f * bfhi(vpv[j]) + 0.001f * gy_ * gy_;
        npy[j] = pya[j] - a_step * m2 / (sqrtf(v2 * inv_bc2) + 1e-8f);
        sumy += npy[j] * npy[j];

        nmw[j] = bfpack(m1, m2);
        nvw[j] = bfpack(v1, v2);
        npk[j] = packh2(npx[j], npy[j]);
        spv[j] = sa[j] + R;
    }
    *(uint4*)(mP + idx) = make_uint4(nmw[0], nmw[1], nmw[2], nmw[3]);
    *(uint4*)(vP + idx) = make_uint4(nvw[0], nvw[1], nvw[2], nvw[3]);
    if (mode != 2)
        *(uint4*)(pCur + idx) = make_uint4(npk[0], npk[1], npk[2], npk[3]);
    if (mode != 0) {
        *(float4*)(outx + idx) = make_float4(npx[0], npx[1], npx[2], npx[3]);
        *(float4*)(outy + idx) = make_float4(npy[0], npy[1], npy[2], npy[3]);
    }
    if (mode == 2)
        *(float4*)(sp + idx) = make_float4(spv[0], spv[1], spv[2], spv[3]);

    block_acc(sumx, sumy, sRed, accCur + (size_t)blockIdx.z * 8);
}

__global__ __launch_bounds__(256)
void k_init(const float* __restrict__ px0, const float* __restrict__ py0,
            unsigned* __restrict__ p0,
            unsigned* __restrict__ mP, unsigned* __restrict__ vP,
            unsigned long long* __restrict__ acc0)
{
    __shared__ float sRed[8];
    const int tid = threadIdx.x;
    const size_t base = (size_t)blockIdx.x * 2048;
    uint4 z4 = make_uint4(0u, 0u, 0u, 0u);
    float sx = 0.f, sy = 0.f;
#pragma unroll
    for (int k = 0; k < 2; ++k) {
        size_t idx = base + (size_t)(k * 1024 + tid * 4);
        float4 x = *(const float4*)(px0 + idx);
        float4 y = *(const float4*)(py0 + idx);
        *(uint4*)(p0 + idx) = make_uint4(packh2(x.x, y.x), packh2(x.y, y.y),
                                         packh2(x.z, y.z), packh2(x.w, y.w));
        *(uint4*)(mP + idx) = z4;   *(uint4*)(vP + idx) = z4;
        sx += x.x * x.x + x.y * x.y + x.z * x.z + x.w * x.w;
        sy += y.x * y.x + y.y * y.y + y.z * y.z + y.w * y.w;
    }
    block_acc(sx, sy, sRed, acc0 + (size_t)(blockIdx.x & (NSLOT - 1)) * 8);
}

extern "C" void kernel_launch(void* const* d_in, const int* in_sizes, int n_in,
                              void* d_out, int out_size, void* d_ws, size_t ws_size,
                              hipStream_t stream) {
    (void)in_sizes; (void)n_in; (void)out_size; (void)ws_size;
    const float* S   = (const float*)d_in[0];
    const float* px0 = (const float*)d_in[1];
    const float* py0 = (const float*)d_in[2];
    float* out = (float*)d_out;

    float* sp     = out;                      // slot 0: Sp
    float* outA_x = out + (size_t)NTOT;       // slot 1: phi_x post
    float* outA_y = out + 2 * (size_t)NTOT;   // slot 2: phi_y post
    float* outB_x = out + 3 * (size_t)NTOT;   // slot 3: phi_x pre
    float* outB_y = out + 4 * (size_t)NTOT;   // slot 4: phi_y pre

    unsigned* ws = (unsigned*)d_ws;
    unsigned* p0 = ws;                        // packed (fp16 phix, fp16 phiy), 16 MB
    unsigned* p1 = p0 + (size_t)NTOT;         // ping-pong partner, 16 MB
    unsigned* mP = p1 + (size_t)NTOT;         // packed (bf16 mx, bf16 my), 16 MB
    unsigned* vP = mP + (size_t)NTOT;         // packed (bf16 vx, bf16 vy), 16 MB
    unsigned long long* acc = (unsigned long long*)(vP + (size_t)NTOT);  // [NACC][NSLOT][8]

    hipMemsetAsync(acc, 0, (size_t)NACC * NSLOT * 8 * sizeof(unsigned long long), stream);

    dim3 grid(8, 8, 64), blk(256, 1, 1);

    k_init<<<2048, 256, 0, stream>>>(px0, py0, p0, mP, vP, acc);

    for (int t = 1; t <= 50; ++t) {
        double bc1 = 1.0 - pow(0.9, (double)t);
        double bc2 = 1.0 - pow(0.999, (double)t);
        float a_step = (float)(0.05 / bc1);
        float inv_bc2 = (float)(1.0 / bc2);
        bool odd = (t & 1) != 0;
        const unsigned* pPrev = odd ? p0 : p1;
        unsigned* pCur = odd ? p1 : p0;
        int mode = (t == 49) ? 1 : ((t == 50) ? 2 : 0);
        float* ox = (t == 50) ? outA_x : outB_x;   // mode1 -> pre slots, mode2 -> post
        float* oy = (t == 50) ? outA_y : outB_y;
        k_step<<<grid, blk, 0, stream>>>(S, pPrev, pCur, mP, vP,
                                         acc + (size_t)(t - 1) * NSLOT * 8,
                                         acc + (size_t)t * NSLOT * 8,
                                         a_step, inv_bc2, mode, ox, oy, sp);
    }
}

// Round 8
// 2066.364 us; speedup vs baseline: 6.7942x; 1.0609x over previous
//
#include <hip/hip_runtime.h>
#include <hip/hip_fp16.h>
#include <cmath>

#define Wd 256
#define Hd 256
#define HWd 65536
#define NTOT 4194304
#define NACC 51
#define NSLOT 64                     // atomic slots per step, one 64B line each

#define C_COUP (2.0f / 4194304.0f)   // 2*COUPLING/N
#define C_KIN  (0.2f / 4194304.0f)   // 2*ALPHA/N
#define C_VOID 0.0098f               // 2*GAMMA^2
#define SCFP 68719476736.0           // 2^36 fixed-point scale

// ---- packed bf16 pair helpers for Adam state (RNE, deterministic) ----
__device__ __forceinline__ float bflo(unsigned w) { return __uint_as_float(w << 16); }
__device__ __forceinline__ float bfhi(unsigned w) { return __uint_as_float(w & 0xFFFF0000u); }
__device__ __forceinline__ unsigned bfpack(float lo, float hi) {
    unsigned ul = __float_as_uint(lo);
    ul = (ul + 0x7FFFu + ((ul >> 16) & 1u)) >> 16;
    unsigned uh = __float_as_uint(hi);
    uh = (uh + 0x7FFFu + ((uh >> 16) & 1u)) & 0xFFFF0000u;
    return (ul & 0xFFFFu) | uh;
}

// ---- packed fp16 pair helpers for phi ping-pong (RNE, deterministic) ----
__device__ __forceinline__ float2 unpackh2(unsigned w) {
    __half2 h = *(__half2*)&w;
    return __half22float2(h);
}
__device__ __forceinline__ unsigned packh2(float a, float b) {
    __half2 h = __floats2half2_rn(a, b);
    return *(unsigned*)&h;
}

// block-level reduce of phi^2 sums -> one deterministic fixed-point atomic pair
__device__ __forceinline__ void block_acc(float sumx, float sumy, float* sRed,
                                          unsigned long long* slot) {
    for (int off = 32; off > 0; off >>= 1) {
        sumx += __shfl_down(sumx, off, 64);
        sumy += __shfl_down(sumy, off, 64);
    }
    const int tid = threadIdx.x;
    const int wid = tid >> 6;
    if ((tid & 63) == 0) { sRed[wid] = sumx; sRed[4 + wid] = sumy; }
    __syncthreads();
    if (tid == 0) {
        float fx = sRed[0] + sRed[1] + sRed[2] + sRed[3];
        float fy = sRed[4] + sRed[5] + sRed[6] + sRed[7];
        atomicAdd(&slot[0], (unsigned long long)((double)fx * SCFP + 0.5));
        atomicAdd(&slot[1], (unsigned long long)((double)fy * SCFP + 0.5));
    }
}

// mode: 0 = write packed only; 1 = packed + f32 outs (step 49);
//       2 = f32 outs + sp, no packed (step 50)
__global__ __launch_bounds__(256)
void k_step(const float* __restrict__ S,
            const unsigned* __restrict__ pPrev, unsigned* __restrict__ pCur,
            unsigned* __restrict__ mP, unsigned* __restrict__ vP,
            const unsigned long long* __restrict__ accPrev,
            unsigned long long* __restrict__ accCur,
            float a_step, float inv_bc2, int mode,
            float* __restrict__ outx, float* __restrict__ outy,
            float* __restrict__ sp)
{
    // sP: phi strip, col cc_p = local_col + 4 (local cols -4..39)
    __shared__ __align__(16) float sPx[36][44];
    __shared__ __align__(16) float sPy[36][44];
    // sC: Sobel-corr intermediates, row a = grid row y0-1+a (a 0..33),
    //     col cc = local_col + 3 (local cols -3..32), stride 36
    __shared__ __align__(16) float sC1x[34][36], sC2x[34][36];
    __shared__ __align__(16) float sC1y[34][36], sC2y[34][36];
    __shared__ float sRed[8];

    const int tid = threadIdx.x;
    const int cgi = tid & 7;
    const int rr  = tid >> 3;
    const int x0  = blockIdx.x * 32;
    const int y0  = blockIdx.y * 32;
    const size_t base = (size_t)blockIdx.z * HWd;

    // SSB coefs: sum previous step's 64 fixed-point slot pairs (order-independent)
    unsigned long long axu = 0ull, ayu = 0ull;
#pragma unroll 8
    for (int i = 0; i < NSLOT; ++i) { axu += accPrev[i * 8]; ayu += accPrev[i * 8 + 1]; }
    double axd = (double)axu * (1.0 / SCFP);
    double ayd = (double)ayu * (1.0 / SCFP);
    double nxd = sqrt(axd), nyd = sqrt(ayd);
    double pnd = nxd + nyd;
    double uu = pnd * pnd - 0.01;                 // V^2
    double sg = (uu > 0.0) ? 1.0 : ((uu < 0.0) ? -1.0 : 0.0);
    const float coefx = (float)(0.2 * sg * pnd / nxd);
    const float coefy = (float)(0.2 * sg * pnd / nyd);

    // ---- strip load, both fields from one packed array: 360 uint4 tasks ----
#pragma unroll
    for (int k = 0; k < 2; ++k) {
        int task = tid + (k << 8);
        if (task < 360) {
            int u = (task * 205) >> 11;          // task/10 exact for task<360
            int v = task - 10 * u;
            int gy = y0 - 2 + u, gx = x0 - 4 + 4 * v;
            uint4 w = make_uint4(0u, 0u, 0u, 0u);
            if ((unsigned)gy < 256u && (unsigned)gx < 256u)
                w = *(const uint4*)(pPrev + base + (size_t)gy * Wd + gx);
            float2 a = unpackh2(w.x), b = unpackh2(w.y);
            float2 c = unpackh2(w.z), d = unpackh2(w.w);
            *(float4*)&sPx[u][4 * v] = make_float4(a.x, b.x, c.x, d.x);
            *(float4*)&sPy[u][4 * v] = make_float4(a.y, b.y, c.y, d.y);
        }
    }
    __syncthreads();

    // ---- c-stage, vectorized: 612 float4 tasks (34 rows x 9 groups x 2 fields) ----
#pragma unroll
    for (int k = 0; k < 3; ++k) {
        int task = tid + (k << 8);
        if (task < 612) {
            int f = (task >= 306) ? 1 : 0;
            int r = task - (f ? 306 : 0);
            int a = (r * 57) >> 9;               // r/9 exact for r<306
            int v = r - 9 * a;
            int gyy = y0 - 1 + a;                // c row
            int gl0 = 4 * v - 3;                 // first local col of this group
            float4 c1o = make_float4(0.f, 0.f, 0.f, 0.f);
            float4 c2o = make_float4(0.f, 0.f, 0.f, 0.f);
            if ((unsigned)gyy < 256u) {
                float (*sP)[44] = f ? sPy : sPx;
                // phi window: local cols gl0-1 .. gl0+4 -> cc_p 4v .. 4v+5
                float4 At = *(float4*)&sP[a][4 * v];
                float4 Bt = *(float4*)&sP[a][4 * v + 4];
                float4 Am = *(float4*)&sP[a + 1][4 * v];
                float4 Bm = *(float4*)&sP[a + 1][4 * v + 4];
                float4 Ab = *(float4*)&sP[a + 2][4 * v];
                float4 Bb = *(float4*)&sP[a + 2][4 * v + 4];
                float wt[6] = {At.x, At.y, At.z, At.w, Bt.x, Bt.y};
                float wm[6] = {Am.x, Am.y, Am.z, Am.w, Bm.x, Bm.y};
                float wb[6] = {Ab.x, Ab.y, Ab.z, Ab.w, Bb.x, Bb.y};
                float c1v[4], c2v[4];
#pragma unroll
                for (int jj = 0; jj < 4; ++jj) {
                    float c1 = 0.125f * ((wt[jj + 2] - wt[jj]) + (wb[jj + 2] - wb[jj]))
                             + 0.25f  * (wm[jj + 2] - wm[jj]);
                    float c2 = 0.125f * ((wb[jj] - wt[jj]) + (wb[jj + 2] - wt[jj + 2]))
                             + 0.25f  * (wb[jj + 1] - wt[jj + 1]);
                    bool okc = (unsigned)(x0 + gl0 + jj) < 256u;
                    c1v[jj] = okc ? c1 : 0.f;
                    c2v[jj] = okc ? c2 : 0.f;
                }
                c1o = make_float4(c1v[0], c1v[1], c1v[2], c1v[3]);
                c2o = make_float4(c2v[0], c2v[1], c2v[2], c2v[3]);
            }
            *(float4*)&(f ? sC1y : sC1x)[a][4 * v] = c1o;
            *(float4*)&(f ? sC2y : sC2x)[a][4 * v] = c2o;
        }
    }
    __syncthreads();

    // ---- d-stage, vectorized: second Sobel corr + center phi ----
    float dKx[4], dKy[4], pxa[4], pya[4];
    {
        float4 p4 = *(float4*)&sPx[rr + 2][4 * cgi + 4];
        pxa[0] = p4.x; pxa[1] = p4.y; pxa[2] = p4.z; pxa[3] = p4.w;
        float4 q4 = *(float4*)&sPy[rr + 2][4 * cgi + 4];
        pya[0] = q4.x; pya[1] = q4.y; pya[2] = q4.z; pya[3] = q4.w;
        const int cb = 4 * cgi;
#pragma unroll
        for (int f = 0; f < 2; ++f) {
            float (*sC1)[36] = f ? sC1y : sC1x;
            float (*sC2)[36] = f ? sC2y : sC2x;
            float* dK = f ? dKy : dKx;
            float u0[8], u1[8], u2[8], t0[8], t2[8];
            *(float4*)&u0[0] = *(float4*)&sC1[rr][cb];
            *(float4*)&u0[4] = *(float4*)&sC1[rr][cb + 4];
            *(float4*)&u1[0] = *(float4*)&sC1[rr + 1][cb];
            *(float4*)&u1[4] = *(float4*)&sC1[rr + 1][cb + 4];
            *(float4*)&u2[0] = *(float4*)&sC1[rr + 2][cb];
            *(float4*)&u2[4] = *(float4*)&sC1[rr + 2][cb + 4];
            *(float4*)&t0[0] = *(float4*)&sC2[rr][cb];
            *(float4*)&t0[4] = *(float4*)&sC2[rr][cb + 4];
            *(float4*)&t2[0] = *(float4*)&sC2[rr + 2][cb];
            *(float4*)&t2[4] = *(float4*)&sC2[rr + 2][cb + 4];
#pragma unroll
            for (int jj = 0; jj < 4; ++jj) {
                dK[jj] = 0.125f * ((u0[jj + 4] - u0[jj + 2]) + (u2[jj + 4] - u2[jj + 2])
                                 + (t2[jj + 2] - t0[jj + 2]) + (t2[jj + 4] - t0[jj + 4]))
                       + 0.25f  * ((u1[jj + 4] - u1[jj + 2]) + (t2[jj + 3] - t0[jj + 3]));
            }
        }
    }

    // ---- pointwise grad + Adam (state packed bf16, phi packed fp16) ----
    const int gy = y0 + rr;
    const int gxb = x0 + 4 * cgi;
    const size_t idx = base + (size_t)gy * Wd + gxb;

    float4 s4 = *(const float4*)(S + idx);
    float sa[4] = {s4.x, s4.y, s4.z, s4.w};
    const bool ok_e = (gxb + 4 < Wd);
    float sE = ok_e ? S[idx + 4] : 0.f;
    const bool ok_d = (gy + 1 < Hd);
    float4 sD = ok_d ? *(const float4*)(S + idx + Wd) : make_float4(0.f, 0.f, 0.f, 0.f);
    float sdv[4] = {sD.x, sD.y, sD.z, sD.w};

    uint4 mp4 = *(const uint4*)(mP + idx);
    uint4 vp4 = *(const uint4*)(vP + idx);
    unsigned mpv[4] = {mp4.x, mp4.y, mp4.z, mp4.w};
    unsigned vpv[4] = {vp4.x, vp4.y, vp4.z, vp4.w};

    unsigned nmw[4], nvw[4], npk[4];
    float npx[4], npy[4], spv[4];
    float sumx = 0.f, sumy = 0.f;
#pragma unroll
    for (int j = 0; j < 4; ++j) {
        float dx_ = (j < 3) ? (sa[j + 1] - sa[j]) : (ok_e ? (sE - sa[3]) : 0.f);
        float dy_ = ok_d ? (sdv[j] - sa[j]) : 0.f;
        float R = pxa[j] * dx_ + pya[j] * dy_;
        float vmc = (sa[j] < 0.05f) ? C_VOID : 0.f;
        float gx_ = C_COUP * R * dx_ - C_KIN * dKx[j] + (coefx + vmc) * pxa[j];
        float gy_ = C_COUP * R * dy_ - C_KIN * dKy[j] + (coefy + vmc) * pya[j];

        float m1 = 0.9f * bflo(mpv[j]) + 0.1f * gx_;
        float v1 = 0.999f * bflo(vpv[j]) + 0.001f * gx_ * gx_;
        npx[j] = pxa[j] - __fdividef(a_step * m1, sqrtf(v1 * inv_bc2) + 1e-8f);
        sumx += npx[j] * npx[j];

        float m2 = 0.9f * bfhi(mpv[j]) + 0.1f * gy_;
        float v2 = 0.999f * bfhi(vpv[j]) + 0.001f * gy_ * gy_;
        npy[j] = pya[j] - __fdividef(a_step * m2, sqrtf(v2 * inv_bc2) + 1e-8f);
        sumy += npy[j] * npy[j];

        nmw[j] = bfpack(m1, m2);
        nvw[j] = bfpack(v1, v2);
        npk[j] = packh2(npx[j], npy[j]);
        spv[j] = sa[j] + R;
    }
    *(uint4*)(mP + idx) = make_uint4(nmw[0], nmw[1], nmw[2], nmw[3]);
    *(uint4*)(vP + idx) = make_uint4(nvw[0], nvw[1], nvw[2], nvw[3]);
    if (mode != 2)
        *(uint4*)(pCur + idx) = make_uint4(npk[0], npk[1], npk[2], npk[3]);
    if (mode != 0) {
        *(float4*)(outx + idx) = make_float4(npx[0], npx[1], npx[2], npx[3]);
        *(float4*)(outy + idx) = make_float4(npy[0], npy[1], npy[2], npy[3]);
    }
    if (mode == 2)
        *(float4*)(sp + idx) = make_float4(spv[0], spv[1], spv[2], spv[3]);

    block_acc(sumx, sumy, sRed, accCur + (size_t)blockIdx.z * 8);
}

__global__ __launch_bounds__(256)
void k_init(const float* __restrict__ px0, const float* __restrict__ py0,
            unsigned* __restrict__ p0,
            unsigned* __restrict__ mP, unsigned* __restrict__ vP,
            unsigned long long* __restrict__ acc0)
{
    __shared__ float sRed[8];
    const int tid = threadIdx.x;
    const size_t base = (size_t)blockIdx.x * 2048;
    uint4 z4 = make_uint4(0u, 0u, 0u, 0u);
    float sx = 0.f, sy = 0.f;
#pragma unroll
    for (int k = 0; k < 2; ++k) {
        size_t idx = base + (size_t)(k * 1024 + tid * 4);
        float4 x = *(const float4*)(px0 + idx);
        float4 y = *(const float4*)(py0 + idx);
        *(uint4*)(p0 + idx) = make_uint4(packh2(x.x, y.x), packh2(x.y, y.y),
                                         packh2(x.z, y.z), packh2(x.w, y.w));
        *(uint4*)(mP + idx) = z4;   *(uint4*)(vP + idx) = z4;
        sx += x.x * x.x + x.y * x.y + x.z * x.z + x.w * x.w;
        sy += y.x * y.x + y.y * y.y + y.z * y.z + y.w * y.w;
    }
    block_acc(sx, sy, sRed, acc0 + (size_t)(blockIdx.x & (NSLOT - 1)) * 8);
}

extern "C" void kernel_launch(void* const* d_in, const int* in_sizes, int n_in,
                              void* d_out, int out_size, void* d_ws, size_t ws_size,
                              hipStream_t stream) {
    (void)in_sizes; (void)n_in; (void)out_size; (void)ws_size;
    const float* S   = (const float*)d_in[0];
    const float* px0 = (const float*)d_in[1];
    const float* py0 = (const float*)d_in[2];
    float* out = (float*)d_out;

    float* sp     = out;                      // slot 0: Sp
    float* outA_x = out + (size_t)NTOT;       // slot 1: phi_x post
    float* outA_y = out + 2 * (size_t)NTOT;   // slot 2: phi_y post
    float* outB_x = out + 3 * (size_t)NTOT;   // slot 3: phi_x pre
    float* outB_y = out + 4 * (size_t)NTOT;   // slot 4: phi_y pre

    unsigned* ws = (unsigned*)d_ws;
    unsigned* p0 = ws;                        // packed (fp16 phix, fp16 phiy), 16 MB
    unsigned* p1 = p0 + (size_t)NTOT;         // ping-pong partner, 16 MB
    unsigned* mP = p1 + (size_t)NTOT;         // packed (bf16 mx, bf16 my), 16 MB
    unsigned* vP = mP + (size_t)NTOT;         // packed (bf16 vx, bf16 vy), 16 MB
    unsigned long long* acc = (unsigned long long*)(vP + (size_t)NTOT);  // [NACC][NSLOT][8]

    hipMemsetAsync(acc, 0, (size_t)NACC * NSLOT * 8 * sizeof(unsigned long long), stream);

    dim3 grid(8, 8, 64), blk(256, 1, 1);

    k_init<<<2048, 256, 0, stream>>>(px0, py0, p0, mP, vP, acc);

    for (int t = 1; t <= 50; ++t) {
        double bc1 = 1.0 - pow(0.9, (double)t);
        double bc2 = 1.0 - pow(0.999, (double)t);
        float a_step = (float)(0.05 / bc1);
        float inv_bc2 = (float)(1.0 / bc2);
        bool odd = (t & 1) != 0;
        const unsigned* pPrev = odd ? p0 : p1;
        unsigned* pCur = odd ? p1 : p0;
        int mode = (t == 49) ? 1 : ((t == 50) ? 2 : 0);
        float* ox = (t == 50) ? outA_x : outB_x;   // mode1 -> pre slots, mode2 -> post
        float* oy = (t == 50) ? outA_y : outB_y;
        k_step<<<grid, blk, 0, stream>>>(S, pPrev, pCur, mP, vP,
                                         acc + (size_t)(t - 1) * NSLOT * 8,
                                         acc + (size_t)t * NSLOT * 8,
                                         a_step, inv_bc2, mode, ox, oy, sp);
    }
}

// Round 9
// 1721.009 us; speedup vs baseline: 8.1576x; 1.2007x over previous
//
#include <hip/hip_runtime.h>
#include <hip/hip_fp16.h>
#include <cmath>

#define Wd 256
#define Hd 256
#define HWd 65536
#define NTOT 4194304
#define NACC 51
#define NSLOT 64                     // atomic slots per step, one 64B line each

#define C_COUP (2.0f / 4194304.0f)   // 2*COUPLING/N
#define C_KIN  (0.2f / 4194304.0f)   // 2*ALPHA/N
#define C_VOID 0.0098f               // 2*GAMMA^2
#define SCFP 68719476736.0           // 2^36 fixed-point scale

// ---- packed bf16 pair helpers for Adam state (RNE, deterministic) ----
__device__ __forceinline__ float bflo(unsigned w) { return __uint_as_float(w << 16); }
__device__ __forceinline__ float bfhi(unsigned w) { return __uint_as_float(w & 0xFFFF0000u); }
__device__ __forceinline__ unsigned bfpack(float lo, float hi) {
    unsigned ul = __float_as_uint(lo);
    ul = (ul + 0x7FFFu + ((ul >> 16) & 1u)) >> 16;
    unsigned uh = __float_as_uint(hi);
    uh = (uh + 0x7FFFu + ((uh >> 16) & 1u)) & 0xFFFF0000u;
    return (ul & 0xFFFFu) | uh;
}

// ---- packed fp16 pair helpers for phi ping-pong (RNE, deterministic) ----
__device__ __forceinline__ unsigned packh2(float a, float b) {
    __half2 h = __floats2half2_rn(a, b);
    return *(unsigned*)&h;
}
__device__ __forceinline__ __half2 ash2(unsigned w) { return *(__half2*)&w; }
__device__ __forceinline__ unsigned asu32(__half2 h) { return *(unsigned*)&h; }

// block-level reduce of phi^2 sums -> one deterministic fixed-point atomic pair
__device__ __forceinline__ void block_acc(float sumx, float sumy, float* sRed,
                                          unsigned long long* slot) {
    for (int off = 32; off > 0; off >>= 1) {
        sumx += __shfl_down(sumx, off, 64);
        sumy += __shfl_down(sumy, off, 64);
    }
    const int tid = threadIdx.x;
    const int wid = tid >> 6;
    if ((tid & 63) == 0) { sRed[wid] = sumx; sRed[4 + wid] = sumy; }
    __syncthreads();
    if (tid == 0) {
        float fx = sRed[0] + sRed[1] + sRed[2] + sRed[3];
        float fy = sRed[4] + sRed[5] + sRed[6] + sRed[7];
        atomicAdd(&slot[0], (unsigned long long)((double)fx * SCFP + 0.5));
        atomicAdd(&slot[1], (unsigned long long)((double)fy * SCFP + 0.5));
    }
}

// mode: 0 = write packed only; 1 = packed + f32 outs (step 49);
//       2 = f32 outs + sp, no packed (step 50)
__global__ __launch_bounds__(256, 8)
void k_step(const float* __restrict__ S,
            const unsigned* __restrict__ pPrev, unsigned* __restrict__ pCur,
            unsigned* __restrict__ mP, unsigned* __restrict__ vP,
            const unsigned long long* __restrict__ accPrev,
            unsigned long long* __restrict__ accCur,
            float a_step, float inv_bc2, int mode,
            float* __restrict__ outx, float* __restrict__ outy,
            float* __restrict__ sp)
{
    // sP: phi strip as packed half2, col = local_col + 4 (local -4..35), stride 40
    __shared__ __align__(16) unsigned sP[36][40];
    // sC: Sobel-corr intermediates packed half2, row a = grid row y0-1+a,
    //     col = local_col + 3 (local -3..32), stride 36
    __shared__ __align__(16) unsigned sC1[34][36];
    __shared__ __align__(16) unsigned sC2[34][36];
    __shared__ float sRed[8];

    const int tid = threadIdx.x;
    const int cgi = tid & 7;
    const int rr  = tid >> 3;
    const int x0  = blockIdx.x * 32;
    const int y0  = blockIdx.y * 32;
    const size_t base = (size_t)blockIdx.z * HWd;

    // SSB coefs: sum previous step's 64 fixed-point slot pairs (order-independent)
    unsigned long long axu = 0ull, ayu = 0ull;
#pragma unroll 8
    for (int i = 0; i < NSLOT; ++i) { axu += accPrev[i * 8]; ayu += accPrev[i * 8 + 1]; }
    double axd = (double)axu * (1.0 / SCFP);
    double ayd = (double)ayu * (1.0 / SCFP);
    double nxd = sqrt(axd), nyd = sqrt(ayd);
    double pnd = nxd + nyd;
    double uu = pnd * pnd - 0.01;                 // V^2
    double sg = (uu > 0.0) ? 1.0 : ((uu < 0.0) ? -1.0 : 0.0);
    const float coefx = (float)(0.2 * sg * pnd / nxd);
    const float coefy = (float)(0.2 * sg * pnd / nyd);

    const __half2 k8 = __float2half2_rn(0.125f);
    const __half2 k4 = __float2half2_rn(0.25f);

    // ---- strip load: 360 uint4 tasks, stored packed (no conversion) ----
#pragma unroll
    for (int k = 0; k < 2; ++k) {
        int task = tid + (k << 8);
        if (task < 360) {
            int u = (task * 205) >> 11;          // task/10 exact for task<360
            int v = task - 10 * u;
            int gy = y0 - 2 + u, gx = x0 - 4 + 4 * v;
            uint4 w = make_uint4(0u, 0u, 0u, 0u);
            if ((unsigned)gy < 256u && (unsigned)gx < 256u)
                w = *(const uint4*)(pPrev + base + (size_t)gy * Wd + gx);
            *(uint4*)&sP[u][4 * v] = w;
        }
    }
    __syncthreads();

    // ---- c-stage, packed both fields: 306 tasks (34 rows x 9 col groups) ----
#pragma unroll
    for (int k = 0; k < 2; ++k) {
        int task = tid + (k << 8);
        if (task < 306) {
            int a = (task * 57) >> 9;            // task/9 exact for task<306
            int v = task - 9 * a;
            int gyy = y0 - 1 + a;
            uint4 c1o = make_uint4(0u, 0u, 0u, 0u);
            uint4 c2o = make_uint4(0u, 0u, 0u, 0u);
            if ((unsigned)gyy < 256u) {
                uint4 T0 = *(uint4*)&sP[a][4 * v];     uint4 T1 = *(uint4*)&sP[a][4 * v + 4];
                uint4 M0 = *(uint4*)&sP[a + 1][4 * v]; uint4 M1 = *(uint4*)&sP[a + 1][4 * v + 4];
                uint4 B0 = *(uint4*)&sP[a + 2][4 * v]; uint4 B1 = *(uint4*)&sP[a + 2][4 * v + 4];
                __half2 wt[6] = {ash2(T0.x), ash2(T0.y), ash2(T0.z), ash2(T0.w), ash2(T1.x), ash2(T1.y)};
                __half2 wm[6] = {ash2(M0.x), ash2(M0.y), ash2(M0.z), ash2(M0.w), ash2(M1.x), ash2(M1.y)};
                __half2 wb[6] = {ash2(B0.x), ash2(B0.y), ash2(B0.z), ash2(B0.w), ash2(B1.x), ash2(B1.y)};
                unsigned c1u[4], c2u[4];
#pragma unroll
                for (int jj = 0; jj < 4; ++jj) {
                    __half2 c1 = __hfma2(k4, __hsub2(wm[jj + 2], wm[jj]),
                                 __hmul2(k8, __hadd2(__hsub2(wt[jj + 2], wt[jj]),
                                                     __hsub2(wb[jj + 2], wb[jj]))));
                    __half2 c2 = __hfma2(k4, __hsub2(wb[jj + 1], wt[jj + 1]),
                                 __hmul2(k8, __hadd2(__hsub2(wb[jj], wt[jj]),
                                                     __hsub2(wb[jj + 2], wt[jj + 2]))));
                    unsigned msk = ((unsigned)(x0 + 4 * v - 3 + jj) < 256u) ? 0xFFFFFFFFu : 0u;
                    c1u[jj] = asu32(c1) & msk;
                    c2u[jj] = asu32(c2) & msk;
                }
                c1o = make_uint4(c1u[0], c1u[1], c1u[2], c1u[3]);
                c2o = make_uint4(c2u[0], c2u[1], c2u[2], c2u[3]);
            }
            *(uint4*)&sC1[a][4 * v] = c1o;
            *(uint4*)&sC2[a][4 * v] = c2o;
        }
    }
    __syncthreads();

    // ---- d-stage, packed: second Sobel corr + center phi ----
    float dKx[4], dKy[4], pxa[4], pya[4];
    {
        uint4 pw = *(uint4*)&sP[rr + 2][4 * cgi + 4];
        unsigned pwv[4] = {pw.x, pw.y, pw.z, pw.w};
#pragma unroll
        for (int j = 0; j < 4; ++j) {
            float2 f = __half22float2(ash2(pwv[j]));
            pxa[j] = f.x; pya[j] = f.y;
        }
        const int cb = 4 * cgi;
        uint4 U0a = *(uint4*)&sC1[rr][cb];     uint4 U0b = *(uint4*)&sC1[rr][cb + 4];
        uint4 U1a = *(uint4*)&sC1[rr + 1][cb]; uint4 U1b = *(uint4*)&sC1[rr + 1][cb + 4];
        uint4 U2a = *(uint4*)&sC1[rr + 2][cb]; uint4 U2b = *(uint4*)&sC1[rr + 2][cb + 4];
        uint4 V0a = *(uint4*)&sC2[rr][cb];     uint4 V0b = *(uint4*)&sC2[rr][cb + 4];
        uint4 V2a = *(uint4*)&sC2[rr + 2][cb]; uint4 V2b = *(uint4*)&sC2[rr + 2][cb + 4];
        __half2 u0[8] = {ash2(U0a.x), ash2(U0a.y), ash2(U0a.z), ash2(U0a.w),
                         ash2(U0b.x), ash2(U0b.y), ash2(U0b.z), ash2(U0b.w)};
        __half2 u1[8] = {ash2(U1a.x), ash2(U1a.y), ash2(U1a.z), ash2(U1a.w),
                         ash2(U1b.x), ash2(U1b.y), ash2(U1b.z), ash2(U1b.w)};
        __half2 u2[8] = {ash2(U2a.x), ash2(U2a.y), ash2(U2a.z), ash2(U2a.w),
                         ash2(U2b.x), ash2(U2b.y), ash2(U2b.z), ash2(U2b.w)};
        __half2 t0[8] = {ash2(V0a.x), ash2(V0a.y), ash2(V0a.z), ash2(V0a.w),
                         ash2(V0b.x), ash2(V0b.y), ash2(V0b.z), ash2(V0b.w)};
        __half2 t2[8] = {ash2(V2a.x), ash2(V2a.y), ash2(V2a.z), ash2(V2a.w),
                         ash2(V2b.x), ash2(V2b.y), ash2(V2b.z), ash2(V2b.w)};
#pragma unroll
        for (int jj = 0; jj < 4; ++jj) {
            __half2 A = __hadd2(__hadd2(__hsub2(u0[jj + 4], u0[jj + 2]),
                                        __hsub2(u2[jj + 4], u2[jj + 2])),
                                __hadd2(__hsub2(t2[jj + 2], t0[jj + 2]),
                                        __hsub2(t2[jj + 4], t0[jj + 4])));
            __half2 B = __hadd2(__hsub2(u1[jj + 4], u1[jj + 2]),
                                __hsub2(t2[jj + 3], t0[jj + 3]));
            __half2 dk = __hfma2(k4, B, __hmul2(k8, A));
            float2 f = __half22float2(dk);
            dKx[jj] = f.x; dKy[jj] = f.y;
        }
    }

    // ---- pointwise grad + Adam (state packed bf16, phi packed fp16) ----
    const int gy = y0 + rr;
    const int gxb = x0 + 4 * cgi;
    const size_t idx = base + (size_t)gy * Wd + gxb;

    float4 s4 = *(const float4*)(S + idx);
    float sa[4] = {s4.x, s4.y, s4.z, s4.w};
    const bool ok_e = (gxb + 4 < Wd);
    float sE = ok_e ? S[idx + 4] : 0.f;
    const bool ok_d = (gy + 1 < Hd);
    float4 sD = ok_d ? *(const float4*)(S + idx + Wd) : make_float4(0.f, 0.f, 0.f, 0.f);
    float sdv[4] = {sD.x, sD.y, sD.z, sD.w};

    uint4 mp4 = *(const uint4*)(mP + idx);
    uint4 vp4 = *(const uint4*)(vP + idx);
    unsigned mpv[4] = {mp4.x, mp4.y, mp4.z, mp4.w};
    unsigned vpv[4] = {vp4.x, vp4.y, vp4.z, vp4.w};

    unsigned nmw[4], nvw[4], npk[4];
    float npx[4], npy[4], spv[4];
    float sumx = 0.f, sumy = 0.f;
#pragma unroll
    for (int j = 0; j < 4; ++j) {
        float dx_ = (j < 3) ? (sa[j + 1] - sa[j]) : (ok_e ? (sE - sa[3]) : 0.f);
        float dy_ = ok_d ? (sdv[j] - sa[j]) : 0.f;
        float R = pxa[j] * dx_ + pya[j] * dy_;
        float vmc = (sa[j] < 0.05f) ? C_VOID : 0.f;
        float gx_ = C_COUP * R * dx_ - C_KIN * dKx[j] + (coefx + vmc) * pxa[j];
        float gy_ = C_COUP * R * dy_ - C_KIN * dKy[j] + (coefy + vmc) * pya[j];

        float m1 = 0.9f * bflo(mpv[j]) + 0.1f * gx_;
        float v1 = 0.999f * bflo(vpv[j]) + 0.001f * gx_ * gx_;
        npx[j] = pxa[j] - __fdividef(a_step * m1, sqrtf(v1 * inv_bc2) + 1e-8f);
        sumx += npx[j] * npx[j];

        float m2 = 0.9f * bfhi(mpv[j]) + 0.1f * gy_;
        float v2 = 0.999f * bfhi(vpv[j]) + 0.001f * gy_ * gy_;
        npy[j] = pya[j] - __fdividef(a_step * m2, sqrtf(v2 * inv_bc2) + 1e-8f);
        sumy += npy[j] * npy[j];

        nmw[j] = bfpack(m1, m2);
        nvw[j] = bfpack(v1, v2);
        npk[j] = packh2(npx[j], npy[j]);
        spv[j] = sa[j] + R;
    }
    *(uint4*)(mP + idx) = make_uint4(nmw[0], nmw[1], nmw[2], nmw[3]);
    *(uint4*)(vP + idx) = make_uint4(nvw[0], nvw[1], nvw[2], nvw[3]);
    if (mode != 2)
        *(uint4*)(pCur + idx) = make_uint4(npk[0], npk[1], npk[2], npk[3]);
    if (mode != 0) {
        *(float4*)(outx + idx) = make_float4(npx[0], npx[1], npx[2], npx[3]);
        *(float4*)(outy + idx) = make_float4(npy[0], npy[1], npy[2], npy[3]);
    }
    if (mode == 2)
        *(float4*)(sp + idx) = make_float4(spv[0], spv[1], spv[2], spv[3]);

    block_acc(sumx, sumy, sRed, accCur + (size_t)blockIdx.z * 8);
}

__global__ __launch_bounds__(256)
void k_init(const float* __restrict__ px0, const float* __restrict__ py0,
            unsigned* __restrict__ p0,
            unsigned* __restrict__ mP, unsigned* __restrict__ vP,
            unsigned long long* __restrict__ acc0)
{
    __shared__ float sRed[8];
    const int tid = threadIdx.x;
    const size_t base = (size_t)blockIdx.x * 2048;
    uint4 z4 = make_uint4(0u, 0u, 0u, 0u);
    float sx = 0.f, sy = 0.f;
#pragma unroll
    for (int k = 0; k < 2; ++k) {
        size_t idx = base + (size_t)(k * 1024 + tid * 4);
        float4 x = *(const float4*)(px0 + idx);
        float4 y = *(const float4*)(py0 + idx);
        *(uint4*)(p0 + idx) = make_uint4(packh2(x.x, y.x), packh2(x.y, y.y),
                                         packh2(x.z, y.z), packh2(x.w, y.w));
        *(uint4*)(mP + idx) = z4;   *(uint4*)(vP + idx) = z4;
        sx += x.x * x.x + x.y * x.y + x.z * x.z + x.w * x.w;
        sy += y.x * y.x + y.y * y.y + y.z * y.z + y.w * y.w;
    }
    block_acc(sx, sy, sRed, acc0 + (size_t)(blockIdx.x & (NSLOT - 1)) * 8);
}

extern "C" void kernel_launch(void* const* d_in, const int* in_sizes, int n_in,
                              void* d_out, int out_size, void* d_ws, size_t ws_size,
                              hipStream_t stream) {
    (void)in_sizes; (void)n_in; (void)out_size; (void)ws_size;
    const float* S   = (const float*)d_in[0];
    const float* px0 = (const float*)d_in[1];
    const float* py0 = (const float*)d_in[2];
    float* out = (float*)d_out;

    float* sp     = out;                      // slot 0: Sp
    float* outA_x = out + (size_t)NTOT;       // slot 1: phi_x post
    float* outA_y = out + 2 * (size_t)NTOT;   // slot 2: phi_y post
    float* outB_x = out + 3 * (size_t)NTOT;   // slot 3: phi_x pre
    float* outB_y = out + 4 * (size_t)NTOT;   // slot 4: phi_y pre

    unsigned* ws = (unsigned*)d_ws;
    unsigned* p0 = ws;                        // packed (fp16 phix, fp16 phiy), 16 MB
    unsigned* p1 = p0 + (size_t)NTOT;         // ping-pong partner, 16 MB
    unsigned* mP = p1 + (size_t)NTOT;         // packed (bf16 mx, bf16 my), 16 MB
    unsigned* vP = mP + (size_t)NTOT;         // packed (bf16 vx, bf16 vy), 16 MB
    unsigned long long* acc = (unsigned long long*)(vP + (size_t)NTOT);  // [NACC][NSLOT][8]

    hipMemsetAsync(acc, 0, (size_t)NACC * NSLOT * 8 * sizeof(unsigned long long), stream);

    dim3 grid(8, 8, 64), blk(256, 1, 1);

    k_init<<<2048, 256, 0, stream>>>(px0, py0, p0, mP, vP, acc);

    for (int t = 1; t <= 50; ++t) {
        double bc1 = 1.0 - pow(0.9, (double)t);
        double bc2 = 1.0 - pow(0.999, (double)t);
        float a_step = (float)(0.05 / bc1);
        float inv_bc2 = (float)(1.0 / bc2);
        bool odd = (t & 1) != 0;
        const unsigned* pPrev = odd ? p0 : p1;
        unsigned* pCur = odd ? p1 : p0;
        int mode = (t == 49) ? 1 : ((t == 50) ? 2 : 0);
        float* ox = (t == 50) ? outA_x : outB_x;   // mode1 -> pre slots, mode2 -> post
        float* oy = (t == 50) ? outA_y : outB_y;
        k_step<<<grid, blk, 0, stream>>>(S, pPrev, pCur, mP, vP,
                                         acc + (size_t)(t - 1) * NSLOT * 8,
                                         acc + (size_t)t * NSLOT * 8,
                                         a_step, inv_bc2, mode, ox, oy, sp);
    }
}

// Round 10
// 1649.600 us; speedup vs baseline: 8.5107x; 1.0433x over previous
//
#include <hip/hip_runtime.h>
#include <hip/hip_fp16.h>
#include <cmath>

#define Wd 256
#define Hd 256
#define HWd 65536
#define NTOT 4194304
#define NACC 51
#define NSLOT 64                     // atomic slots per step, one 64B line each

#define C_COUP (2.0f / 4194304.0f)   // 2*COUPLING/N
#define C_KIN  (0.2f / 4194304.0f)   // 2*ALPHA/N
#define C_VOID 0.0098f               // 2*GAMMA^2
#define SCFP 68719476736.0           // 2^36 fixed-point scale

// ---- packed bf16 pair helpers for Adam state (RNE, deterministic) ----
__device__ __forceinline__ float bflo(unsigned w) { return __uint_as_float(w << 16); }
__device__ __forceinline__ float bfhi(unsigned w) { return __uint_as_float(w & 0xFFFF0000u); }
__device__ __forceinline__ unsigned bfpack(float lo, float hi) {
    unsigned ul = __float_as_uint(lo);
    ul = (ul + 0x7FFFu + ((ul >> 16) & 1u)) >> 16;
    unsigned uh = __float_as_uint(hi);
    uh = (uh + 0x7FFFu + ((uh >> 16) & 1u)) & 0xFFFF0000u;
    return (ul & 0xFFFFu) | uh;
}

// ---- packed fp16 pair helpers (RNE, deterministic) ----
__device__ __forceinline__ unsigned packh2(float a, float b) {
    __half2 h = __floats2half2_rn(a, b);
    return *(unsigned*)&h;
}
__device__ __forceinline__ __half2 ash2(unsigned w) { return *(__half2*)&w; }
__device__ __forceinline__ unsigned asu32(__half2 h) { return *(unsigned*)&h; }

// block-level reduce of phi^2 sums -> one deterministic fixed-point atomic pair
__device__ __forceinline__ void block_acc(float sumx, float sumy, float* sRed,
                                          unsigned long long* slot) {
    for (int off = 32; off > 0; off >>= 1) {
        sumx += __shfl_down(sumx, off, 64);
        sumy += __shfl_down(sumy, off, 64);
    }
    const int tid = threadIdx.x;
    const int wid = tid >> 6;
    if ((tid & 63) == 0) { sRed[wid] = sumx; sRed[4 + wid] = sumy; }
    __syncthreads();
    if (tid == 0) {
        float fx = sRed[0] + sRed[1] + sRed[2] + sRed[3];
        float fy = sRed[4] + sRed[5] + sRed[6] + sRed[7];
        atomicAdd(&slot[0], (unsigned long long)((double)fx * SCFP + 0.5));
        atomicAdd(&slot[1], (unsigned long long)((double)fy * SCFP + 0.5));
    }
}

// mode: 0 = write packed only; 1 = packed + f32 outs (step 49);
//       2 = f32 outs + sp, no packed (step 50). first: t==1 (m,v implicit zero)
__global__ __launch_bounds__(256, 6)
void k_step(const float* __restrict__ S,
            const unsigned* __restrict__ dxy,
            const unsigned* __restrict__ pPrev, unsigned* __restrict__ pCur,
            unsigned* __restrict__ mP, unsigned* __restrict__ vP,
            const unsigned long long* __restrict__ accPrev,
            unsigned long long* __restrict__ accCur,
            float a_step, float inv_bc2, int mode, int first,
            float* __restrict__ outx, float* __restrict__ outy,
            float* __restrict__ sp)
{
    __shared__ __align__(16) unsigned sP[36][40];    // phi strip packed half2
    __shared__ __align__(16) unsigned sC1[34][36];   // Sobel-corr packed half2
    __shared__ __align__(16) unsigned sC2[34][36];
    __shared__ float sRed[8];

    const int tid = threadIdx.x;
    const int cgi = tid & 7;
    const int rr  = tid >> 3;
    const int x0  = blockIdx.x * 32;
    const int y0  = blockIdx.y * 32;
    const size_t base = (size_t)blockIdx.z * HWd;
    const int gy = y0 + rr;
    const int gxb = x0 + 4 * cgi;
    const size_t idx = base + (size_t)gy * Wd + gxb;

    // ---- hoisted global loads: latency hides under the LDS phases ----
    uint4 d4 = *(const uint4*)(dxy + idx);
    uint4 mp4 = make_uint4(0u, 0u, 0u, 0u), vp4 = make_uint4(0u, 0u, 0u, 0u);
    if (!first) { mp4 = *(const uint4*)(mP + idx); vp4 = *(const uint4*)(vP + idx); }
    float4 s4 = make_float4(0.f, 0.f, 0.f, 0.f);
    if (mode == 2) s4 = *(const float4*)(S + idx);

    // ---- strip load: 360 uint4 tasks, stored packed ----
#pragma unroll
    for (int k = 0; k < 2; ++k) {
        int task = tid + (k << 8);
        if (task < 360) {
            int u = (task * 205) >> 11;          // task/10 exact for task<360
            int v = task - 10 * u;
            int gyy = y0 - 2 + u, gxx = x0 - 4 + 4 * v;
            uint4 w = make_uint4(0u, 0u, 0u, 0u);
            if ((unsigned)gyy < 256u && (unsigned)gxx < 256u)
                w = *(const uint4*)(pPrev + base + (size_t)gyy * Wd + gxx);
            *(uint4*)&sP[u][4 * v] = w;
        }
    }

    // ---- SSB coef prologue on wave 3 only (overlaps strip load) ----
    if (tid >= 192) {
        int l = tid - 192;
        unsigned long long ax = accPrev[l * 8];
        unsigned long long ay = accPrev[l * 8 + 1];
#pragma unroll
        for (int off = 1; off < 64; off <<= 1) {
            ax += __shfl_xor(ax, off, 64);
            ay += __shfl_xor(ay, off, 64);
        }
        if (l == 0) {
            double axd = (double)ax * (1.0 / SCFP);
            double ayd = (double)ay * (1.0 / SCFP);
            double nxd = sqrt(axd), nyd = sqrt(ayd);
            double pnd = nxd + nyd;
            double uu = pnd * pnd - 0.01;             // V^2
            double sg = (uu > 0.0) ? 1.0 : ((uu < 0.0) ? -1.0 : 0.0);
            sRed[6] = (float)(0.2 * sg * pnd / nxd);
            sRed[7] = (float)(0.2 * sg * pnd / nyd);
        }
    }
    __syncthreads();
    const float coefx = sRed[6];
    const float coefy = sRed[7];

    const __half2 k8 = __float2half2_rn(0.125f);
    const __half2 k4 = __float2half2_rn(0.25f);

    // ---- c-stage, packed both fields: 306 tasks (34 rows x 9 col groups) ----
#pragma unroll
    for (int k = 0; k < 2; ++k) {
        int task = tid + (k << 8);
        if (task < 306) {
            int a = (task * 57) >> 9;            // task/9 exact for task<306
            int v = task - 9 * a;
            int gyy = y0 - 1 + a;
            uint4 c1o = make_uint4(0u, 0u, 0u, 0u);
            uint4 c2o = make_uint4(0u, 0u, 0u, 0u);
            if ((unsigned)gyy < 256u) {
                uint4 T0 = *(uint4*)&sP[a][4 * v];     uint4 T1 = *(uint4*)&sP[a][4 * v + 4];
                uint4 M0 = *(uint4*)&sP[a + 1][4 * v]; uint4 M1 = *(uint4*)&sP[a + 1][4 * v + 4];
                uint4 B0 = *(uint4*)&sP[a + 2][4 * v]; uint4 B1 = *(uint4*)&sP[a + 2][4 * v + 4];
                __half2 wt[6] = {ash2(T0.x), ash2(T0.y), ash2(T0.z), ash2(T0.w), ash2(T1.x), ash2(T1.y)};
                __half2 wm[6] = {ash2(M0.x), ash2(M0.y), ash2(M0.z), ash2(M0.w), ash2(M1.x), ash2(M1.y)};
                __half2 wb[6] = {ash2(B0.x), ash2(B0.y), ash2(B0.z), ash2(B0.w), ash2(B1.x), ash2(B1.y)};
                unsigned c1u[4], c2u[4];
#pragma unroll
                for (int jj = 0; jj < 4; ++jj) {
                    __half2 c1 = __hfma2(k4, __hsub2(wm[jj + 2], wm[jj]),
                                 __hmul2(k8, __hadd2(__hsub2(wt[jj + 2], wt[jj]),
                                                     __hsub2(wb[jj + 2], wb[jj]))));
                    __half2 c2 = __hfma2(k4, __hsub2(wb[jj + 1], wt[jj + 1]),
                                 __hmul2(k8, __hadd2(__hsub2(wb[jj], wt[jj]),
                                                     __hsub2(wb[jj + 2], wt[jj + 2]))));
                    unsigned msk = ((unsigned)(x0 + 4 * v - 3 + jj) < 256u) ? 0xFFFFFFFFu : 0u;
                    c1u[jj] = asu32(c1) & msk;
                    c2u[jj] = asu32(c2) & msk;
                }
                c1o = make_uint4(c1u[0], c1u[1], c1u[2], c1u[3]);
                c2o = make_uint4(c2u[0], c2u[1], c2u[2], c2u[3]);
            }
            *(uint4*)&sC1[a][4 * v] = c1o;
            *(uint4*)&sC2[a][4 * v] = c2o;
        }
    }
    __syncthreads();

    // ---- d-stage, packed: second Sobel corr + center phi ----
    float dKx[4], dKy[4], pxa[4], pya[4];
    {
        uint4 pw = *(uint4*)&sP[rr + 2][4 * cgi + 4];
        unsigned pwv[4] = {pw.x, pw.y, pw.z, pw.w};
#pragma unroll
        for (int j = 0; j < 4; ++j) {
            float2 f = __half22float2(ash2(pwv[j]));
            pxa[j] = f.x; pya[j] = f.y;
        }
        const int cb = 4 * cgi;
        uint4 U0a = *(uint4*)&sC1[rr][cb];     uint4 U0b = *(uint4*)&sC1[rr][cb + 4];
        uint4 U1a = *(uint4*)&sC1[rr + 1][cb]; uint4 U1b = *(uint4*)&sC1[rr + 1][cb + 4];
        uint4 U2a = *(uint4*)&sC1[rr + 2][cb]; uint4 U2b = *(uint4*)&sC1[rr + 2][cb + 4];
        uint4 V0a = *(uint4*)&sC2[rr][cb];     uint4 V0b = *(uint4*)&sC2[rr][cb + 4];
        uint4 V2a = *(uint4*)&sC2[rr + 2][cb]; uint4 V2b = *(uint4*)&sC2[rr + 2][cb + 4];
        __half2 u0[8] = {ash2(U0a.x), ash2(U0a.y), ash2(U0a.z), ash2(U0a.w),
                         ash2(U0b.x), ash2(U0b.y), ash2(U0b.z), ash2(U0b.w)};
        __half2 u1[8] = {ash2(U1a.x), ash2(U1a.y), ash2(U1a.z), ash2(U1a.w),
                         ash2(U1b.x), ash2(U1b.y), ash2(U1b.z), ash2(U1b.w)};
        __half2 u2[8] = {ash2(U2a.x), ash2(U2a.y), ash2(U2a.z), ash2(U2a.w),
                         ash2(U2b.x), ash2(U2b.y), ash2(U2b.z), ash2(U2b.w)};
        __half2 t0[8] = {ash2(V0a.x), ash2(V0a.y), ash2(V0a.z), ash2(V0a.w),
                         ash2(V0b.x), ash2(V0b.y), ash2(V0b.z), ash2(V0b.w)};
        __half2 t2[8] = {ash2(V2a.x), ash2(V2a.y), ash2(V2a.z), ash2(V2a.w),
                         ash2(V2b.x), ash2(V2b.y), ash2(V2b.z), ash2(V2b.w)};
#pragma unroll
        for (int jj = 0; jj < 4; ++jj) {
            __half2 A = __hadd2(__hadd2(__hsub2(u0[jj + 4], u0[jj + 2]),
                                        __hsub2(u2[jj + 4], u2[jj + 2])),
                                __hadd2(__hsub2(t2[jj + 2], t0[jj + 2]),
                                        __hsub2(t2[jj + 4], t0[jj + 4])));
            __half2 B = __hadd2(__hsub2(u1[jj + 4], u1[jj + 2]),
                                __hsub2(t2[jj + 3], t0[jj + 3]));
            __half2 dk = __hfma2(k4, B, __hmul2(k8, A));
            float2 f = __half22float2(dk);
            dKx[jj] = f.x; dKy[jj] = f.y;
        }
    }

    // ---- pointwise grad + Adam (dx,dy,void from precomputed pack) ----
    unsigned duv[4] = {d4.x, d4.y, d4.z, d4.w};
    unsigned mpv[4] = {mp4.x, mp4.y, mp4.z, mp4.w};
    unsigned vpv[4] = {vp4.x, vp4.y, vp4.z, vp4.w};
    float sa[4] = {s4.x, s4.y, s4.z, s4.w};

    unsigned nmw[4], nvw[4], npk[4];
    float npx[4], npy[4], spv[4];
    float sumx = 0.f, sumy = 0.f;
#pragma unroll
    for (int j = 0; j < 4; ++j) {
        float2 dd = __half22float2(ash2(duv[j]));
        float dx_ = dd.x, dy_ = dd.y;
        float vmc = (duv[j] & 1u) ? C_VOID : 0.f;
        float R = pxa[j] * dx_ + pya[j] * dy_;
        float gx_ = C_COUP * R * dx_ - C_KIN * dKx[j] + (coefx + vmc) * pxa[j];
        float gy_ = C_COUP * R * dy_ - C_KIN * dKy[j] + (coefy + vmc) * pya[j];

        float m1 = first ? (0.1f * gx_) : (0.9f * bflo(mpv[j]) + 0.1f * gx_);
        float v1 = first ? (0.001f * gx_ * gx_) : (0.999f * bflo(vpv[j]) + 0.001f * gx_ * gx_);
        npx[j] = pxa[j] - __fdividef(a_step * m1, sqrtf(v1 * inv_bc2) + 1e-8f);
        sumx += npx[j] * npx[j];

        float m2 = first ? (0.1f * gy_) : (0.9f * bfhi(mpv[j]) + 0.1f * gy_);
        float v2 = first ? (0.001f * gy_ * gy_) : (0.999f * bfhi(vpv[j]) + 0.001f * gy_ * gy_);
        npy[j] = pya[j] - __fdividef(a_step * m2, sqrtf(v2 * inv_bc2) + 1e-8f);
        sumy += npy[j] * npy[j];

        nmw[j] = bfpack(m1, m2);
        nvw[j] = bfpack(v1, v2);
        npk[j] = packh2(npx[j], npy[j]);
        spv[j] = sa[j] + R;
    }
    *(uint4*)(mP + idx) = make_uint4(nmw[0], nmw[1], nmw[2], nmw[3]);
    *(uint4*)(vP + idx) = make_uint4(nvw[0], nvw[1], nvw[2], nvw[3]);
    if (mode != 2)
        *(uint4*)(pCur + idx) = make_uint4(npk[0], npk[1], npk[2], npk[3]);
    if (mode != 0) {
        *(float4*)(outx + idx) = make_float4(npx[0], npx[1], npx[2], npx[3]);
        *(float4*)(outy + idx) = make_float4(npy[0], npy[1], npy[2], npy[3]);
    }
    if (mode == 2)
        *(float4*)(sp + idx) = make_float4(spv[0], spv[1], spv[2], spv[3]);

    block_acc(sumx, sumy, sRed, accCur + (size_t)blockIdx.z * 8);
}

// init: pack phi0 -> p0, precompute packed (dx,dy,void) from S, ||phi0||^2
__global__ __launch_bounds__(256)
void k_init(const float* __restrict__ S,
            const float* __restrict__ px0, const float* __restrict__ py0,
            unsigned* __restrict__ p0, unsigned* __restrict__ dxy,
            unsigned long long* __restrict__ acc0)
{
    __shared__ float sRed[8];
    const int tid = threadIdx.x;
    float sx = 0.f, sy = 0.f;
#pragma unroll
    for (int k = 0; k < 2; ++k) {
        size_t idx = (size_t)blockIdx.x * 2048 + (size_t)(k * 1024 + tid * 4);
        float4 x = *(const float4*)(px0 + idx);
        float4 y = *(const float4*)(py0 + idx);
        *(uint4*)(p0 + idx) = make_uint4(packh2(x.x, y.x), packh2(x.y, y.y),
                                         packh2(x.z, y.z), packh2(x.w, y.w));
        sx += x.x * x.x + x.y * x.y + x.z * x.z + x.w * x.w;
        sy += y.x * y.x + y.y * y.y + y.z * y.z + y.w * y.w;

        // dx,dy,void pack
        int col = (int)(idx & 255u);
        int row = (int)((idx >> 8) & 255u);
        float4 s4 = *(const float4*)(S + idx);
        float sa[4] = {s4.x, s4.y, s4.z, s4.w};
        float sE = (col + 4 < 256) ? S[idx + 4] : 0.f;
        float4 sD = (row < 255) ? *(const float4*)(S + idx + 256) : make_float4(0.f, 0.f, 0.f, 0.f);
        float sd[4] = {sD.x, sD.y, sD.z, sD.w};
        unsigned du[4];
#pragma unroll
        for (int j = 0; j < 4; ++j) {
            float dx_ = (j < 3) ? (sa[j + 1] - sa[j]) : ((col + 4 < 256) ? (sE - sa[3]) : 0.f);
            float dy_ = (row < 255) ? (sd[j] - sa[j]) : 0.f;
            unsigned u = packh2(dx_, dy_);
            du[j] = (u & ~1u) | ((sa[j] < 0.05f) ? 1u : 0u);
        }
        *(uint4*)(dxy + idx) = make_uint4(du[0], du[1], du[2], du[3]);
    }
    block_acc(sx, sy, sRed, acc0 + (size_t)(blockIdx.x & (NSLOT - 1)) * 8);
}

extern "C" void kernel_launch(void* const* d_in, const int* in_sizes, int n_in,
                              void* d_out, int out_size, void* d_ws, size_t ws_size,
                              hipStream_t stream) {
    (void)in_sizes; (void)n_in; (void)out_size; (void)ws_size;
    const float* S   = (const float*)d_in[0];
    const float* px0 = (const float*)d_in[1];
    const float* py0 = (const float*)d_in[2];
    float* out = (float*)d_out;

    float* sp     = out;                      // slot 0: Sp
    float* outA_x = out + (size_t)NTOT;       // slot 1: phi_x post
    float* outA_y = out + 2 * (size_t)NTOT;   // slot 2: phi_y post
    float* outB_x = out + 3 * (size_t)NTOT;   // slot 3: phi_x pre
    float* outB_y = out + 4 * (size_t)NTOT;   // slot 4: phi_y pre

    unsigned* ws = (unsigned*)d_ws;
    unsigned* p0 = ws;                        // packed (fp16 phix, fp16 phiy), 16 MB
    unsigned* p1 = p0 + (size_t)NTOT;         // ping-pong partner, 16 MB
    unsigned* mP = p1 + (size_t)NTOT;         // packed (bf16 mx, bf16 my), 16 MB
    unsigned* vP = mP + (size_t)NTOT;         // packed (bf16 vx, bf16 vy), 16 MB
    unsigned* dxy = vP + (size_t)NTOT;        // packed (fp16 dx, fp16 dy | void), 16 MB
    unsigned long long* acc = (unsigned long long*)(dxy + (size_t)NTOT);  // [NACC][NSLOT][8]

    hipMemsetAsync(acc, 0, (size_t)NACC * NSLOT * 8 * sizeof(unsigned long long), stream);

    dim3 grid(8, 8, 64), blk(256, 1, 1);

    k_init<<<2048, 256, 0, stream>>>(S, px0, py0, p0, dxy, acc);

    for (int t = 1; t <= 50; ++t) {
        double bc1 = 1.0 - pow(0.9, (double)t);
        double bc2 = 1.0 - pow(0.999, (double)t);
        float a_step = (float)(0.05 / bc1);
        float inv_bc2 = (float)(1.0 / bc2);
        bool odd = (t & 1) != 0;
        const unsigned* pPrev = odd ? p0 : p1;
        unsigned* pCur = odd ? p1 : p0;
        int mode = (t == 49) ? 1 : ((t == 50) ? 2 : 0);
        float* ox = (t == 50) ? outA_x : outB_x;   // mode1 -> pre slots, mode2 -> post
        float* oy = (t == 50) ? outA_y : outB_y;
        k_step<<<grid, blk, 0, stream>>>(S, dxy, pPrev, pCur, mP, vP,
                                         acc + (size_t)(t - 1) * NSLOT * 8,
                                         acc + (size_t)t * NSLOT * 8,
                                         a_step, inv_bc2, mode, (t == 1) ? 1 : 0,
                                         ox, oy, sp);
    }
}

// Round 11
// 1589.453 us; speedup vs baseline: 8.8327x; 1.0378x over previous
//
#include <hip/hip_runtime.h>
#include <hip/hip_fp16.h>
#include <cmath>

#define Wd 256
#define Hd 256
#define HWd 65536
#define NTOT 4194304
#define NACC 51
#define NSLOT 64                     // atomic slots per step, one 64B line each

#define C_COUP (2.0f / 4194304.0f)   // 2*COUPLING/N
#define C_KIN  (0.2f / 4194304.0f)   // 2*ALPHA/N
#define C_VOID 0.0098f               // 2*GAMMA^2
#define SCFP 68719476736.0           // 2^36 fixed-point scale

// ---- packed bf16 pair helpers for Adam state ----
__device__ __forceinline__ float bflo(unsigned w) { return __uint_as_float(w << 16); }
__device__ __forceinline__ float bfhi(unsigned w) { return __uint_as_float(w & 0xFFFF0000u); }
// hardware pack: lo=bf16(a), hi=bf16(b), RNE (deterministic)
__device__ __forceinline__ unsigned bfpack(float a, float b) {
    unsigned r;
    asm volatile("v_cvt_pk_bf16_f32 %0, %1, %2" : "=v"(r) : "v"(a), "v"(b));
    return r;
}

// ---- packed fp16 pair helpers (deterministic) ----
__device__ __forceinline__ unsigned packh2(float a, float b) {
    __half2 h = __floats2half2_rn(a, b);
    return *(unsigned*)&h;
}
// hardware pack RTZ (1 instr) for the phi ping-pong
__device__ __forceinline__ unsigned packh2z(float a, float b) {
    auto h = __builtin_amdgcn_cvt_pkrtz(a, b);
    return *(unsigned*)&h;
}
__device__ __forceinline__ __half2 ash2(unsigned w) { return *(__half2*)&w; }
__device__ __forceinline__ unsigned asu32(__half2 h) { return *(unsigned*)&h; }

// block-level reduce of phi^2 sums -> one deterministic fixed-point atomic pair
__device__ __forceinline__ void block_acc(float sumx, float sumy, float* sRed,
                                          unsigned long long* slot) {
    for (int off = 32; off > 0; off >>= 1) {
        sumx += __shfl_down(sumx, off, 64);
        sumy += __shfl_down(sumy, off, 64);
    }
    const int tid = threadIdx.x;
    const int wid = tid >> 6;
    if ((tid & 63) == 0) { sRed[wid] = sumx; sRed[4 + wid] = sumy; }
    __syncthreads();
    if (tid == 0) {
        float fx = sRed[0] + sRed[1] + sRed[2] + sRed[3];
        float fy = sRed[4] + sRed[5] + sRed[6] + sRed[7];
        atomicAdd(&slot[0], (unsigned long long)((double)fx * SCFP + 0.5));
        atomicAdd(&slot[1], (unsigned long long)((double)fy * SCFP + 0.5));
    }
}

// mode: 0 = write packed only; 1 = packed + f32 outs (step 49);
//       2 = f32 outs + sp, no packed/state (step 50). first: t==1 (m,v implicit zero)
__global__ __launch_bounds__(256, 8)
void k_step(const float* __restrict__ S,
            const unsigned* __restrict__ dxy,
            const unsigned* __restrict__ pPrev, unsigned* __restrict__ pCur,
            unsigned* __restrict__ mP, unsigned* __restrict__ vP,
            const unsigned long long* __restrict__ accPrev,
            unsigned long long* __restrict__ accCur,
            float a_step, float inv_bc2, int mode, int first,
            float* __restrict__ outx, float* __restrict__ outy,
            float* __restrict__ sp)
{
    __shared__ __align__(16) unsigned sP[36][40];    // phi strip packed half2
    __shared__ __align__(16) unsigned sC1[34][36];   // Sobel-corr packed half2
    __shared__ __align__(16) unsigned sC2[34][36];
    __shared__ float sRed[8];

    const int tid = threadIdx.x;
    const int cgi = tid & 7;
    const int rr  = tid >> 3;
    const int x0  = blockIdx.x * 32;
    const int y0  = blockIdx.y * 32;
    const size_t base = (size_t)blockIdx.z * HWd;
    const int gy = y0 + rr;
    const int gxb = x0 + 4 * cgi;
    const size_t idx = base + (size_t)gy * Wd + gxb;

    // ---- hoisted global loads: latency hides under the LDS phases ----
    uint4 d4 = *(const uint4*)(dxy + idx);
    uint4 mp4 = make_uint4(0u, 0u, 0u, 0u), vp4 = make_uint4(0u, 0u, 0u, 0u);
    if (!first) { mp4 = *(const uint4*)(mP + idx); vp4 = *(const uint4*)(vP + idx); }
    float4 s4 = make_float4(0.f, 0.f, 0.f, 0.f);
    if (mode == 2) s4 = *(const float4*)(S + idx);

    // ---- strip load: 360 uint4 tasks, stored packed ----
#pragma unroll
    for (int k = 0; k < 2; ++k) {
        int task = tid + (k << 8);
        if (task < 360) {
            int u = (task * 205) >> 11;          // task/10 exact for task<360
            int v = task - 10 * u;
            int gyy = y0 - 2 + u, gxx = x0 - 4 + 4 * v;
            uint4 w = make_uint4(0u, 0u, 0u, 0u);
            if ((unsigned)gyy < 256u && (unsigned)gxx < 256u)
                w = *(const uint4*)(pPrev + base + (size_t)gyy * Wd + gxx);
            *(uint4*)&sP[u][4 * v] = w;
        }
    }

    // ---- SSB coef prologue on wave 3 only (overlaps strip load) ----
    if (tid >= 192) {
        int l = tid - 192;
        unsigned long long ax = accPrev[l * 8];
        unsigned long long ay = accPrev[l * 8 + 1];
#pragma unroll
        for (int off = 1; off < 64; off <<= 1) {
            ax += __shfl_xor(ax, off, 64);
            ay += __shfl_xor(ay, off, 64);
        }
        if (l == 0) {
            double axd = (double)ax * (1.0 / SCFP);
            double ayd = (double)ay * (1.0 / SCFP);
            double nxd = sqrt(axd), nyd = sqrt(ayd);
            double pnd = nxd + nyd;
            double uu = pnd * pnd - 0.01;             // V^2
            double sg = (uu > 0.0) ? 1.0 : ((uu < 0.0) ? -1.0 : 0.0);
            sRed[6] = (float)(0.2 * sg * pnd / nxd);
            sRed[7] = (float)(0.2 * sg * pnd / nyd);
        }
    }
    __syncthreads();
    const float coefx = sRed[6];
    const float coefy = sRed[7];

    const __half2 k8 = __float2half2_rn(0.125f);
    const __half2 k4 = __float2half2_rn(0.25f);

    // ---- c-stage, packed both fields: 306 tasks (34 rows x 9 col groups) ----
#pragma unroll
    for (int k = 0; k < 2; ++k) {
        int task = tid + (k << 8);
        if (task < 306) {
            int a = (task * 57) >> 9;            // task/9 exact for task<306
            int v = task - 9 * a;
            int gyy = y0 - 1 + a;
            uint4 c1o = make_uint4(0u, 0u, 0u, 0u);
            uint4 c2o = make_uint4(0u, 0u, 0u, 0u);
            if ((unsigned)gyy < 256u) {
                uint4 T0 = *(uint4*)&sP[a][4 * v];     uint4 T1 = *(uint4*)&sP[a][4 * v + 4];
                uint4 M0 = *(uint4*)&sP[a + 1][4 * v]; uint4 M1 = *(uint4*)&sP[a + 1][4 * v + 4];
                uint4 B0 = *(uint4*)&sP[a + 2][4 * v]; uint4 B1 = *(uint4*)&sP[a + 2][4 * v + 4];
                __half2 wt[6] = {ash2(T0.x), ash2(T0.y), ash2(T0.z), ash2(T0.w), ash2(T1.x), ash2(T1.y)};
                __half2 wm[6] = {ash2(M0.x), ash2(M0.y), ash2(M0.z), ash2(M0.w), ash2(M1.x), ash2(M1.y)};
                __half2 wb[6] = {ash2(B0.x), ash2(B0.y), ash2(B0.z), ash2(B0.w), ash2(B1.x), ash2(B1.y)};
                unsigned c1u[4], c2u[4];
#pragma unroll
                for (int jj = 0; jj < 4; ++jj) {
                    __half2 c1 = __hfma2(k4, __hsub2(wm[jj + 2], wm[jj]),
                                 __hmul2(k8, __hadd2(__hsub2(wt[jj + 2], wt[jj]),
                                                     __hsub2(wb[jj + 2], wb[jj]))));
                    __half2 c2 = __hfma2(k4, __hsub2(wb[jj + 1], wt[jj + 1]),
                                 __hmul2(k8, __hadd2(__hsub2(wb[jj], wt[jj]),
                                                     __hsub2(wb[jj + 2], wt[jj + 2]))));
                    unsigned msk = ((unsigned)(x0 + 4 * v - 3 + jj) < 256u) ? 0xFFFFFFFFu : 0u;
                    c1u[jj] = asu32(c1) & msk;
                    c2u[jj] = asu32(c2) & msk;
                }
                c1o = make_uint4(c1u[0], c1u[1], c1u[2], c1u[3]);
                c2o = make_uint4(c2u[0], c2u[1], c2u[2], c2u[3]);
            }
            *(uint4*)&sC1[a][4 * v] = c1o;
            *(uint4*)&sC2[a][4 * v] = c2o;
        }
    }
    __syncthreads();

    // ---- d-stage, packed: second Sobel corr + center phi ----
    float dKx[4], dKy[4], pxa[4], pya[4];
    {
        uint4 pw = *(uint4*)&sP[rr + 2][4 * cgi + 4];
        unsigned pwv[4] = {pw.x, pw.y, pw.z, pw.w};
#pragma unroll
        for (int j = 0; j < 4; ++j) {
            float2 f = __half22float2(ash2(pwv[j]));
            pxa[j] = f.x; pya[j] = f.y;
        }
        const int cb = 4 * cgi;
        uint4 U0a = *(uint4*)&sC1[rr][cb];     uint4 U0b = *(uint4*)&sC1[rr][cb + 4];
        uint4 U1a = *(uint4*)&sC1[rr + 1][cb]; uint4 U1b = *(uint4*)&sC1[rr + 1][cb + 4];
        uint4 U2a = *(uint4*)&sC1[rr + 2][cb]; uint4 U2b = *(uint4*)&sC1[rr + 2][cb + 4];
        uint4 V0a = *(uint4*)&sC2[rr][cb];     uint4 V0b = *(uint4*)&sC2[rr][cb + 4];
        uint4 V2a = *(uint4*)&sC2[rr + 2][cb]; uint4 V2b = *(uint4*)&sC2[rr + 2][cb + 4];
        __half2 u0[8] = {ash2(U0a.x), ash2(U0a.y), ash2(U0a.z), ash2(U0a.w),
                         ash2(U0b.x), ash2(U0b.y), ash2(U0b.z), ash2(U0b.w)};
        __half2 u1[8] = {ash2(U1a.x), ash2(U1a.y), ash2(U1a.z), ash2(U1a.w),
                         ash2(U1b.x), ash2(U1b.y), ash2(U1b.z), ash2(U1b.w)};
        __half2 u2[8] = {ash2(U2a.x), ash2(U2a.y), ash2(U2a.z), ash2(U2a.w),
                         ash2(U2b.x), ash2(U2b.y), ash2(U2b.z), ash2(U2b.w)};
        __half2 t0[8] = {ash2(V0a.x), ash2(V0a.y), ash2(V0a.z), ash2(V0a.w),
                         ash2(V0b.x), ash2(V0b.y), ash2(V0b.z), ash2(V0b.w)};
        __half2 t2[8] = {ash2(V2a.x), ash2(V2a.y), ash2(V2a.z), ash2(V2a.w),
                         ash2(V2b.x), ash2(V2b.y), ash2(V2b.z), ash2(V2b.w)};
#pragma unroll
        for (int jj = 0; jj < 4; ++jj) {
            __half2 A = __hadd2(__hadd2(__hsub2(u0[jj + 4], u0[jj + 2]),
                                        __hsub2(u2[jj + 4], u2[jj + 2])),
                                __hadd2(__hsub2(t2[jj + 2], t0[jj + 2]),
                                        __hsub2(t2[jj + 4], t0[jj + 4])));
            __half2 B = __hadd2(__hsub2(u1[jj + 4], u1[jj + 2]),
                                __hsub2(t2[jj + 3], t0[jj + 3]));
            __half2 dk = __hfma2(k4, B, __hmul2(k8, A));
            float2 f = __half22float2(dk);
            dKx[jj] = f.x; dKy[jj] = f.y;
        }
    }

    // ---- pointwise grad + Adam (dx,dy,void from precomputed pack) ----
    unsigned duv[4] = {d4.x, d4.y, d4.z, d4.w};
    unsigned mpv[4] = {mp4.x, mp4.y, mp4.z, mp4.w};
    unsigned vpv[4] = {vp4.x, vp4.y, vp4.z, vp4.w};
    float sa[4] = {s4.x, s4.y, s4.z, s4.w};

    unsigned nmw[4], nvw[4], npk[4];
    float npx[4], npy[4], spv[4];
    float sumx = 0.f, sumy = 0.f;
#pragma unroll
    for (int j = 0; j < 4; ++j) {
        float2 dd = __half22float2(ash2(duv[j]));
        float dx_ = dd.x, dy_ = dd.y;
        float vmc = (duv[j] & 1u) ? C_VOID : 0.f;
        float R = pxa[j] * dx_ + pya[j] * dy_;
        float gx_ = C_COUP * R * dx_ - C_KIN * dKx[j] + (coefx + vmc) * pxa[j];
        float gy_ = C_COUP * R * dy_ - C_KIN * dKy[j] + (coefy + vmc) * pya[j];

        float m1 = first ? (0.1f * gx_) : (0.9f * bflo(mpv[j]) + 0.1f * gx_);
        float v1 = first ? (0.001f * gx_ * gx_) : (0.999f * bflo(vpv[j]) + 0.001f * gx_ * gx_);
        npx[j] = pxa[j] - __fdividef(a_step * m1, sqrtf(v1 * inv_bc2) + 1e-8f);
        sumx += npx[j] * npx[j];

        float m2 = first ? (0.1f * gy_) : (0.9f * bfhi(mpv[j]) + 0.1f * gy_);
        float v2 = first ? (0.001f * gy_ * gy_) : (0.999f * bfhi(vpv[j]) + 0.001f * gy_ * gy_);
        npy[j] = pya[j] - __fdividef(a_step * m2, sqrtf(v2 * inv_bc2) + 1e-8f);
        sumy += npy[j] * npy[j];

        nmw[j] = bfpack(m1, m2);
        nvw[j] = bfpack(v1, v2);
        npk[j] = packh2z(npx[j], npy[j]);
        spv[j] = sa[j] + R;
    }
    if (mode != 2) {   // last step: state never read again
        *(uint4*)(mP + idx) = make_uint4(nmw[0], nmw[1], nmw[2], nmw[3]);
        *(uint4*)(vP + idx) = make_uint4(nvw[0], nvw[1], nvw[2], nvw[3]);
        *(uint4*)(pCur + idx) = make_uint4(npk[0], npk[1], npk[2], npk[3]);
    }
    if (mode != 0) {
        *(float4*)(outx + idx) = make_float4(npx[0], npx[1], npx[2], npx[3]);
        *(float4*)(outy + idx) = make_float4(npy[0], npy[1], npy[2], npy[3]);
    }
    if (mode == 2)
        *(float4*)(sp + idx) = make_float4(spv[0], spv[1], spv[2], spv[3]);

    block_acc(sumx, sumy, sRed, accCur + (size_t)blockIdx.z * 8);
}

// init: pack phi0 -> p0, precompute packed (dx,dy,void) from S, ||phi0||^2
__global__ __launch_bounds__(256)
void k_init(const float* __restrict__ S,
            const float* __restrict__ px0, const float* __restrict__ py0,
            unsigned* __restrict__ p0, unsigned* __restrict__ dxy,
            unsigned long long* __restrict__ acc0)
{
    __shared__ float sRed[8];
    const int tid = threadIdx.x;
    float sx = 0.f, sy = 0.f;
#pragma unroll
    for (int k = 0; k < 2; ++k) {
        size_t idx = (size_t)blockIdx.x * 2048 + (size_t)(k * 1024 + tid * 4);
        float4 x = *(const float4*)(px0 + idx);
        float4 y = *(const float4*)(py0 + idx);
        *(uint4*)(p0 + idx) = make_uint4(packh2(x.x, y.x), packh2(x.y, y.y),
                                         packh2(x.z, y.z), packh2(x.w, y.w));
        sx += x.x * x.x + x.y * x.y + x.z * x.z + x.w * x.w;
        sy += y.x * y.x + y.y * y.y + y.z * y.z + y.w * y.w;

        // dx,dy,void pack
        int col = (int)(idx & 255u);
        int row = (int)((idx >> 8) & 255u);
        float4 s4 = *(const float4*)(S + idx);
        float sa[4] = {s4.x, s4.y, s4.z, s4.w};
        float sE = (col + 4 < 256) ? S[idx + 4] : 0.f;
        float4 sD = (row < 255) ? *(const float4*)(S + idx + 256) : make_float4(0.f, 0.f, 0.f, 0.f);
        float sd[4] = {sD.x, sD.y, sD.z, sD.w};
        unsigned du[4];
#pragma unroll
        for (int j = 0; j < 4; ++j) {
            float dx_ = (j < 3) ? (sa[j + 1] - sa[j]) : ((col + 4 < 256) ? (sE - sa[3]) : 0.f);
            float dy_ = (row < 255) ? (sd[j] - sa[j]) : 0.f;
            unsigned u = packh2(dx_, dy_);
            du[j] = (u & ~1u) | ((sa[j] < 0.05f) ? 1u : 0u);
        }
        *(uint4*)(dxy + idx) = make_uint4(du[0], du[1], du[2], du[3]);
    }
    block_acc(sx, sy, sRed, acc0 + (size_t)(blockIdx.x & (NSLOT - 1)) * 8);
}

extern "C" void kernel_launch(void* const* d_in, const int* in_sizes, int n_in,
                              void* d_out, int out_size, void* d_ws, size_t ws_size,
                              hipStream_t stream) {
    (void)in_sizes; (void)n_in; (void)out_size; (void)ws_size;
    const float* S   = (const float*)d_in[0];
    const float* px0 = (const float*)d_in[1];
    const float* py0 = (const float*)d_in[2];
    float* out = (float*)d_out;

    float* sp     = out;                      // slot 0: Sp
    float* outA_x = out + (size_t)NTOT;       // slot 1: phi_x post
    float* outA_y = out + 2 * (size_t)NTOT;   // slot 2: phi_y post
    float* outB_x = out + 3 * (size_t)NTOT;   // slot 3: phi_x pre
    float* outB_y = out + 4 * (size_t)NTOT;   // slot 4: phi_y pre

    unsigned* ws = (unsigned*)d_ws;
    unsigned* p0 = ws;                        // packed (fp16 phix, fp16 phiy), 16 MB
    unsigned* p1 = p0 + (size_t)NTOT;         // ping-pong partner, 16 MB
    unsigned* mP = p1 + (size_t)NTOT;         // packed (bf16 mx, bf16 my), 16 MB
    unsigned* vP = mP + (size_t)NTOT;         // packed (bf16 vx, bf16 vy), 16 MB
    unsigned* dxy = vP + (size_t)NTOT;        // packed (fp16 dx, fp16 dy | void), 16 MB
    unsigned long long* acc = (unsigned long long*)(dxy + (size_t)NTOT);  // [NACC][NSLOT][8]

    hipMemsetAsync(acc, 0, (size_t)NACC * NSLOT * 8 * sizeof(unsigned long long), stream);

    dim3 grid(8, 8, 64), blk(256, 1, 1);

    k_init<<<2048, 256, 0, stream>>>(S, px0, py0, p0, dxy, acc);

    for (int t = 1; t <= 50; ++t) {
        double bc1 = 1.0 - pow(0.9, (double)t);
        double bc2 = 1.0 - pow(0.999, (double)t);
        float a_step = (float)(0.05 / bc1);
        float inv_bc2 = (float)(1.0 / bc2);
        bool odd = (t & 1) != 0;
        const unsigned* pPrev = odd ? p0 : p1;
        unsigned* pCur = odd ? p1 : p0;
        int mode = (t == 49) ? 1 : ((t == 50) ? 2 : 0);
        float* ox = (t == 50) ? outA_x : outB_x;   // mode1 -> pre slots, mode2 -> post
        float* oy = (t == 50) ? outA_y : outB_y;
        k_step<<<grid, blk, 0, stream>>>(S, dxy, pPrev, pCur, mP, vP,
                                         acc + (size_t)(t - 1) * NSLOT * 8,
                                         acc + (size_t)t * NSLOT * 8,
                                         a_step, inv_bc2, mode, (t == 1) ? 1 : 0,
                                         ox, oy, sp);
    }
}

// Round 12
// 1579.298 us; speedup vs baseline: 8.8895x; 1.0064x over previous
//
#include <hip/hip_runtime.h>
#include <hip/hip_fp16.h>
#include <cmath>

#define Wd 256
#define Hd 256
#define HWd 65536
#define NTOT 4194304
#define NACC 51
#define NSLOT 64                     // atomic slots per step, one 64B line each

#define C_COUP (2.0f / 4194304.0f)   // 2*COUPLING/N
#define C_KIN  (0.2f / 4194304.0f)   // 2*ALPHA/N
#define C_VOID 0.0098f               // 2*GAMMA^2
#define SCFP 68719476736.0           // 2^36 fixed-point scale

// ---- packed bf16 pair helpers for Adam state ----
__device__ __forceinline__ float bflo(unsigned w) { return __uint_as_float(w << 16); }
__device__ __forceinline__ float bfhi(unsigned w) { return __uint_as_float(w & 0xFFFF0000u); }
// hardware pack: lo=bf16(a), hi=bf16(b), RNE (deterministic)
__device__ __forceinline__ unsigned bfpack(float a, float b) {
    unsigned r;
    asm volatile("v_cvt_pk_bf16_f32 %0, %1, %2" : "=v"(r) : "v"(a), "v"(b));
    return r;
}

// ---- packed fp16 pair helpers (deterministic) ----
__device__ __forceinline__ unsigned packh2(float a, float b) {
    __half2 h = __floats2half2_rn(a, b);
    return *(unsigned*)&h;
}
// hardware pack RTZ (1 instr) for the phi ping-pong
__device__ __forceinline__ unsigned packh2z(float a, float b) {
    auto h = __builtin_amdgcn_cvt_pkrtz(a, b);
    return *(unsigned*)&h;
}
__device__ __forceinline__ __half2 ash2(unsigned w) { return *(__half2*)&w; }
__device__ __forceinline__ unsigned asu32(__half2 h) { return *(unsigned*)&h; }

// block-level reduce of phi^2 sums -> one deterministic fixed-point atomic pair
__device__ __forceinline__ void block_acc(float sumx, float sumy, float* sRed,
                                          unsigned long long* slot) {
    for (int off = 32; off > 0; off >>= 1) {
        sumx += __shfl_down(sumx, off, 64);
        sumy += __shfl_down(sumy, off, 64);
    }
    const int tid = threadIdx.x;
    const int wid = tid >> 6;
    if ((tid & 63) == 0) { sRed[wid] = sumx; sRed[4 + wid] = sumy; }
    __syncthreads();
    if (tid == 0) {
        float fx = sRed[0] + sRed[1] + sRed[2] + sRed[3];
        float fy = sRed[4] + sRed[5] + sRed[6] + sRed[7];
        atomicAdd(&slot[0], (unsigned long long)((double)fx * SCFP + 0.5));
        atomicAdd(&slot[1], (unsigned long long)((double)fy * SCFP + 0.5));
    }
}

// mode: 0 = write packed only; 1 = packed + f32 outs (step 49);
//       2 = f32 outs + sp, no packed/state (step 50). first: t==1 (m,v implicit zero)
__global__ __launch_bounds__(256, 8)
void k_step(const float* __restrict__ S,
            const unsigned* __restrict__ dxy,
            const unsigned* __restrict__ pPrev, unsigned* __restrict__ pCur,
            unsigned* __restrict__ mP, unsigned* __restrict__ vP,
            const unsigned long long* __restrict__ accPrev,
            unsigned long long* __restrict__ accCur,
            float a_step, float inv_bc2, int mode, int first,
            float* __restrict__ outx, float* __restrict__ outy,
            float* __restrict__ sp)
{
    __shared__ __align__(16) unsigned sP[36][40];    // phi strip packed half2
    __shared__ __align__(16) unsigned sC1[34][40];   // stride 40: 2-way banks max
    __shared__ __align__(16) unsigned sC2[34][40];
    __shared__ float sRed[8];

    const int tid = threadIdx.x;
    const int cgi = tid & 7;
    const int rr  = tid >> 3;
    const int x0  = blockIdx.x * 32;
    const int y0  = blockIdx.y * 32;
    const size_t base = (size_t)blockIdx.z * HWd;
    const int gy = y0 + rr;
    const int gxb = x0 + 4 * cgi;
    const size_t idx = base + (size_t)gy * Wd + gxb;
    const bool interior = (blockIdx.x != 0) & (blockIdx.x != 7) &
                          (blockIdx.y != 0) & (blockIdx.y != 7);

    // ---- hoisted global loads: latency hides under the LDS phases ----
    uint4 d4 = *(const uint4*)(dxy + idx);
    uint4 mp4 = make_uint4(0u, 0u, 0u, 0u), vp4 = make_uint4(0u, 0u, 0u, 0u);
    if (!first) { mp4 = *(const uint4*)(mP + idx); vp4 = *(const uint4*)(vP + idx); }
    float4 s4 = make_float4(0.f, 0.f, 0.f, 0.f);
    if (mode == 2) s4 = *(const float4*)(S + idx);

    // ---- strip load: 360 uint4 tasks, stored packed ----
    if (interior) {
#pragma unroll
        for (int k = 0; k < 2; ++k) {
            int task = tid + (k << 8);
            if (task < 360) {
                int u = (task * 205) >> 11;      // task/10 exact for task<360
                int v = task - 10 * u;
                *(uint4*)&sP[u][4 * v] =
                    *(const uint4*)(pPrev + base + (size_t)(y0 - 2 + u) * Wd + (x0 - 4 + 4 * v));
            }
        }
    } else {
#pragma unroll
        for (int k = 0; k < 2; ++k) {
            int task = tid + (k << 8);
            if (task < 360) {
                int u = (task * 205) >> 11;
                int v = task - 10 * u;
                int gyy = y0 - 2 + u, gxx = x0 - 4 + 4 * v;
                uint4 w = make_uint4(0u, 0u, 0u, 0u);
                if ((unsigned)gyy < 256u && (unsigned)gxx < 256u)
                    w = *(const uint4*)(pPrev + base + (size_t)gyy * Wd + gxx);
                *(uint4*)&sP[u][4 * v] = w;
            }
        }
    }

    // ---- SSB coef prologue on wave 3 only (overlaps strip load) ----
    if (tid >= 192) {
        int l = tid - 192;
        unsigned long long ax = accPrev[l * 8];
        unsigned long long ay = accPrev[l * 8 + 1];
#pragma unroll
        for (int off = 1; off < 64; off <<= 1) {
            ax += __shfl_xor(ax, off, 64);
            ay += __shfl_xor(ay, off, 64);
        }
        if (l == 0) {
            double axd = (double)ax * (1.0 / SCFP);
            double ayd = (double)ay * (1.0 / SCFP);
            double nxd = sqrt(axd), nyd = sqrt(ayd);
            double pnd = nxd + nyd;
            double uu = pnd * pnd - 0.01;             // V^2
            double sg = (uu > 0.0) ? 1.0 : ((uu < 0.0) ? -1.0 : 0.0);
            sRed[6] = (float)(0.2 * sg * pnd / nxd);
            sRed[7] = (float)(0.2 * sg * pnd / nyd);
        }
    }
    __syncthreads();
    const float coefx = sRed[6];
    const float coefy = sRed[7];

    const __half2 k8 = __float2half2_rn(0.125f);
    const __half2 k4 = __float2half2_rn(0.25f);

    // ---- c-stage, packed both fields: 306 tasks (34 rows x 9 col groups) ----
#pragma unroll
    for (int k = 0; k < 2; ++k) {
        int task = tid + (k << 8);
        if (task < 306) {
            int a = (task * 57) >> 9;            // task/9 exact for task<306
            int v = task - 9 * a;
            uint4 T0 = *(uint4*)&sP[a][4 * v];     uint4 T1 = *(uint4*)&sP[a][4 * v + 4];
            uint4 M0 = *(uint4*)&sP[a + 1][4 * v]; uint4 M1 = *(uint4*)&sP[a + 1][4 * v + 4];
            uint4 B0 = *(uint4*)&sP[a + 2][4 * v]; uint4 B1 = *(uint4*)&sP[a + 2][4 * v + 4];
            __half2 wt[6] = {ash2(T0.x), ash2(T0.y), ash2(T0.z), ash2(T0.w), ash2(T1.x), ash2(T1.y)};
            __half2 wm[6] = {ash2(M0.x), ash2(M0.y), ash2(M0.z), ash2(M0.w), ash2(M1.x), ash2(M1.y)};
            __half2 wb[6] = {ash2(B0.x), ash2(B0.y), ash2(B0.z), ash2(B0.w), ash2(B1.x), ash2(B1.y)};
            unsigned c1u[4], c2u[4];
            if (interior) {
#pragma unroll
                for (int jj = 0; jj < 4; ++jj) {
                    __half2 c1 = __hfma2(k4, __hsub2(wm[jj + 2], wm[jj]),
                                 __hmul2(k8, __hadd2(__hsub2(wt[jj + 2], wt[jj]),
                                                     __hsub2(wb[jj + 2], wb[jj]))));
                    __half2 c2 = __hfma2(k4, __hsub2(wb[jj + 1], wt[jj + 1]),
                                 __hmul2(k8, __hadd2(__hsub2(wb[jj], wt[jj]),
                                                     __hsub2(wb[jj + 2], wt[jj + 2]))));
                    c1u[jj] = asu32(c1);
                    c2u[jj] = asu32(c2);
                }
            } else {
                int gyy = y0 - 1 + a;
                bool rowok = (unsigned)gyy < 256u;
#pragma unroll
                for (int jj = 0; jj < 4; ++jj) {
                    __half2 c1 = __hfma2(k4, __hsub2(wm[jj + 2], wm[jj]),
                                 __hmul2(k8, __hadd2(__hsub2(wt[jj + 2], wt[jj]),
                                                     __hsub2(wb[jj + 2], wb[jj]))));
                    __half2 c2 = __hfma2(k4, __hsub2(wb[jj + 1], wt[jj + 1]),
                                 __hmul2(k8, __hadd2(__hsub2(wb[jj], wt[jj]),
                                                     __hsub2(wb[jj + 2], wt[jj + 2]))));
                    unsigned msk = (rowok && (unsigned)(x0 + 4 * v - 3 + jj) < 256u)
                                   ? 0xFFFFFFFFu : 0u;
                    c1u[jj] = asu32(c1) & msk;
                    c2u[jj] = asu32(c2) & msk;
                }
            }
            *(uint4*)&sC1[a][4 * v] = make_uint4(c1u[0], c1u[1], c1u[2], c1u[3]);
            *(uint4*)&sC2[a][4 * v] = make_uint4(c2u[0], c2u[1], c2u[2], c2u[3]);
        }
    }
    __syncthreads();

    // ---- d-stage, packed: second Sobel corr + center phi ----
    float dKx[4], dKy[4], pxa[4], pya[4];
    {
        uint4 pw = *(uint4*)&sP[rr + 2][4 * cgi + 4];
        unsigned pwv[4] = {pw.x, pw.y, pw.z, pw.w};
#pragma unroll
        for (int j = 0; j < 4; ++j) {
            float2 f = __half22float2(ash2(pwv[j]));
            pxa[j] = f.x; pya[j] = f.y;
        }
        const int cb = 4 * cgi;
        uint4 U0a = *(uint4*)&sC1[rr][cb];     uint4 U0b = *(uint4*)&sC1[rr][cb + 4];
        uint4 U1a = *(uint4*)&sC1[rr + 1][cb]; uint4 U1b = *(uint4*)&sC1[rr + 1][cb + 4];
        uint4 U2a = *(uint4*)&sC1[rr + 2][cb]; uint4 U2b = *(uint4*)&sC1[rr + 2][cb + 4];
        uint4 V0a = *(uint4*)&sC2[rr][cb];     uint4 V0b = *(uint4*)&sC2[rr][cb + 4];
        uint4 V2a = *(uint4*)&sC2[rr + 2][cb]; uint4 V2b = *(uint4*)&sC2[rr + 2][cb + 4];
        __half2 u0[8] = {ash2(U0a.x), ash2(U0a.y), ash2(U0a.z), ash2(U0a.w),
                         ash2(U0b.x), ash2(U0b.y), ash2(U0b.z), ash2(U0b.w)};
        __half2 u1[8] = {ash2(U1a.x), ash2(U1a.y), ash2(U1a.z), ash2(U1a.w),
                         ash2(U1b.x), ash2(U1b.y), ash2(U1b.z), ash2(U1b.w)};
        __half2 u2[8] = {ash2(U2a.x), ash2(U2a.y), ash2(U2a.z), ash2(U2a.w),
                         ash2(U2b.x), ash2(U2b.y), ash2(U2b.z), ash2(U2b.w)};
        __half2 t0[8] = {ash2(V0a.x), ash2(V0a.y), ash2(V0a.z), ash2(V0a.w),
                         ash2(V0b.x), ash2(V0b.y), ash2(V0b.z), ash2(V0b.w)};
        __half2 t2[8] = {ash2(V2a.x), ash2(V2a.y), ash2(V2a.z), ash2(V2a.w),
                         ash2(V2b.x), ash2(V2b.y), ash2(V2b.z), ash2(V2b.w)};
#pragma unroll
        for (int jj = 0; jj < 4; ++jj) {
            __half2 A = __hadd2(__hadd2(__hsub2(u0[jj + 4], u0[jj + 2]),
                                        __hsub2(u2[jj + 4], u2[jj + 2])),
                                __hadd2(__hsub2(t2[jj + 2], t0[jj + 2]),
                                        __hsub2(t2[jj + 4], t0[jj + 4])));
            __half2 B = __hadd2(__hsub2(u1[jj + 4], u1[jj + 2]),
                                __hsub2(t2[jj + 3], t0[jj + 3]));
            __half2 dk = __hfma2(k4, B, __hmul2(k8, A));
            float2 f = __half22float2(dk);
            dKx[jj] = f.x; dKy[jj] = f.y;
        }
    }

    // ---- pointwise grad + Adam (dx,dy,void from precomputed pack) ----
    unsigned duv[4] = {d4.x, d4.y, d4.z, d4.w};
    unsigned mpv[4] = {mp4.x, mp4.y, mp4.z, mp4.w};
    unsigned vpv[4] = {vp4.x, vp4.y, vp4.z, vp4.w};
    float sa[4] = {s4.x, s4.y, s4.z, s4.w};

    unsigned nmw[4], nvw[4], npk[4];
    float npx[4], npy[4], spv[4];
    float sumx = 0.f, sumy = 0.f;
#pragma unroll
    for (int j = 0; j < 4; ++j) {
        float2 dd = __half22float2(ash2(duv[j]));
        float dx_ = dd.x, dy_ = dd.y;
        float vmc = (duv[j] & 1u) ? C_VOID : 0.f;
        float R = pxa[j] * dx_ + pya[j] * dy_;
        float gx_ = C_COUP * R * dx_ - C_KIN * dKx[j] + (coefx + vmc) * pxa[j];
        float gy_ = C_COUP * R * dy_ - C_KIN * dKy[j] + (coefy + vmc) * pya[j];

        float m1 = first ? (0.1f * gx_) : (0.9f * bflo(mpv[j]) + 0.1f * gx_);
        float v1 = first ? (0.001f * gx_ * gx_) : (0.999f * bflo(vpv[j]) + 0.001f * gx_ * gx_);
        npx[j] = pxa[j] - __fdividef(a_step * m1, sqrtf(v1 * inv_bc2) + 1e-8f);
        sumx += npx[j] * npx[j];

        float m2 = first ? (0.1f * gy_) : (0.9f * bfhi(mpv[j]) + 0.1f * gy_);
        float v2 = first ? (0.001f * gy_ * gy_) : (0.999f * bfhi(vpv[j]) + 0.001f * gy_ * gy_);
        npy[j] = pya[j] - __fdividef(a_step * m2, sqrtf(v2 * inv_bc2) + 1e-8f);
        sumy += npy[j] * npy[j];

        nmw[j] = bfpack(m1, m2);
        nvw[j] = bfpack(v1, v2);
        npk[j] = packh2z(npx[j], npy[j]);
        spv[j] = sa[j] + R;
    }
    if (mode != 2) {   // last step: state never read again
        *(uint4*)(mP + idx) = make_uint4(nmw[0], nmw[1], nmw[2], nmw[3]);
        *(uint4*)(vP + idx) = make_uint4(nvw[0], nvw[1], nvw[2], nvw[3]);
        *(uint4*)(pCur + idx) = make_uint4(npk[0], npk[1], npk[2], npk[3]);
    }
    if (mode != 0) {
        *(float4*)(outx + idx) = make_float4(npx[0], npx[1], npx[2], npx[3]);
        *(float4*)(outy + idx) = make_float4(npy[0], npy[1], npy[2], npy[3]);
    }
    if (mode == 2)
        *(float4*)(sp + idx) = make_float4(spv[0], spv[1], spv[2], spv[3]);

    block_acc(sumx, sumy, sRed, accCur + (size_t)blockIdx.z * 8);
}

// init: pack phi0 -> p0, precompute packed (dx,dy,void) from S, ||phi0||^2
__global__ __launch_bounds__(256)
void k_init(const float* __restrict__ S,
            const float* __restrict__ px0, const float* __restrict__ py0,
            unsigned* __restrict__ p0, unsigned* __restrict__ dxy,
            unsigned long long* __restrict__ acc0)
{
    __shared__ float sRed[8];
    const int tid = threadIdx.x;
    float sx = 0.f, sy = 0.f;
#pragma unroll
    for (int k = 0; k < 2; ++k) {
        size_t idx = (size_t)blockIdx.x * 2048 + (size_t)(k * 1024 + tid * 4);
        float4 x = *(const float4*)(px0 + idx);
        float4 y = *(const float4*)(py0 + idx);
        *(uint4*)(p0 + idx) = make_uint4(packh2(x.x, y.x), packh2(x.y, y.y),
                                         packh2(x.z, y.z), packh2(x.w, y.w));
        sx += x.x * x.x + x.y * x.y + x.z * x.z + x.w * x.w;
        sy += y.x * y.x + y.y * y.y + y.z * y.z + y.w * y.w;

        // dx,dy,void pack
        int col = (int)(idx & 255u);
        int row = (int)((idx >> 8) & 255u);
        float4 s4 = *(const float4*)(S + idx);
        float sa[4] = {s4.x, s4.y, s4.z, s4.w};
        float sE = (col + 4 < 256) ? S[idx + 4] : 0.f;
        float4 sD = (row < 255) ? *(const float4*)(S + idx + 256) : make_float4(0.f, 0.f, 0.f, 0.f);
        float sd[4] = {sD.x, sD.y, sD.z, sD.w};
        unsigned du[4];
#pragma unroll
        for (int j = 0; j < 4; ++j) {
            float dx_ = (j < 3) ? (sa[j + 1] - sa[j]) : ((col + 4 < 256) ? (sE - sa[3]) : 0.f);
            float dy_ = (row < 255) ? (sd[j] - sa[j]) : 0.f;
            unsigned u = packh2(dx_, dy_);
            du[j] = (u & ~1u) | ((sa[j] < 0.05f) ? 1u : 0u);
        }
        *(uint4*)(dxy + idx) = make_uint4(du[0], du[1], du[2], du[3]);
    }
    block_acc(sx, sy, sRed, acc0 + (size_t)(blockIdx.x & (NSLOT - 1)) * 8);
}

extern "C" void kernel_launch(void* const* d_in, const int* in_sizes, int n_in,
                              void* d_out, int out_size, void* d_ws, size_t ws_size,
                              hipStream_t stream) {
    (void)in_sizes; (void)n_in; (void)out_size; (void)ws_size;
    const float* S   = (const float*)d_in[0];
    const float* px0 = (const float*)d_in[1];
    const float* py0 = (const float*)d_in[2];
    float* out = (float*)d_out;

    float* sp     = out;                      // slot 0: Sp
    float* outA_x = out + (size_t)NTOT;       // slot 1: phi_x post
    float* outA_y = out + 2 * (size_t)NTOT;   // slot 2: phi_y post
    float* outB_x = out + 3 * (size_t)NTOT;   // slot 3: phi_x pre
    float* outB_y = out + 4 * (size_t)NTOT;   // slot 4: phi_y pre

    unsigned* ws = (unsigned*)d_ws;
    unsigned* p0 = ws;                        // packed (fp16 phix, fp16 phiy), 16 MB
    unsigned* p1 = p0 + (size_t)NTOT;         // ping-pong partner, 16 MB
    unsigned* mP = p1 + (size_t)NTOT;         // packed (bf16 mx, bf16 my), 16 MB
    unsigned* vP = mP + (size_t)NTOT;         // packed (bf16 vx, bf16 vy), 16 MB
    unsigned* dxy = vP + (size_t)NTOT;        // packed (fp16 dx, fp16 dy | void), 16 MB
    unsigned long long* acc = (unsigned long long*)(dxy + (size_t)NTOT);  // [NACC][NSLOT][8]

    hipMemsetAsync(acc, 0, (size_t)NACC * NSLOT * 8 * sizeof(unsigned long long), stream);

    dim3 grid(8, 8, 64), blk(256, 1, 1);

    k_init<<<2048, 256, 0, stream>>>(S, px0, py0, p0, dxy, acc);

    for (int t = 1; t <= 50; ++t) {
        double bc1 = 1.0 - pow(0.9, (double)t);
        double bc2 = 1.0 - pow(0.999, (double)t);
        float a_step = (float)(0.05 / bc1);
        float inv_bc2 = (float)(1.0 / bc2);
        bool odd = (t & 1) != 0;
        const unsigned* pPrev = odd ? p0 : p1;
        unsigned* pCur = odd ? p1 : p0;
        int mode = (t == 49) ? 1 : ((t == 50) ? 2 : 0);
        float* ox = (t == 50) ? outA_x : outB_x;   // mode1 -> pre slots, mode2 -> post
        float* oy = (t == 50) ? outA_y : outB_y;
        k_step<<<grid, blk, 0, stream>>>(S, dxy, pPrev, pCur, mP, vP,
                                         acc + (size_t)(t - 1) * NSLOT * 8,
                                         acc + (size_t)t * NSLOT * 8,
                                         a_step, inv_bc2, mode, (t == 1) ? 1 : 0,
                                         ox, oy, sp);
    }
}

// Round 13
// 1415.875 us; speedup vs baseline: 9.9156x; 1.1154x over previous
//
#include <hip/hip_runtime.h>
#include <hip/hip_fp16.h>
#include <cmath>

#define Wd 256
#define Hd 256
#define HWd 65536
#define NTOT 4194304
#define NACC 51
#define NSLOT 64                     // atomic slots per step, one 64B line each

#define C_COUP (2.0f / 4194304.0f)   // 2*COUPLING/N
#define C_KIN  (0.2f / 4194304.0f)   // 2*ALPHA/N
#define C_VOID 0.0098f               // 2*GAMMA^2
#define SCFP 68719476736.0           // 2^36 fixed-point scale

// ---- packed bf16 pair helpers for Adam state ----
__device__ __forceinline__ float bflo(unsigned w) { return __uint_as_float(w << 16); }
__device__ __forceinline__ float bfhi(unsigned w) { return __uint_as_float(w & 0xFFFF0000u); }
// hardware pack: lo=bf16(a), hi=bf16(b), RNE (deterministic)
__device__ __forceinline__ unsigned bfpack(float a, float b) {
    unsigned r;
    asm volatile("v_cvt_pk_bf16_f32 %0, %1, %2" : "=v"(r) : "v"(a), "v"(b));
    return r;
}

// ---- packed fp16 pair helpers (deterministic) ----
__device__ __forceinline__ unsigned packh2(float a, float b) {
    __half2 h = __floats2half2_rn(a, b);
    return *(unsigned*)&h;
}
// hardware pack RTZ (1 instr) for the phi ping-pong
__device__ __forceinline__ unsigned packh2z(float a, float b) {
    auto h = __builtin_amdgcn_cvt_pkrtz(a, b);
    return *(unsigned*)&h;
}
__device__ __forceinline__ __half2 ash2(unsigned w) { return *(__half2*)&w; }
__device__ __forceinline__ unsigned asu32(__half2 h) { return *(unsigned*)&h; }

// block-level reduce of phi^2 sums -> one deterministic fixed-point atomic pair
__device__ __forceinline__ void block_acc(float sumx, float sumy, float* sRed,
                                          unsigned long long* slot) {
    for (int off = 32; off > 0; off >>= 1) {
        sumx += __shfl_down(sumx, off, 64);
        sumy += __shfl_down(sumy, off, 64);
    }
    const int tid = threadIdx.x;
    const int wid = tid >> 6;
    if ((tid & 63) == 0) { sRed[wid] = sumx; sRed[4 + wid] = sumy; }
    __syncthreads();
    if (tid == 0) {
        float fx = sRed[0] + sRed[1] + sRed[2] + sRed[3];
        float fy = sRed[4] + sRed[5] + sRed[6] + sRed[7];
        atomicAdd(&slot[0], (unsigned long long)((double)fx * SCFP + 0.5));
        atomicAdd(&slot[1], (unsigned long long)((double)fy * SCFP + 0.5));
    }
}

// mode: 0 = write packed only; 1 = packed + f32 outs (step 49);
//       2 = f32 outs + sp, no packed/state (step 50). first: t==1 (m,v implicit zero)
__global__ __launch_bounds__(256, 8)
void k_step(const float* __restrict__ S,
            const unsigned* __restrict__ dxy,
            const unsigned* __restrict__ pPrev, unsigned* __restrict__ pCur,
            unsigned* __restrict__ mP, unsigned* __restrict__ vP,
            const unsigned long long* __restrict__ accPrev,
            unsigned long long* __restrict__ accCur,
            float a2, int mode, int first,
            float* __restrict__ outx, float* __restrict__ outy,
            float* __restrict__ sp)
{
    __shared__ __align__(16) unsigned sP[36][40];    // phi strip packed half2
    __shared__ __align__(16) unsigned sA[36][40];    // interior: row-pass D; border: c1
    __shared__ __align__(16) unsigned sB[36][40];    // interior: row-pass S; border: c2
    __shared__ float sRed[8];

    const int tid = threadIdx.x;
    const int cgi = tid & 7;
    const int rr  = tid >> 3;
    const int x0  = blockIdx.x * 32;
    const int y0  = blockIdx.y * 32;
    const size_t base = (size_t)blockIdx.z * HWd;
    const int gy = y0 + rr;
    const int gxb = x0 + 4 * cgi;
    const size_t idx = base + (size_t)gy * Wd + gxb;
    const bool interior = (blockIdx.x != 0) & (blockIdx.x != 7) &
                          (blockIdx.y != 0) & (blockIdx.y != 7);
    // composed 5x5 path produces dK*64 -> fold /64 into the kinetic constant
    const float ckin = interior ? (C_KIN * 0.015625f) : C_KIN;

    // ---- hoisted global loads: latency hides under the LDS phases ----
    uint4 d4 = *(const uint4*)(dxy + idx);
    uint4 mp4 = make_uint4(0u, 0u, 0u, 0u), vp4 = make_uint4(0u, 0u, 0u, 0u);
    if (!first) { mp4 = *(const uint4*)(mP + idx); vp4 = *(const uint4*)(vP + idx); }
    float4 s4 = make_float4(0.f, 0.f, 0.f, 0.f);
    if (mode == 2) s4 = *(const float4*)(S + idx);

    // ---- strip load: 360 uint4 tasks, stored packed ----
    if (interior) {
#pragma unroll
        for (int k = 0; k < 2; ++k) {
            int task = tid + (k << 8);
            if (task < 360) {
                int u = (task * 205) >> 11;      // task/10 exact for task<360
                int v = task - 10 * u;
                *(uint4*)&sP[u][4 * v] =
                    *(const uint4*)(pPrev + base + (size_t)(y0 - 2 + u) * Wd + (x0 - 4 + 4 * v));
            }
        }
    } else {
#pragma unroll
        for (int k = 0; k < 2; ++k) {
            int task = tid + (k << 8);
            if (task < 360) {
                int u = (task * 205) >> 11;
                int v = task - 10 * u;
                int gyy = y0 - 2 + u, gxx = x0 - 4 + 4 * v;
                uint4 w = make_uint4(0u, 0u, 0u, 0u);
                if ((unsigned)gyy < 256u && (unsigned)gxx < 256u)
                    w = *(const uint4*)(pPrev + base + (size_t)gyy * Wd + gxx);
                *(uint4*)&sP[u][4 * v] = w;
            }
        }
    }

    // ---- SSB coef prologue on wave 3 only (overlaps strip load) ----
    if (tid >= 192) {
        int l = tid - 192;
        unsigned long long ax = accPrev[l * 8];
        unsigned long long ay = accPrev[l * 8 + 1];
#pragma unroll
        for (int off = 1; off < 64; off <<= 1) {
            ax += __shfl_xor(ax, off, 64);
            ay += __shfl_xor(ay, off, 64);
        }
        if (l == 0) {
            double axd = (double)ax * (1.0 / SCFP);
            double ayd = (double)ay * (1.0 / SCFP);
            double nxd = sqrt(axd), nyd = sqrt(ayd);
            double pnd = nxd + nyd;
            double uu = pnd * pnd - 0.01;             // V^2
            double sg = (uu > 0.0) ? 1.0 : ((uu < 0.0) ? -1.0 : 0.0);
            sRed[6] = (float)(0.2 * sg * pnd / nxd);
            sRed[7] = (float)(0.2 * sg * pnd / nyd);
        }
    }
    __syncthreads();
    const float coefx = sRed[6];
    const float coefy = sRed[7];

    const __half2 k8 = __float2half2_rn(0.125f);
    const __half2 k4 = __float2half2_rn(0.25f);
    const __half2 h4 = __float2half2_rn(4.0f);
    const __half2 h6 = __float2half2_rn(6.0f);
    const __half2 hn2 = __float2half2_rn(-2.0f);

    float dKx[4], dKy[4], pxa[4], pya[4];

    if (interior) {
        // ---- row pass: 288 tasks (36 rows x 8 groups), composed-kernel halves
        //  A = phi[x-2] - 2 phi[x] + phi[x+2]   (D row)
        //  B = phi[x-2] + 4 phi[x-1] + 6 phi[x] + 4 phi[x+1] + phi[x+2]  (S row)
#pragma unroll
        for (int k = 0; k < 2; ++k) {
            int task = tid + (k << 8);
            if (task < 288) {
                int u = task >> 3, g = task & 7;
                uint4 W0 = *(uint4*)&sP[u][4 * g];
                uint4 W1 = *(uint4*)&sP[u][4 * g + 4];
                uint4 W2 = *(uint4*)&sP[u][4 * g + 8];
                __half2 w[12] = {ash2(W0.x), ash2(W0.y), ash2(W0.z), ash2(W0.w),
                                 ash2(W1.x), ash2(W1.y), ash2(W1.z), ash2(W1.w),
                                 ash2(W2.x), ash2(W2.y), ash2(W2.z), ash2(W2.w)};
                unsigned au[4], bu[4];
#pragma unroll
                for (int jj = 0; jj < 4; ++jj) {
                    __half2 e = __hadd2(w[2 + jj], w[6 + jj]);
                    __half2 A = __hfma2(hn2, w[4 + jj], e);
                    __half2 f = __hadd2(w[3 + jj], w[5 + jj]);
                    __half2 B = __hfma2(h6, w[4 + jj], __hfma2(h4, f, e));
                    au[jj] = asu32(A);
                    bu[jj] = asu32(B);
                }
                *(uint4*)&sA[u][4 * g] = make_uint4(au[0], au[1], au[2], au[3]);
                *(uint4*)&sB[u][4 * g] = make_uint4(bu[0], bu[1], bu[2], bu[3]);
            }
        }
        __syncthreads();

        // ---- column pass: dK_raw = S-col(A) + D-col(B) (scale folded in ckin)
        {
            uint4 pw = *(uint4*)&sP[rr + 2][4 * cgi + 4];
            unsigned pwv[4] = {pw.x, pw.y, pw.z, pw.w};
#pragma unroll
            for (int j = 0; j < 4; ++j) {
                float2 f = __half22float2(ash2(pwv[j]));
                pxa[j] = f.x; pya[j] = f.y;
            }
            const int cb = 4 * cgi;
            uint4 A0 = *(uint4*)&sA[rr][cb];
            uint4 A1 = *(uint4*)&sA[rr + 1][cb];
            uint4 A2 = *(uint4*)&sA[rr + 2][cb];
            uint4 A3 = *(uint4*)&sA[rr + 3][cb];
            uint4 A4 = *(uint4*)&sA[rr + 4][cb];
            uint4 B0 = *(uint4*)&sB[rr][cb];
            uint4 B2 = *(uint4*)&sB[rr + 2][cb];
            uint4 B4 = *(uint4*)&sB[rr + 4][cb];
            unsigned a0[4] = {A0.x, A0.y, A0.z, A0.w};
            unsigned a1[4] = {A1.x, A1.y, A1.z, A1.w};
            unsigned a2v[4] = {A2.x, A2.y, A2.z, A2.w};
            unsigned a3[4] = {A3.x, A3.y, A3.z, A3.w};
            unsigned a4[4] = {A4.x, A4.y, A4.z, A4.w};
            unsigned b0[4] = {B0.x, B0.y, B0.z, B0.w};
            unsigned b2[4] = {B2.x, B2.y, B2.z, B2.w};
            unsigned b4[4] = {B4.x, B4.y, B4.z, B4.w};
#pragma unroll
            for (int jj = 0; jj < 4; ++jj) {
                __half2 g1 = __hadd2(ash2(a0[jj]), ash2(a4[jj]));
                __half2 g2 = __hadd2(ash2(a1[jj]), ash2(a3[jj]));
                __half2 colA = __hfma2(h6, ash2(a2v[jj]), __hfma2(h4, g2, g1));
                __half2 g3 = __hadd2(ash2(b0[jj]), ash2(b4[jj]));
                __half2 colB = __hfma2(hn2, ash2(b2[jj]), g3);
                float2 f = __half22float2(__hadd2(colA, colB));
                dKx[jj] = f.x; dKy[jj] = f.y;
            }
        }
    } else {
        // ---- border: exact two-stage path (c-stage then d-stage) ----
#pragma unroll
        for (int k = 0; k < 2; ++k) {
            int task = tid + (k << 8);
            if (task < 306) {
                int a = (task * 57) >> 9;            // task/9 exact for task<306
                int v = task - 9 * a;
                uint4 T0 = *(uint4*)&sP[a][4 * v];     uint4 T1 = *(uint4*)&sP[a][4 * v + 4];
                uint4 M0 = *(uint4*)&sP[a + 1][4 * v]; uint4 M1 = *(uint4*)&sP[a + 1][4 * v + 4];
                uint4 B0 = *(uint4*)&sP[a + 2][4 * v]; uint4 B1 = *(uint4*)&sP[a + 2][4 * v + 4];
                __half2 wt[6] = {ash2(T0.x), ash2(T0.y), ash2(T0.z), ash2(T0.w), ash2(T1.x), ash2(T1.y)};
                __half2 wm[6] = {ash2(M0.x), ash2(M0.y), ash2(M0.z), ash2(M0.w), ash2(M1.x), ash2(M1.y)};
                __half2 wb[6] = {ash2(B0.x), ash2(B0.y), ash2(B0.z), ash2(B0.w), ash2(B1.x), ash2(B1.y)};
                int gyy = y0 - 1 + a;
                bool rowok = (unsigned)gyy < 256u;
                unsigned c1u[4], c2u[4];
#pragma unroll
                for (int jj = 0; jj < 4; ++jj) {
                    __half2 c1 = __hfma2(k4, __hsub2(wm[jj + 2], wm[jj]),
                                 __hmul2(k8, __hadd2(__hsub2(wt[jj + 2], wt[jj]),
                                                     __hsub2(wb[jj + 2], wb[jj]))));
                    __half2 c2 = __hfma2(k4, __hsub2(wb[jj + 1], wt[jj + 1]),
                                 __hmul2(k8, __hadd2(__hsub2(wb[jj], wt[jj]),
                                                     __hsub2(wb[jj + 2], wt[jj + 2]))));
                    unsigned msk = (rowok && (unsigned)(x0 + 4 * v - 3 + jj) < 256u)
                                   ? 0xFFFFFFFFu : 0u;
                    c1u[jj] = asu32(c1) & msk;
                    c2u[jj] = asu32(c2) & msk;
                }
                *(uint4*)&sA[a][4 * v] = make_uint4(c1u[0], c1u[1], c1u[2], c1u[3]);
                *(uint4*)&sB[a][4 * v] = make_uint4(c2u[0], c2u[1], c2u[2], c2u[3]);
            }
        }
        __syncthreads();
        {
            uint4 pw = *(uint4*)&sP[rr + 2][4 * cgi + 4];
            unsigned pwv[4] = {pw.x, pw.y, pw.z, pw.w};
#pragma unroll
            for (int j = 0; j < 4; ++j) {
                float2 f = __half22float2(ash2(pwv[j]));
                pxa[j] = f.x; pya[j] = f.y;
            }
            const int cb = 4 * cgi;
            uint4 U0a = *(uint4*)&sA[rr][cb];     uint4 U0b = *(uint4*)&sA[rr][cb + 4];
            uint4 U1a = *(uint4*)&sA[rr + 1][cb]; uint4 U1b = *(uint4*)&sA[rr + 1][cb + 4];
            uint4 U2a = *(uint4*)&sA[rr + 2][cb]; uint4 U2b = *(uint4*)&sA[rr + 2][cb + 4];
            uint4 V0a = *(uint4*)&sB[rr][cb];     uint4 V0b = *(uint4*)&sB[rr][cb + 4];
            uint4 V2a = *(uint4*)&sB[rr + 2][cb]; uint4 V2b = *(uint4*)&sB[rr + 2][cb + 4];
            __half2 u0[8] = {ash2(U0a.x), ash2(U0a.y), ash2(U0a.z), ash2(U0a.w),
                             ash2(U0b.x), ash2(U0b.y), ash2(U0b.z), ash2(U0b.w)};
            __half2 u1[8] = {ash2(U1a.x), ash2(U1a.y), ash2(U1a.z), ash2(U1a.w),
                             ash2(U1b.x), ash2(U1b.y), ash2(U1b.z), ash2(U1b.w)};
            __half2 u2[8] = {ash2(U2a.x), ash2(U2a.y), ash2(U2a.z), ash2(U2a.w),
                             ash2(U2b.x), ash2(U2b.y), ash2(U2b.z), ash2(U2b.w)};
            __half2 t0[8] = {ash2(V0a.x), ash2(V0a.y), ash2(V0a.z), ash2(V0a.w),
                             ash2(V0b.x), ash2(V0b.y), ash2(V0b.z), ash2(V0b.w)};
            __half2 t2[8] = {ash2(V2a.x), ash2(V2a.y), ash2(V2a.z), ash2(V2a.w),
                             ash2(V2b.x), ash2(V2b.y), ash2(V2b.z), ash2(V2b.w)};
#pragma unroll
            for (int jj = 0; jj < 4; ++jj) {
                __half2 A = __hadd2(__hadd2(__hsub2(u0[jj + 4], u0[jj + 2]),
                                            __hsub2(u2[jj + 4], u2[jj + 2])),
                                    __hadd2(__hsub2(t2[jj + 2], t0[jj + 2]),
                                            __hsub2(t2[jj + 4], t0[jj + 4])));
                __half2 B = __hadd2(__hsub2(u1[jj + 4], u1[jj + 2]),
                                    __hsub2(t2[jj + 3], t0[jj + 3]));
                __half2 dk = __hfma2(k4, B, __hmul2(k8, A));
                float2 f = __half22float2(dk);
                dKx[jj] = f.x; dKy[jj] = f.y;
            }
        }
    }

    // ---- pointwise grad + Adam (dx,dy,void precomputed; rsqrt update) ----
    unsigned duv[4] = {d4.x, d4.y, d4.z, d4.w};
    unsigned mpv[4] = {mp4.x, mp4.y, mp4.z, mp4.w};
    unsigned vpv[4] = {vp4.x, vp4.y, vp4.z, vp4.w};
    float sa[4] = {s4.x, s4.y, s4.z, s4.w};

    unsigned nmw[4], nvw[4], npk[4];
    float npx[4], npy[4], spv[4];
    float sumx = 0.f, sumy = 0.f;
#pragma unroll
    for (int j = 0; j < 4; ++j) {
        float2 dd = __half22float2(ash2(duv[j]));
        float dx_ = dd.x, dy_ = dd.y;
        float vmc = (duv[j] & 1u) ? C_VOID : 0.f;
        float R = pxa[j] * dx_ + pya[j] * dy_;
        float gx_ = C_COUP * R * dx_ - ckin * dKx[j] + (coefx + vmc) * pxa[j];
        float gy_ = C_COUP * R * dy_ - ckin * dKy[j] + (coefy + vmc) * pya[j];

        float m1 = first ? (0.1f * gx_) : (0.9f * bflo(mpv[j]) + 0.1f * gx_);
        float v1 = first ? (0.001f * gx_ * gx_) : (0.999f * bflo(vpv[j]) + 0.001f * gx_ * gx_);
        npx[j] = fmaf(-a2 * m1, __frsqrt_rn(v1), pxa[j]);
        sumx += npx[j] * npx[j];

        float m2 = first ? (0.1f * gy_) : (0.9f * bfhi(mpv[j]) + 0.1f * gy_);
        float v2 = first ? (0.001f * gy_ * gy_) : (0.999f * bfhi(vpv[j]) + 0.001f * gy_ * gy_);
        npy[j] = fmaf(-a2 * m2, __frsqrt_rn(v2), pya[j]);
        sumy += npy[j] * npy[j];

        nmw[j] = bfpack(m1, m2);
        nvw[j] = bfpack(v1, v2);
        npk[j] = packh2z(npx[j], npy[j]);
        spv[j] = sa[j] + R;
    }
    if (mode != 2) {   // last step: state never read again
        *(uint4*)(mP + idx) = make_uint4(nmw[0], nmw[1], nmw[2], nmw[3]);
        *(uint4*)(vP + idx) = make_uint4(nvw[0], nvw[1], nvw[2], nvw[3]);
        *(uint4*)(pCur + idx) = make_uint4(npk[0], npk[1], npk[2], npk[3]);
    }
    if (mode != 0) {
        *(float4*)(outx + idx) = make_float4(npx[0], npx[1], npx[2], npx[3]);
        *(float4*)(outy + idx) = make_float4(npy[0], npy[1], npy[2], npy[3]);
    }
    if (mode == 2)
        *(float4*)(sp + idx) = make_float4(spv[0], spv[1], spv[2], spv[3]);

    block_acc(sumx, sumy, sRed, accCur + (size_t)blockIdx.z * 8);
}

// init: pack phi0 -> p0, precompute packed (dx,dy,void) from S, ||phi0||^2
__global__ __launch_bounds__(256)
void k_init(const float* __restrict__ S,
            const float* __restrict__ px0, const float* __restrict__ py0,
            unsigned* __restrict__ p0, unsigned* __restrict__ dxy,
            unsigned long long* __restrict__ acc0)
{
    __shared__ float sRed[8];
    const int tid = threadIdx.x;
    float sx = 0.f, sy = 0.f;
#pragma unroll
    for (int k = 0; k < 2; ++k) {
        size_t idx = (size_t)blockIdx.x * 2048 + (size_t)(k * 1024 + tid * 4);
        float4 x = *(const float4*)(px0 + idx);
        float4 y = *(const float4*)(py0 + idx);
        *(uint4*)(p0 + idx) = make_uint4(packh2(x.x, y.x), packh2(x.y, y.y),
                                         packh2(x.z, y.z), packh2(x.w, y.w));
        sx += x.x * x.x + x.y * x.y + x.z * x.z + x.w * x.w;
        sy += y.x * y.x + y.y * y.y + y.z * y.z + y.w * y.w;

        // dx,dy,void pack
        int col = (int)(idx & 255u);
        int row = (int)((idx >> 8) & 255u);
        float4 s4 = *(const float4*)(S + idx);
        float sa[4] = {s4.x, s4.y, s4.z, s4.w};
        float sE = (col + 4 < 256) ? S[idx + 4] : 0.f;
        float4 sD = (row < 255) ? *(const float4*)(S + idx + 256) : make_float4(0.f, 0.f, 0.f, 0.f);
        float sd[4] = {sD.x, sD.y, sD.z, sD.w};
        unsigned du[4];
#pragma unroll
        for (int j = 0; j < 4; ++j) {
            float dx_ = (j < 3) ? (sa[j + 1] - sa[j]) : ((col + 4 < 256) ? (sE - sa[3]) : 0.f);
            float dy_ = (row < 255) ? (sd[j] - sa[j]) : 0.f;
            unsigned u = packh2(dx_, dy_);
            du[j] = (u & ~1u) | ((sa[j] < 0.05f) ? 1u : 0u);
        }
        *(uint4*)(dxy + idx) = make_uint4(du[0], du[1], du[2], du[3]);
    }
    block_acc(sx, sy, sRed, acc0 + (size_t)(blockIdx.x & (NSLOT - 1)) * 8);
}

extern "C" void kernel_launch(void* const* d_in, const int* in_sizes, int n_in,
                              void* d_out, int out_size, void* d_ws, size_t ws_size,
                              hipStream_t stream) {
    (void)in_sizes; (void)n_in; (void)out_size; (void)ws_size;
    const float* S   = (const float*)d_in[0];
    const float* px0 = (const float*)d_in[1];
    const float* py0 = (const float*)d_in[2];
    float* out = (float*)d_out;

    float* sp     = out;                      // slot 0: Sp
    float* outA_x = out + (size_t)NTOT;       // slot 1: phi_x post
    float* outA_y = out + 2 * (size_t)NTOT;   // slot 2: phi_y post
    float* outB_x = out + 3 * (size_t)NTOT;   // slot 3: phi_x pre
    float* outB_y = out + 4 * (size_t)NTOT;   // slot 4: phi_y pre

    unsigned* ws = (unsigned*)d_ws;
    unsigned* p0 = ws;                        // packed (fp16 phix, fp16 phiy), 16 MB
    unsigned* p1 = p0 + (size_t)NTOT;         // ping-pong partner, 16 MB
    unsigned* mP = p1 + (size_t)NTOT;         // packed (bf16 mx, bf16 my), 16 MB
    unsigned* vP = mP + (size_t)NTOT;         // packed (bf16 vx, bf16 vy), 16 MB
    unsigned* dxy = vP + (size_t)NTOT;        // packed (fp16 dx, fp16 dy | void), 16 MB
    unsigned long long* acc = (unsigned long long*)(dxy + (size_t)NTOT);  // [NACC][NSLOT][8]

    hipMemsetAsync(acc, 0, (size_t)NACC * NSLOT * 8 * sizeof(unsigned long long), stream);

    dim3 grid(8, 8, 64), blk(256, 1, 1);

    k_init<<<2048, 256, 0, stream>>>(S, px0, py0, p0, dxy, acc);

    for (int t = 1; t <= 50; ++t) {
        double bc1 = 1.0 - pow(0.9, (double)t);
        double bc2 = 1.0 - pow(0.999, (double)t);
        float a2 = (float)(0.05 / bc1 * sqrt(bc2));   // LR/bc1 * sqrt(bc2)
        bool odd = (t & 1) != 0;
        const unsigned* pPrev = odd ? p0 : p1;
        unsigned* pCur = odd ? p1 : p0;
        int mode = (t == 49) ? 1 : ((t == 50) ? 2 : 0);
        float* ox = (t == 50) ? outA_x : outB_x;   // mode1 -> pre slots, mode2 -> post
        float* oy = (t == 50) ? outA_y : outB_y;
        k_step<<<grid, blk, 0, stream>>>(S, dxy, pPrev, pCur, mP, vP,
                                         acc + (size_t)(t - 1) * NSLOT * 8,
                                         acc + (size_t)t * NSLOT * 8,
                                         a2, mode, (t == 1) ? 1 : 0,
                                         ox, oy, sp);
    }
}

// Round 14
// 1249.964 us; speedup vs baseline: 11.2317x; 1.1327x over previous
//
#include <hip/hip_runtime.h>
#include <hip/hip_fp16.h>
#include <cmath>

#define Wd 256
#define Hd 256
#define HWd 65536
#define NTOT 4194304
#define NACC 51
#define NSLOT 64                     // atomic slots per step, one 64B line each

#define C_COUP (2.0f / 4194304.0f)   // 2*COUPLING/N
#define C_KIN  (0.2f / 4194304.0f)   // 2*ALPHA/N
#define C_VOID 0.0098f               // 2*GAMMA^2
#define SCFP 68719476736.0           // 2^36 fixed-point scale

// ---- packed bf16 pair helpers for Adam state ----
__device__ __forceinline__ float bflo(unsigned w) { return __uint_as_float(w << 16); }
__device__ __forceinline__ float bfhi(unsigned w) { return __uint_as_float(w & 0xFFFF0000u); }
// hardware pack: lo=bf16(a), hi=bf16(b), RNE (deterministic)
__device__ __forceinline__ unsigned bfpack(float a, float b) {
    unsigned r;
    asm volatile("v_cvt_pk_bf16_f32 %0, %1, %2" : "=v"(r) : "v"(a), "v"(b));
    return r;
}

// ---- packed fp16 pair helpers (deterministic) ----
__device__ __forceinline__ unsigned packh2(float a, float b) {
    __half2 h = __floats2half2_rn(a, b);
    return *(unsigned*)&h;
}
// hardware pack RTZ (1 instr) for the phi ping-pong
__device__ __forceinline__ unsigned packh2z(float a, float b) {
    auto h = __builtin_amdgcn_cvt_pkrtz(a, b);
    return *(unsigned*)&h;
}
__device__ __forceinline__ __half2 ash2(unsigned w) { return *(__half2*)&w; }
__device__ __forceinline__ unsigned asu32(__half2 h) { return *(unsigned*)&h; }

// block-level reduce of phi^2 sums -> one deterministic fixed-point atomic pair
__device__ __forceinline__ void block_acc(float sumx, float sumy, float* sRed,
                                          unsigned long long* slot) {
    for (int off = 32; off > 0; off >>= 1) {
        sumx += __shfl_down(sumx, off, 64);
        sumy += __shfl_down(sumy, off, 64);
    }
    const int tid = threadIdx.x;
    const int wid = tid >> 6;
    if ((tid & 63) == 0) { sRed[wid] = sumx; sRed[4 + wid] = sumy; }
    __syncthreads();
    if (tid == 0) {
        float fx = sRed[0] + sRed[1] + sRed[2] + sRed[3];
        float fy = sRed[4] + sRed[5] + sRed[6] + sRed[7];
        atomicAdd(&slot[0], (unsigned long long)((double)fx * SCFP + 0.5));
        atomicAdd(&slot[1], (unsigned long long)((double)fy * SCFP + 0.5));
    }
}

// mode: 0 = write packed only; 1 = packed + f32 outs (step 49);
//       2 = f32 outs + sp, no packed/state (step 50). first: t==1 (m,v implicit zero)
__global__ __launch_bounds__(256, 8)
void k_step(const float* __restrict__ S,
            const unsigned* __restrict__ dxy,
            const unsigned* __restrict__ pPrev, unsigned* __restrict__ pCur,
            unsigned* __restrict__ mP, unsigned* __restrict__ vP,
            const unsigned long long* __restrict__ accPrev,
            unsigned long long* __restrict__ accCur,
            float a2, int mode, int first,
            float* __restrict__ outx, float* __restrict__ outy,
            float* __restrict__ sp)
{
    __shared__ __align__(16) unsigned sP[36][40];    // phi strip packed half2
    __shared__ __align__(16) unsigned sA[36][40];    // interior: row-pass D; border: c1
    __shared__ __align__(16) unsigned sB[36][40];    // interior: row-pass S; border: c2
    __shared__ float sRed[8];

    const int tid = threadIdx.x;
    const int cgi = tid & 7;
    const int rr  = tid >> 3;
    // XCD-aware bijective swizzle (4096 % 8 == 0): each XCD owns 8 full z-slices
    const int swz = ((blockIdx.x & 7) << 9) | (blockIdx.x >> 3);
    const int bx  = swz & 7;
    const int by  = (swz >> 3) & 7;
    const int zsl = swz >> 6;
    const int x0  = bx * 32;
    const int y0  = by * 32;
    const size_t base = (size_t)zsl * HWd;
    const int gy = y0 + rr;
    const int gxb = x0 + 4 * cgi;
    const size_t idx = base + (size_t)gy * Wd + gxb;
    const bool interior = (bx != 0) & (bx != 7) & (by != 0) & (by != 7);
    // composed 5x5 path produces dK*64 -> fold /64 into the kinetic constant
    const float ckin = interior ? (C_KIN * 0.015625f) : C_KIN;

    // ---- hoisted global loads: latency hides under the LDS phases ----
    uint4 d4 = *(const uint4*)(dxy + idx);
    uint4 mp4 = make_uint4(0u, 0u, 0u, 0u), vp4 = make_uint4(0u, 0u, 0u, 0u);
    if (!first) { mp4 = *(const uint4*)(mP + idx); vp4 = *(const uint4*)(vP + idx); }
    float4 s4 = make_float4(0.f, 0.f, 0.f, 0.f);
    if (mode == 2) s4 = *(const float4*)(S + idx);

    // ---- strip load: 360 uint4 tasks, stored packed ----
    if (interior) {
#pragma unroll
        for (int k = 0; k < 2; ++k) {
            int task = tid + (k << 8);
            if (task < 360) {
                int u = (task * 205) >> 11;      // task/10 exact for task<360
                int v = task - 10 * u;
                *(uint4*)&sP[u][4 * v] =
                    *(const uint4*)(pPrev + base + (size_t)(y0 - 2 + u) * Wd + (x0 - 4 + 4 * v));
            }
        }
    } else {
#pragma unroll
        for (int k = 0; k < 2; ++k) {
            int task = tid + (k << 8);
            if (task < 360) {
                int u = (task * 205) >> 11;
                int v = task - 10 * u;
                int gyy = y0 - 2 + u, gxx = x0 - 4 + 4 * v;
                uint4 w = make_uint4(0u, 0u, 0u, 0u);
                if ((unsigned)gyy < 256u && (unsigned)gxx < 256u)
                    w = *(const uint4*)(pPrev + base + (size_t)gyy * Wd + gxx);
                *(uint4*)&sP[u][4 * v] = w;
            }
        }
    }

    // ---- SSB coef prologue on wave 3 only (overlaps strip load) ----
    if (tid >= 192) {
        int l = tid - 192;
        unsigned long long ax = accPrev[l * 8];
        unsigned long long ay = accPrev[l * 8 + 1];
#pragma unroll
        for (int off = 1; off < 64; off <<= 1) {
            ax += __shfl_xor(ax, off, 64);
            ay += __shfl_xor(ay, off, 64);
        }
        if (l == 0) {
            double axd = (double)ax * (1.0 / SCFP);
            double ayd = (double)ay * (1.0 / SCFP);
            double nxd = sqrt(axd), nyd = sqrt(ayd);
            double pnd = nxd + nyd;
            double uu = pnd * pnd - 0.01;             // V^2
            double sg = (uu > 0.0) ? 1.0 : ((uu < 0.0) ? -1.0 : 0.0);
            sRed[6] = (float)(0.2 * sg * pnd / nxd);
            sRed[7] = (float)(0.2 * sg * pnd / nyd);
        }
    }
    __syncthreads();
    const float coefx = sRed[6];
    const float coefy = sRed[7];

    const __half2 k8 = __float2half2_rn(0.125f);
    const __half2 k4 = __float2half2_rn(0.25f);
    const __half2 h4 = __float2half2_rn(4.0f);
    const __half2 h6 = __float2half2_rn(6.0f);
    const __half2 hn2 = __float2half2_rn(-2.0f);

    float dKx[4], dKy[4], pxa[4], pya[4];

    if (interior) {
        // ---- row pass: 288 tasks (36 rows x 8 groups), composed-kernel halves
        //  A = phi[x-2] - 2 phi[x] + phi[x+2]   (D row)
        //  B = phi[x-2] + 4 phi[x-1] + 6 phi[x] + 4 phi[x+1] + phi[x+2]  (S row)
#pragma unroll
        for (int k = 0; k < 2; ++k) {
            int task = tid + (k << 8);
            if (task < 288) {
                int u = task >> 3, g = task & 7;
                uint4 W0 = *(uint4*)&sP[u][4 * g];
                uint4 W1 = *(uint4*)&sP[u][4 * g + 4];
                uint4 W2 = *(uint4*)&sP[u][4 * g + 8];
                __half2 w[12] = {ash2(W0.x), ash2(W0.y), ash2(W0.z), ash2(W0.w),
                                 ash2(W1.x), ash2(W1.y), ash2(W1.z), ash2(W1.w),
                                 ash2(W2.x), ash2(W2.y), ash2(W2.z), ash2(W2.w)};
                unsigned au[4], bu[4];
#pragma unroll
                for (int jj = 0; jj < 4; ++jj) {
                    __half2 e = __hadd2(w[2 + jj], w[6 + jj]);
                    __half2 A = __hfma2(hn2, w[4 + jj], e);
                    __half2 f = __hadd2(w[3 + jj], w[5 + jj]);
                    __half2 B = __hfma2(h6, w[4 + jj], __hfma2(h4, f, e));
                    au[jj] = asu32(A);
                    bu[jj] = asu32(B);
                }
                *(uint4*)&sA[u][4 * g] = make_uint4(au[0], au[1], au[2], au[3]);
                *(uint4*)&sB[u][4 * g] = make_uint4(bu[0], bu[1], bu[2], bu[3]);
            }
        }
        __syncthreads();

        // ---- column pass: dK_raw = S-col(A) + D-col(B) (scale folded in ckin)
        {
            uint4 pw = *(uint4*)&sP[rr + 2][4 * cgi + 4];
            unsigned pwv[4] = {pw.x, pw.y, pw.z, pw.w};
#pragma unroll
            for (int j = 0; j < 4; ++j) {
                float2 f = __half22float2(ash2(pwv[j]));
                pxa[j] = f.x; pya[j] = f.y;
            }
            const int cb = 4 * cgi;
            uint4 A0 = *(uint4*)&sA[rr][cb];
            uint4 A1 = *(uint4*)&sA[rr + 1][cb];
            uint4 A2 = *(uint4*)&sA[rr + 2][cb];
            uint4 A3 = *(uint4*)&sA[rr + 3][cb];
            uint4 A4 = *(uint4*)&sA[rr + 4][cb];
            uint4 B0 = *(uint4*)&sB[rr][cb];
            uint4 B2 = *(uint4*)&sB[rr + 2][cb];
            uint4 B4 = *(uint4*)&sB[rr + 4][cb];
            unsigned a0[4] = {A0.x, A0.y, A0.z, A0.w};
            unsigned a1[4] = {A1.x, A1.y, A1.z, A1.w};
            unsigned a2v[4] = {A2.x, A2.y, A2.z, A2.w};
            unsigned a3[4] = {A3.x, A3.y, A3.z, A3.w};
            unsigned a4[4] = {A4.x, A4.y, A4.z, A4.w};
            unsigned b0[4] = {B0.x, B0.y, B0.z, B0.w};
            unsigned b2[4] = {B2.x, B2.y, B2.z, B2.w};
            unsigned b4[4] = {B4.x, B4.y, B4.z, B4.w};
#pragma unroll
            for (int jj = 0; jj < 4; ++jj) {
                __half2 g1 = __hadd2(ash2(a0[jj]), ash2(a4[jj]));
                __half2 g2 = __hadd2(ash2(a1[jj]), ash2(a3[jj]));
                __half2 colA = __hfma2(h6, ash2(a2v[jj]), __hfma2(h4, g2, g1));
                __half2 g3 = __hadd2(ash2(b0[jj]), ash2(b4[jj]));
                __half2 colB = __hfma2(hn2, ash2(b2[jj]), g3);
                float2 f = __half22float2(__hadd2(colA, colB));
                dKx[jj] = f.x; dKy[jj] = f.y;
            }
        }
    } else {
        // ---- border: exact two-stage path (c-stage then d-stage) ----
#pragma unroll
        for (int k = 0; k < 2; ++k) {
            int task = tid + (k << 8);
            if (task < 306) {
                int a = (task * 57) >> 9;            // task/9 exact for task<306
                int v = task - 9 * a;
                uint4 T0 = *(uint4*)&sP[a][4 * v];     uint4 T1 = *(uint4*)&sP[a][4 * v + 4];
                uint4 M0 = *(uint4*)&sP[a + 1][4 * v]; uint4 M1 = *(uint4*)&sP[a + 1][4 * v + 4];
                uint4 B0 = *(uint4*)&sP[a + 2][4 * v]; uint4 B1 = *(uint4*)&sP[a + 2][4 * v + 4];
                __half2 wt[6] = {ash2(T0.x), ash2(T0.y), ash2(T0.z), ash2(T0.w), ash2(T1.x), ash2(T1.y)};
                __half2 wm[6] = {ash2(M0.x), ash2(M0.y), ash2(M0.z), ash2(M0.w), ash2(M1.x), ash2(M1.y)};
                __half2 wb[6] = {ash2(B0.x), ash2(B0.y), ash2(B0.z), ash2(B0.w), ash2(B1.x), ash2(B1.y)};
                int gyy = y0 - 1 + a;
                bool rowok = (unsigned)gyy < 256u;
                unsigned c1u[4], c2u[4];
#pragma unroll
                for (int jj = 0; jj < 4; ++jj) {
                    __half2 c1 = __hfma2(k4, __hsub2(wm[jj + 2], wm[jj]),
                                 __hmul2(k8, __hadd2(__hsub2(wt[jj + 2], wt[jj]),
                                                     __hsub2(wb[jj + 2], wb[jj]))));
                    __half2 c2 = __hfma2(k4, __hsub2(wb[jj + 1], wt[jj + 1]),
                                 __hmul2(k8, __hadd2(__hsub2(wb[jj], wt[jj]),
                                                     __hsub2(wb[jj + 2], wt[jj + 2]))));
                    unsigned msk = (rowok && (unsigned)(x0 + 4 * v - 3 + jj) < 256u)
                                   ? 0xFFFFFFFFu : 0u;
                    c1u[jj] = asu32(c1) & msk;
                    c2u[jj] = asu32(c2) & msk;
                }
                *(uint4*)&sA[a][4 * v] = make_uint4(c1u[0], c1u[1], c1u[2], c1u[3]);
                *(uint4*)&sB[a][4 * v] = make_uint4(c2u[0], c2u[1], c2u[2], c2u[3]);
            }
        }
        __syncthreads();
        {
            uint4 pw = *(uint4*)&sP[rr + 2][4 * cgi + 4];
            unsigned pwv[4] = {pw.x, pw.y, pw.z, pw.w};
#pragma unroll
            for (int j = 0; j < 4; ++j) {
                float2 f = __half22float2(ash2(pwv[j]));
                pxa[j] = f.x; pya[j] = f.y;
            }
            const int cb = 4 * cgi;
            uint4 U0a = *(uint4*)&sA[rr][cb];     uint4 U0b = *(uint4*)&sA[rr][cb + 4];
            uint4 U1a = *(uint4*)&sA[rr + 1][cb]; uint4 U1b = *(uint4*)&sA[rr + 1][cb + 4];
            uint4 U2a = *(uint4*)&sA[rr + 2][cb]; uint4 U2b = *(uint4*)&sA[rr + 2][cb + 4];
            uint4 V0a = *(uint4*)&sB[rr][cb];     uint4 V0b = *(uint4*)&sB[rr][cb + 4];
            uint4 V2a = *(uint4*)&sB[rr + 2][cb]; uint4 V2b = *(uint4*)&sB[rr + 2][cb + 4];
            __half2 u0[8] = {ash2(U0a.x), ash2(U0a.y), ash2(U0a.z), ash2(U0a.w),
                             ash2(U0b.x), ash2(U0b.y), ash2(U0b.z), ash2(U0b.w)};
            __half2 u1[8] = {ash2(U1a.x), ash2(U1a.y), ash2(U1a.z), ash2(U1a.w),
                             ash2(U1b.x), ash2(U1b.y), ash2(U1b.z), ash2(U1b.w)};
            __half2 u2[8] = {ash2(U2a.x), ash2(U2a.y), ash2(U2a.z), ash2(U2a.w),
                             ash2(U2b.x), ash2(U2b.y), ash2(U2b.z), ash2(U2b.w)};
            __half2 t0[8] = {ash2(V0a.x), ash2(V0a.y), ash2(V0a.z), ash2(V0a.w),
                             ash2(V0b.x), ash2(V0b.y), ash2(V0b.z), ash2(V0b.w)};
            __half2 t2[8] = {ash2(V2a.x), ash2(V2a.y), ash2(V2a.z), ash2(V2a.w),
                             ash2(V2b.x), ash2(V2b.y), ash2(V2b.z), ash2(V2b.w)};
#pragma unroll
            for (int jj = 0; jj < 4; ++jj) {
                __half2 A = __hadd2(__hadd2(__hsub2(u0[jj + 4], u0[jj + 2]),
                                            __hsub2(u2[jj + 4], u2[jj + 2])),
                                    __hadd2(__hsub2(t2[jj + 2], t0[jj + 2]),
                                            __hsub2(t2[jj + 4], t0[jj + 4])));
                __half2 B = __hadd2(__hsub2(u1[jj + 4], u1[jj + 2]),
                                    __hsub2(t2[jj + 3], t0[jj + 3]));
                __half2 dk = __hfma2(k4, B, __hmul2(k8, A));
                float2 f = __half22float2(dk);
                dKx[jj] = f.x; dKy[jj] = f.y;
            }
        }
    }

    // ---- pointwise grad + Adam (dx,dy,void precomputed; rsqrt update) ----
    unsigned duv[4] = {d4.x, d4.y, d4.z, d4.w};
    unsigned mpv[4] = {mp4.x, mp4.y, mp4.z, mp4.w};
    unsigned vpv[4] = {vp4.x, vp4.y, vp4.z, vp4.w};
    float sa[4] = {s4.x, s4.y, s4.z, s4.w};

    unsigned nmw[4], nvw[4], npk[4];
    float npx[4], npy[4], spv[4];
    float sumx = 0.f, sumy = 0.f;
#pragma unroll
    for (int j = 0; j < 4; ++j) {
        float2 dd = __half22float2(ash2(duv[j]));
        float dx_ = dd.x, dy_ = dd.y;
        float vmc = (duv[j] & 1u) ? C_VOID : 0.f;
        float R = pxa[j] * dx_ + pya[j] * dy_;
        float gx_ = C_COUP * R * dx_ - ckin * dKx[j] + (coefx + vmc) * pxa[j];
        float gy_ = C_COUP * R * dy_ - ckin * dKy[j] + (coefy + vmc) * pya[j];

        float m1 = first ? (0.1f * gx_) : (0.9f * bflo(mpv[j]) + 0.1f * gx_);
        float v1 = first ? (0.001f * gx_ * gx_) : (0.999f * bflo(vpv[j]) + 0.001f * gx_ * gx_);
        npx[j] = fmaf(-a2 * m1, __frsqrt_rn(v1), pxa[j]);
        sumx += npx[j] * npx[j];

        float m2 = first ? (0.1f * gy_) : (0.9f * bfhi(mpv[j]) + 0.1f * gy_);
        float v2 = first ? (0.001f * gy_ * gy_) : (0.999f * bfhi(vpv[j]) + 0.001f * gy_ * gy_);
        npy[j] = fmaf(-a2 * m2, __frsqrt_rn(v2), pya[j]);
        sumy += npy[j] * npy[j];

        nmw[j] = bfpack(m1, m2);
        nvw[j] = bfpack(v1, v2);
        npk[j] = packh2z(npx[j], npy[j]);
        spv[j] = sa[j] + R;
    }
    if (mode != 2) {   // last step: state never read again
        *(uint4*)(mP + idx) = make_uint4(nmw[0], nmw[1], nmw[2], nmw[3]);
        *(uint4*)(vP + idx) = make_uint4(nvw[0], nvw[1], nvw[2], nvw[3]);
        *(uint4*)(pCur + idx) = make_uint4(npk[0], npk[1], npk[2], npk[3]);
    }
    if (mode != 0) {
        *(float4*)(outx + idx) = make_float4(npx[0], npx[1], npx[2], npx[3]);
        *(float4*)(outy + idx) = make_float4(npy[0], npy[1], npy[2], npy[3]);
    }
    if (mode == 2)
        *(float4*)(sp + idx) = make_float4(spv[0], spv[1], spv[2], spv[3]);

    block_acc(sumx, sumy, sRed, accCur + (size_t)zsl * 8);
}

// init: pack phi0 -> p0, precompute packed (dx,dy,void) from S, ||phi0||^2
__global__ __launch_bounds__(256)
void k_init(const float* __restrict__ S,
            const float* __restrict__ px0, const float* __restrict__ py0,
            unsigned* __restrict__ p0, unsigned* __restrict__ dxy,
            unsigned long long* __restrict__ acc0)
{
    __shared__ float sRed[8];
    const int tid = threadIdx.x;
    float sx = 0.f, sy = 0.f;
#pragma unroll
    for (int k = 0; k < 2; ++k) {
        size_t idx = (size_t)blockIdx.x * 2048 + (size_t)(k * 1024 + tid * 4);
        float4 x = *(const float4*)(px0 + idx);
        float4 y = *(const float4*)(py0 + idx);
        *(uint4*)(p0 + idx) = make_uint4(packh2(x.x, y.x), packh2(x.y, y.y),
                                         packh2(x.z, y.z), packh2(x.w, y.w));
        sx += x.x * x.x + x.y * x.y + x.z * x.z + x.w * x.w;
        sy += y.x * y.x + y.y * y.y + y.z * y.z + y.w * y.w;

        // dx,dy,void pack
        int col = (int)(idx & 255u);
        int row = (int)((idx >> 8) & 255u);
        float4 s4 = *(const float4*)(S + idx);
        float sa[4] = {s4.x, s4.y, s4.z, s4.w};
        float sE = (col + 4 < 256) ? S[idx + 4] : 0.f;
        float4 sD = (row < 255) ? *(const float4*)(S + idx + 256) : make_float4(0.f, 0.f, 0.f, 0.f);
        float sd[4] = {sD.x, sD.y, sD.z, sD.w};
        unsigned du[4];
#pragma unroll
        for (int j = 0; j < 4; ++j) {
            float dx_ = (j < 3) ? (sa[j + 1] - sa[j]) : ((col + 4 < 256) ? (sE - sa[3]) : 0.f);
            float dy_ = (row < 255) ? (sd[j] - sa[j]) : 0.f;
            unsigned u = packh2(dx_, dy_);
            du[j] = (u & ~1u) | ((sa[j] < 0.05f) ? 1u : 0u);
        }
        *(uint4*)(dxy + idx) = make_uint4(du[0], du[1], du[2], du[3]);
    }
    block_acc(sx, sy, sRed, acc0 + (size_t)(blockIdx.x & (NSLOT - 1)) * 8);
}

extern "C" void kernel_launch(void* const* d_in, const int* in_sizes, int n_in,
                              void* d_out, int out_size, void* d_ws, size_t ws_size,
                              hipStream_t stream) {
    (void)in_sizes; (void)n_in; (void)out_size; (void)ws_size;
    const float* S   = (const float*)d_in[0];
    const float* px0 = (const float*)d_in[1];
    const float* py0 = (const float*)d_in[2];
    float* out = (float*)d_out;

    float* sp     = out;                      // slot 0: Sp
    float* outA_x = out + (size_t)NTOT;       // slot 1: phi_x post
    float* outA_y = out + 2 * (size_t)NTOT;   // slot 2: phi_y post
    float* outB_x = out + 3 * (size_t)NTOT;   // slot 3: phi_x pre
    float* outB_y = out + 4 * (size_t)NTOT;   // slot 4: phi_y pre

    unsigned* ws = (unsigned*)d_ws;
    unsigned* p0 = ws;                        // packed (fp16 phix, fp16 phiy), 16 MB
    unsigned* p1 = p0 + (size_t)NTOT;         // ping-pong partner, 16 MB
    unsigned* mP = p1 + (size_t)NTOT;         // packed (bf16 mx, bf16 my), 16 MB
    unsigned* vP = mP + (size_t)NTOT;         // packed (bf16 vx, bf16 vy), 16 MB
    unsigned* dxy = vP + (size_t)NTOT;        // packed (fp16 dx, fp16 dy | void), 16 MB
    unsigned long long* acc = (unsigned long long*)(dxy + (size_t)NTOT);  // [NACC][NSLOT][8]

    hipMemsetAsync(acc, 0, (size_t)NACC * NSLOT * 8 * sizeof(unsigned long long), stream);

    k_init<<<2048, 256, 0, stream>>>(S, px0, py0, p0, dxy, acc);

    for (int t = 1; t <= 50; ++t) {
        double bc1 = 1.0 - pow(0.9, (double)t);
        double bc2 = 1.0 - pow(0.999, (double)t);
        float a2 = (float)(0.05 / bc1 * sqrt(bc2));   // LR/bc1 * sqrt(bc2)
        bool odd = (t & 1) != 0;
        const unsigned* pPrev = odd ? p0 : p1;
        unsigned* pCur = odd ? p1 : p0;
        int mode = (t == 49) ? 1 : ((t == 50) ? 2 : 0);
        float* ox = (t == 50) ? outA_x : outB_x;   // mode1 -> pre slots, mode2 -> post
        float* oy = (t == 50) ? outA_y : outB_y;
        k_step<<<4096, 256, 0, stream>>>(S, dxy, pPrev, pCur, mP, vP,
                                         acc + (size_t)(t - 1) * NSLOT * 8,
                                         acc + (size_t)t * NSLOT * 8,
                                         a2, mode, (t == 1) ? 1 : 0,
                                         ox, oy, sp);
    }
}